// Round 1
// baseline (436.880 us; speedup 1.0000x reference)
//
#include <hip/hip_runtime.h>
#include <math.h>

#define N_NODES 50000
#define N_EDGES 800000
#define N_GRAPHS 64
#define DIM 128
#define OUTD 16

// ---------------- CSR build ----------------

__global__ void k_count(const int* __restrict__ dst, int* __restrict__ cnt) {
    int e = blockIdx.x * blockDim.x + threadIdx.x;
    if (e < N_EDGES) atomicAdd(&cnt[dst[e]], 1);
}

// block-local exclusive scan (1024/block); block totals to bsum
__global__ void k_scan1(const int* __restrict__ cnt, int* __restrict__ excl,
                        int* __restrict__ bsum) {
    __shared__ int s[1024];
    int i = blockIdx.x * 1024 + threadIdx.x;
    int v = (i < N_NODES) ? cnt[i] : 0;
    s[threadIdx.x] = v;
    __syncthreads();
    for (int off = 1; off < 1024; off <<= 1) {
        int t = (threadIdx.x >= off) ? s[threadIdx.x - off] : 0;
        __syncthreads();
        s[threadIdx.x] += t;
        __syncthreads();
    }
    if (i < N_NODES) excl[i] = s[threadIdx.x] - v;   // exclusive
    if (threadIdx.x == 1023) bsum[blockIdx.x] = s[1023];
}

// single-wave exclusive scan of block sums (nb <= 64)
__global__ void k_scan2(int* __restrict__ bsum, int nb) {
    int tid = threadIdx.x;
    int v = (tid < nb) ? bsum[tid] : 0;
    int orig = v;
    for (int off = 1; off < 64; off <<= 1) {
        int t = __shfl_up(v, off);
        if (tid >= off) v += t;
    }
    if (tid < nb) bsum[tid] = v - orig;
}

// add block offsets; emit cursor (= row start) and deg_inv_sqrt
__global__ void k_scan3(const int* __restrict__ cnt, const int* __restrict__ bsum,
                        int* __restrict__ row_off, int* __restrict__ cursor,
                        float* __restrict__ dis) {
    int i = blockIdx.x * 1024 + threadIdx.x;
    if (i < N_NODES) {
        int ro = row_off[i] + bsum[blockIdx.x];
        row_off[i] = ro;
        cursor[i] = ro;
        dis[i] = rsqrtf((float)(cnt[i] + 1));   // +1 = self-loop
    }
    if (i == 0) row_off[N_NODES] = N_EDGES;
}

__global__ void k_fill(const int* __restrict__ src, const int* __restrict__ dstp,
                       const float* __restrict__ dis, int* __restrict__ cursor,
                       int* __restrict__ csr_src, float* __restrict__ csr_w) {
    int e = blockIdx.x * blockDim.x + threadIdx.x;
    if (e < N_EDGES) {
        int s = src[e], d = dstp[e];
        int pos = atomicAdd(&cursor[d], 1);
        csr_src[pos] = s;
        csr_w[pos] = dis[s] * dis[d];
    }
}

// ---------------- GEMM: C[n,128] = A[n,128] @ W[128,128] ----------------
// W fully in LDS (64 KB). Thread micro-tile: 4 rows x 4 cols.
__global__ __launch_bounds__(256) void k_gemm(const float* __restrict__ A,
                                              const float* __restrict__ Wg,
                                              float* __restrict__ C, int nrows) {
    __shared__ float Wl[DIM * DIM];
    const float4* Wg4 = (const float4*)Wg;
    float4* Wl4 = (float4*)Wl;
#pragma unroll
    for (int i = 0; i < 16; ++i)
        Wl4[threadIdx.x + 256 * i] = Wg4[threadIdx.x + 256 * i];
    __syncthreads();

    int cq = threadIdx.x & 31;        // col quad: cols 4*cq .. 4*cq+3
    int rg = threadIdx.x >> 5;        // 0..7
    int r0 = blockIdx.x * 32 + rg * 4;

    const float4* A4 = (const float4*)A;
    float4 acc[4];
    int rc[4];
#pragma unroll
    for (int j = 0; j < 4; ++j) {
        acc[j] = make_float4(0.f, 0.f, 0.f, 0.f);
        int r = r0 + j;
        rc[j] = (r < nrows) ? r : 0;  // clamp loads; stores guarded
    }

    for (int k = 0; k < DIM; k += 4) {
        float4 w0 = Wl4[(k + 0) * 32 + cq];
        float4 w1 = Wl4[(k + 1) * 32 + cq];
        float4 w2 = Wl4[(k + 2) * 32 + cq];
        float4 w3 = Wl4[(k + 3) * 32 + cq];
#pragma unroll
        for (int j = 0; j < 4; ++j) {
            float4 av = A4[(size_t)rc[j] * 32 + (k >> 2)];
            acc[j].x = fmaf(av.x, w0.x, fmaf(av.y, w1.x, fmaf(av.z, w2.x, fmaf(av.w, w3.x, acc[j].x))));
            acc[j].y = fmaf(av.x, w0.y, fmaf(av.y, w1.y, fmaf(av.z, w2.y, fmaf(av.w, w3.y, acc[j].y))));
            acc[j].z = fmaf(av.x, w0.z, fmaf(av.y, w1.z, fmaf(av.z, w2.z, fmaf(av.w, w3.z, acc[j].z))));
            acc[j].w = fmaf(av.x, w0.w, fmaf(av.y, w1.w, fmaf(av.z, w2.w, fmaf(av.w, w3.w, acc[j].w))));
        }
    }

    float4* C4 = (float4*)C;
#pragma unroll
    for (int j = 0; j < 4; ++j) {
        int r = r0 + j;
        if (r < nrows) C4[(size_t)r * 32 + cq] = acc[j];
    }
}

// ---------------- Aggregation (pull): out = relu(b + D^-1/2 A D^-1/2 H) ----
// 32 lanes per node, float4 per lane -> 128 channels. Each output row written once.
__global__ __launch_bounds__(256) void k_agg(const float* __restrict__ H,
                                             const int* __restrict__ row_off,
                                             const int* __restrict__ csr_src,
                                             const float* __restrict__ csr_w,
                                             const float* __restrict__ dis,
                                             const float* __restrict__ bias,
                                             float* __restrict__ out) {
    int lane = threadIdx.x & 31;
    int node = blockIdx.x * 8 + (threadIdx.x >> 5);
    if (node >= N_NODES) return;

    const float4* H4 = (const float4*)H;
    float dn = dis[node];
    float wself = dn * dn;
    float4 hv = H4[(size_t)node * 32 + lane];
    float4 acc;
    acc.x = wself * hv.x; acc.y = wself * hv.y;
    acc.z = wself * hv.z; acc.w = wself * hv.w;

    int e0 = row_off[node], e1 = row_off[node + 1];
    for (int e = e0; e < e1; ++e) {
        int s = csr_src[e];
        float w = csr_w[e];
        float4 v = H4[(size_t)s * 32 + lane];
        acc.x = fmaf(w, v.x, acc.x);
        acc.y = fmaf(w, v.y, acc.y);
        acc.z = fmaf(w, v.z, acc.z);
        acc.w = fmaf(w, v.w, acc.w);
    }
    float4 b = ((const float4*)bias)[lane];
    acc.x = fmaxf(acc.x + b.x, 0.f);
    acc.y = fmaxf(acc.y + b.y, 0.f);
    acc.z = fmaxf(acc.z + b.z, 0.f);
    acc.w = fmaxf(acc.w + b.w, 0.f);
    ((float4*)out)[(size_t)node * 32 + lane] = acc;
}

// ---------------- Mean pool (batch sorted -> chunked accumulation) --------
__global__ void k_pool(const float* __restrict__ h, const int* __restrict__ batch,
                       float* __restrict__ pool, float* __restrict__ pcnt) {
    int chunk = (N_NODES + gridDim.x - 1) / gridDim.x;
    int n0 = blockIdx.x * chunk;
    int n1 = min(n0 + chunk, N_NODES);
    if (n0 >= n1) return;
    int c = threadIdx.x;              // 128 threads = channels
    int curg = batch[n0];
    float acc = 0.f;
    int count = 0;
    for (int n = n0; n < n1; ++n) {
        int g = batch[n];             // uniform across block
        if (g != curg) {
            atomicAdd(&pool[curg * DIM + c], acc);
            if (c == 0) atomicAdd(&pcnt[curg], (float)count);
            acc = 0.f; count = 0; curg = g;
        }
        acc += h[(size_t)n * DIM + c];
        count++;
    }
    atomicAdd(&pool[curg * DIM + c], acc);
    if (c == 0) atomicAdd(&pcnt[curg], (float)count);
}

// ---------------- Final FC: out[g,o] = bfc[o] + (pool[g]/cnt[g]) @ Wfc ----
__global__ void k_fc(const float* __restrict__ pool, const float* __restrict__ pcnt,
                     const float* __restrict__ Wfc, const float* __restrict__ bfc,
                     float* __restrict__ out) {
    int id = blockIdx.x * blockDim.x + threadIdx.x;
    if (id >= N_GRAPHS * OUTD) return;
    int g = id >> 4, o = id & 15;
    float inv = 1.0f / fmaxf(pcnt[g], 1.0f);
    float acc = bfc[o];
    const float* p = pool + g * DIM;
    for (int c = 0; c < DIM; ++c)
        acc = fmaf(p[c] * inv, Wfc[c * OUTD + o], acc);
    out[id] = acc;
}

// ---------------- launch ----------------

extern "C" void kernel_launch(void* const* d_in, const int* in_sizes, int n_in,
                              void* d_out, int out_size, void* d_ws, size_t ws_size,
                              hipStream_t stream) {
    const float* x    = (const float*)d_in[0];
    const int*   ei   = (const int*)d_in[1];
    const int*   batch= (const int*)d_in[2];
    const float* W1   = (const float*)d_in[3];
    const float* b1   = (const float*)d_in[4];
    const float* W2   = (const float*)d_in[5];
    const float* b2   = (const float*)d_in[6];
    const float* Wfc  = (const float*)d_in[7];
    const float* bfc  = (const float*)d_in[8];
    float* out = (float*)d_out;

    char* ws = (char*)d_ws;
    size_t off = 0;
    auto alloc = [&](size_t bytes) -> char* {
        char* p = ws + off;
        off = (off + bytes + 255) & ~(size_t)255;
        return p;
    };
    int*   cnt     = (int*)  alloc((size_t)N_NODES * 4);
    int*   row_off = (int*)  alloc((size_t)(N_NODES + 1) * 4);
    int*   cursor  = (int*)  alloc((size_t)N_NODES * 4);
    float* dis     = (float*)alloc((size_t)N_NODES * 4);
    int*   bsum    = (int*)  alloc(64 * 4);
    int*   csr_src = (int*)  alloc((size_t)N_EDGES * 4);
    float* csr_w   = (float*)alloc((size_t)N_EDGES * 4);
    float* pool    = (float*)alloc((size_t)N_GRAPHS * DIM * 4);
    float* pcnt    = (float*)alloc((size_t)N_GRAPHS * 4);
    float* bufA    = (float*)alloc((size_t)N_NODES * DIM * 4);
    float* bufB    = (float*)alloc((size_t)N_NODES * DIM * 4);

    const int* src = ei;            // edge_index[0]
    const int* dst = ei + N_EDGES;  // edge_index[1]

    hipMemsetAsync(cnt,  0, (size_t)N_NODES * 4, stream);
    hipMemsetAsync(pool, 0, (size_t)N_GRAPHS * DIM * 4, stream);
    hipMemsetAsync(pcnt, 0, (size_t)N_GRAPHS * 4, stream);

    int nb = (N_NODES + 1023) / 1024;  // 49
    k_count<<<(N_EDGES + 255) / 256, 256, 0, stream>>>(dst, cnt);
    k_scan1<<<nb, 1024, 0, stream>>>(cnt, row_off, bsum);
    k_scan2<<<1, 64, 0, stream>>>(bsum, nb);
    k_scan3<<<nb, 1024, 0, stream>>>(cnt, bsum, row_off, cursor, dis);
    k_fill<<<(N_EDGES + 255) / 256, 256, 0, stream>>>(src, dst, dis, cursor, csr_src, csr_w);

    // layer 1
    k_gemm<<<(N_NODES + 31) / 32, 256, 0, stream>>>(x, W1, bufA, N_NODES);
    k_agg<<<(N_NODES + 7) / 8, 256, 0, stream>>>(bufA, row_off, csr_src, csr_w, dis, b1, bufB);
    // layer 2
    k_gemm<<<(N_NODES + 31) / 32, 256, 0, stream>>>(bufB, W2, bufA, N_NODES);
    k_agg<<<(N_NODES + 7) / 8, 256, 0, stream>>>(bufA, row_off, csr_src, csr_w, dis, b2, bufB);
    // pool + fc
    k_pool<<<256, DIM, 0, stream>>>(bufB, batch, pool, pcnt);
    k_fc<<<(N_GRAPHS * OUTD + 255) / 256, 256, 0, stream>>>(pool, pcnt, Wfc, bfc, out);
}

// Round 2
// 374.666 us; speedup vs baseline: 1.1661x; 1.1661x over previous
//
#include <hip/hip_runtime.h>
#include <math.h>

#define N_NODES 50000
#define N_EDGES 800000
#define N_GRAPHS 64
#define DIM 128
#define OUTD 16

// ---- bf16 helpers (round-to-nearest-even; values are finite) ----
static __device__ __forceinline__ unsigned short f2bf(float f) {
    unsigned u = __float_as_uint(f);
    u += 0x7fffu + ((u >> 16) & 1u);
    return (unsigned short)(u >> 16);
}
static __device__ __forceinline__ float bfl(unsigned u) {   // low bf16 of packed pair
    return __uint_as_float(u << 16);
}
static __device__ __forceinline__ float bfh(unsigned u) {   // high bf16 of packed pair
    return __uint_as_float(u & 0xffff0000u);
}

// ---------------- CSR build ----------------

__global__ void k_count(const int* __restrict__ dst, int* __restrict__ cnt) {
    int e = blockIdx.x * blockDim.x + threadIdx.x;
    if (e < N_EDGES) atomicAdd(&cnt[dst[e]], 1);
}

__global__ void k_scan1(const int* __restrict__ cnt, int* __restrict__ excl,
                        int* __restrict__ bsum) {
    __shared__ int s[1024];
    int i = blockIdx.x * 1024 + threadIdx.x;
    int v = (i < N_NODES) ? cnt[i] : 0;
    s[threadIdx.x] = v;
    __syncthreads();
    for (int off = 1; off < 1024; off <<= 1) {
        int t = (threadIdx.x >= off) ? s[threadIdx.x - off] : 0;
        __syncthreads();
        s[threadIdx.x] += t;
        __syncthreads();
    }
    if (i < N_NODES) excl[i] = s[threadIdx.x] - v;
    if (threadIdx.x == 1023) bsum[blockIdx.x] = s[1023];
}

__global__ void k_scan2(int* __restrict__ bsum, int nb) {
    int tid = threadIdx.x;
    int v = (tid < nb) ? bsum[tid] : 0;
    int orig = v;
    for (int off = 1; off < 64; off <<= 1) {
        int t = __shfl_up(v, off);
        if (tid >= off) v += t;
    }
    if (tid < nb) bsum[tid] = v - orig;
}

__global__ void k_scan3(const int* __restrict__ cnt, const int* __restrict__ bsum,
                        int* __restrict__ row_off, int* __restrict__ cursor,
                        float* __restrict__ dis) {
    int i = blockIdx.x * 1024 + threadIdx.x;
    if (i < N_NODES) {
        int ro = row_off[i] + bsum[blockIdx.x];
        row_off[i] = ro;
        cursor[i] = ro;
        dis[i] = rsqrtf((float)(cnt[i] + 1));
    }
    if (i == 0) row_off[N_NODES] = N_EDGES;
}

// packed CSR entry: {int src, float w} in 8B -> one scatter store per edge
__global__ void k_fill(const int* __restrict__ src, const int* __restrict__ dstp,
                       const float* __restrict__ dis, int* __restrict__ cursor,
                       int2* __restrict__ csr) {
    int e = blockIdx.x * blockDim.x + threadIdx.x;
    if (e < N_EDGES) {
        int s = src[e], d = dstp[e];
        int pos = atomicAdd(&cursor[d], 1);
        csr[pos] = make_int2(s, __float_as_int(dis[s] * dis[d]));
    }
}

// ---------------- GEMM: C[n,128](bf16) = A[n,128](f32) @ W[128,128](f32) ----
__global__ __launch_bounds__(256) void k_gemm(const float* __restrict__ A,
                                              const float* __restrict__ Wg,
                                              unsigned short* __restrict__ C,
                                              int nrows) {
    __shared__ float Wl[DIM * DIM];
    const float4* Wg4 = (const float4*)Wg;
    float4* Wl4 = (float4*)Wl;
#pragma unroll
    for (int i = 0; i < 16; ++i)
        Wl4[threadIdx.x + 256 * i] = Wg4[threadIdx.x + 256 * i];
    __syncthreads();

    int cq = threadIdx.x & 31;
    int rg = threadIdx.x >> 5;
    int r0 = blockIdx.x * 32 + rg * 4;

    const float4* A4 = (const float4*)A;
    float4 acc[4];
    int rc[4];
#pragma unroll
    for (int j = 0; j < 4; ++j) {
        acc[j] = make_float4(0.f, 0.f, 0.f, 0.f);
        int r = r0 + j;
        rc[j] = (r < nrows) ? r : 0;
    }

    for (int k = 0; k < DIM; k += 4) {
        float4 w0 = Wl4[(k + 0) * 32 + cq];
        float4 w1 = Wl4[(k + 1) * 32 + cq];
        float4 w2 = Wl4[(k + 2) * 32 + cq];
        float4 w3 = Wl4[(k + 3) * 32 + cq];
#pragma unroll
        for (int j = 0; j < 4; ++j) {
            float4 av = A4[(size_t)rc[j] * 32 + (k >> 2)];
            acc[j].x = fmaf(av.x, w0.x, fmaf(av.y, w1.x, fmaf(av.z, w2.x, fmaf(av.w, w3.x, acc[j].x))));
            acc[j].y = fmaf(av.x, w0.y, fmaf(av.y, w1.y, fmaf(av.z, w2.y, fmaf(av.w, w3.y, acc[j].y))));
            acc[j].z = fmaf(av.x, w0.z, fmaf(av.y, w1.z, fmaf(av.z, w2.z, fmaf(av.w, w3.z, acc[j].z))));
            acc[j].w = fmaf(av.x, w0.w, fmaf(av.y, w1.w, fmaf(av.z, w2.w, fmaf(av.w, w3.w, acc[j].w))));
        }
    }

    ushort4* C4 = (ushort4*)C;
#pragma unroll
    for (int j = 0; j < 4; ++j) {
        int r = r0 + j;
        if (r < nrows) {
            ushort4 o;
            o.x = f2bf(acc[j].x); o.y = f2bf(acc[j].y);
            o.z = f2bf(acc[j].z); o.w = f2bf(acc[j].w);
            C4[(size_t)r * 32 + cq] = o;
        }
    }
}

// ---------------- Aggregation (pull, bf16 gather, f32 out) ----------------
// 32 lanes/node, 4 channels (8B bf16) per lane. Edge loop unrolled x4 with
// independent accumulators to keep 4 gathers in flight.
__global__ __launch_bounds__(256) void k_agg(const uint2* __restrict__ Hb,
                                             const int* __restrict__ row_off,
                                             const int2* __restrict__ csr,
                                             const float* __restrict__ dis,
                                             const float* __restrict__ bias,
                                             float* __restrict__ out) {
    int lane = threadIdx.x & 31;
    int node = blockIdx.x * 8 + (threadIdx.x >> 5);
    if (node >= N_NODES) return;

    float dn = dis[node];
    float wself = dn * dn;
    uint2 hp = Hb[(size_t)node * 32 + lane];
    float4 a0, a1, a2, a3;
    a0.x = wself * bfl(hp.x); a0.y = wself * bfh(hp.x);
    a0.z = wself * bfl(hp.y); a0.w = wself * bfh(hp.y);
    a1 = make_float4(0.f, 0.f, 0.f, 0.f);
    a2 = a1; a3 = a1;

    int e = row_off[node], e1 = row_off[node + 1];
    for (; e + 4 <= e1; e += 4) {
        int2 q0 = csr[e];     int2 q1 = csr[e + 1];
        int2 q2 = csr[e + 2]; int2 q3 = csr[e + 3];
        uint2 g0 = Hb[(size_t)q0.x * 32 + lane];
        uint2 g1 = Hb[(size_t)q1.x * 32 + lane];
        uint2 g2 = Hb[(size_t)q2.x * 32 + lane];
        uint2 g3 = Hb[(size_t)q3.x * 32 + lane];
        float w0 = __int_as_float(q0.y), w1 = __int_as_float(q1.y);
        float w2 = __int_as_float(q2.y), w3 = __int_as_float(q3.y);
        a0.x = fmaf(w0, bfl(g0.x), a0.x); a0.y = fmaf(w0, bfh(g0.x), a0.y);
        a0.z = fmaf(w0, bfl(g0.y), a0.z); a0.w = fmaf(w0, bfh(g0.y), a0.w);
        a1.x = fmaf(w1, bfl(g1.x), a1.x); a1.y = fmaf(w1, bfh(g1.x), a1.y);
        a1.z = fmaf(w1, bfl(g1.y), a1.z); a1.w = fmaf(w1, bfh(g1.y), a1.w);
        a2.x = fmaf(w2, bfl(g2.x), a2.x); a2.y = fmaf(w2, bfh(g2.x), a2.y);
        a2.z = fmaf(w2, bfl(g2.y), a2.z); a2.w = fmaf(w2, bfh(g2.y), a2.w);
        a3.x = fmaf(w3, bfl(g3.x), a3.x); a3.y = fmaf(w3, bfh(g3.x), a3.y);
        a3.z = fmaf(w3, bfl(g3.y), a3.z); a3.w = fmaf(w3, bfh(g3.y), a3.w);
    }
    for (; e < e1; ++e) {
        int2 q = csr[e];
        uint2 g = Hb[(size_t)q.x * 32 + lane];
        float w = __int_as_float(q.y);
        a0.x = fmaf(w, bfl(g.x), a0.x); a0.y = fmaf(w, bfh(g.x), a0.y);
        a0.z = fmaf(w, bfl(g.y), a0.z); a0.w = fmaf(w, bfh(g.y), a0.w);
    }

    float4 b = ((const float4*)bias)[lane];
    float4 r;
    r.x = fmaxf(a0.x + a1.x + a2.x + a3.x + b.x, 0.f);
    r.y = fmaxf(a0.y + a1.y + a2.y + a3.y + b.y, 0.f);
    r.z = fmaxf(a0.z + a1.z + a2.z + a3.z + b.z, 0.f);
    r.w = fmaxf(a0.w + a1.w + a2.w + a3.w + b.w, 0.f);
    ((float4*)out)[(size_t)node * 32 + lane] = r;
}

// ---------------- Mean pool ----------------
__global__ void k_pool(const float* __restrict__ h, const int* __restrict__ batch,
                       float* __restrict__ pool, float* __restrict__ pcnt) {
    int chunk = (N_NODES + gridDim.x - 1) / gridDim.x;
    int n0 = blockIdx.x * chunk;
    int n1 = min(n0 + chunk, N_NODES);
    if (n0 >= n1) return;
    int c = threadIdx.x;
    int curg = batch[n0];
    float acc = 0.f;
    int count = 0;
    for (int n = n0; n < n1; ++n) {
        int g = batch[n];
        if (g != curg) {
            atomicAdd(&pool[curg * DIM + c], acc);
            if (c == 0) atomicAdd(&pcnt[curg], (float)count);
            acc = 0.f; count = 0; curg = g;
        }
        acc += h[(size_t)n * DIM + c];
        count++;
    }
    atomicAdd(&pool[curg * DIM + c], acc);
    if (c == 0) atomicAdd(&pcnt[curg], (float)count);
}

// ---------------- Final FC ----------------
__global__ void k_fc(const float* __restrict__ pool, const float* __restrict__ pcnt,
                     const float* __restrict__ Wfc, const float* __restrict__ bfc,
                     float* __restrict__ out) {
    int id = blockIdx.x * blockDim.x + threadIdx.x;
    if (id >= N_GRAPHS * OUTD) return;
    int g = id >> 4, o = id & 15;
    float inv = 1.0f / fmaxf(pcnt[g], 1.0f);
    float acc = bfc[o];
    const float* p = pool + g * DIM;
    for (int c = 0; c < DIM; ++c)
        acc = fmaf(p[c] * inv, Wfc[c * OUTD + o], acc);
    out[id] = acc;
}

// ---------------- launch ----------------

extern "C" void kernel_launch(void* const* d_in, const int* in_sizes, int n_in,
                              void* d_out, int out_size, void* d_ws, size_t ws_size,
                              hipStream_t stream) {
    const float* x    = (const float*)d_in[0];
    const int*   ei   = (const int*)d_in[1];
    const int*   batch= (const int*)d_in[2];
    const float* W1   = (const float*)d_in[3];
    const float* b1   = (const float*)d_in[4];
    const float* W2   = (const float*)d_in[5];
    const float* b2   = (const float*)d_in[6];
    const float* Wfc  = (const float*)d_in[7];
    const float* bfc  = (const float*)d_in[8];
    float* out = (float*)d_out;

    char* ws = (char*)d_ws;
    size_t off = 0;
    auto alloc = [&](size_t bytes) -> char* {
        char* p = ws + off;
        off = (off + bytes + 255) & ~(size_t)255;
        return p;
    };
    int*   cnt     = (int*)  alloc((size_t)N_NODES * 4);
    int*   row_off = (int*)  alloc((size_t)(N_NODES + 1) * 4);
    int*   cursor  = (int*)  alloc((size_t)N_NODES * 4);
    float* dis     = (float*)alloc((size_t)N_NODES * 4);
    int*   bsum    = (int*)  alloc(64 * 4);
    int2*  csr     = (int2*) alloc((size_t)N_EDGES * 8);
    float* pool    = (float*)alloc((size_t)N_GRAPHS * DIM * 4);
    float* pcnt    = (float*)alloc((size_t)N_GRAPHS * 4);
    unsigned short* Hb = (unsigned short*)alloc((size_t)N_NODES * DIM * 2); // bf16
    float* F1      = (float*)alloc((size_t)N_NODES * DIM * 4);              // f32

    const int* src = ei;
    const int* dst = ei + N_EDGES;

    hipMemsetAsync(cnt,  0, (size_t)N_NODES * 4, stream);
    hipMemsetAsync(pool, 0, (size_t)N_GRAPHS * DIM * 4, stream);
    hipMemsetAsync(pcnt, 0, (size_t)N_GRAPHS * 4, stream);

    int nb = (N_NODES + 1023) / 1024;  // 49
    k_count<<<(N_EDGES + 255) / 256, 256, 0, stream>>>(dst, cnt);
    k_scan1<<<nb, 1024, 0, stream>>>(cnt, row_off, bsum);
    k_scan2<<<1, 64, 0, stream>>>(bsum, nb);
    k_scan3<<<nb, 1024, 0, stream>>>(cnt, bsum, row_off, cursor, dis);
    k_fill<<<(N_EDGES + 255) / 256, 256, 0, stream>>>(src, dst, dis, cursor, csr);

    // layer 1: gemm (f32 in, bf16 out) -> agg (bf16 gather, f32 out)
    k_gemm<<<(N_NODES + 31) / 32, 256, 0, stream>>>(x, W1, Hb, N_NODES);
    k_agg<<<(N_NODES + 7) / 8, 256, 0, stream>>>((const uint2*)Hb, row_off, csr, dis, b1, F1);
    // layer 2
    k_gemm<<<(N_NODES + 31) / 32, 256, 0, stream>>>(F1, W2, Hb, N_NODES);
    k_agg<<<(N_NODES + 7) / 8, 256, 0, stream>>>((const uint2*)Hb, row_off, csr, dis, b2, F1);
    // pool + fc
    k_pool<<<256, DIM, 0, stream>>>(F1, batch, pool, pcnt);
    k_fc<<<(N_GRAPHS * OUTD + 255) / 256, 256, 0, stream>>>(pool, pcnt, Wfc, bfc, out);
}

// Round 3
// 333.208 us; speedup vs baseline: 1.3111x; 1.1244x over previous
//
#include <hip/hip_runtime.h>
#include <math.h>

#define N_NODES 50000
#define N_EDGES 800000
#define N_GRAPHS 64
#define DIM 128
#define OUTD 16
#define POOL_BLOCKS 1024

// ---- bf16 helpers (round-to-nearest-even; values are finite) ----
static __device__ __forceinline__ unsigned short f2bf(float f) {
    unsigned u = __float_as_uint(f);
    u += 0x7fffu + ((u >> 16) & 1u);
    return (unsigned short)(u >> 16);
}
static __device__ __forceinline__ float bfl(unsigned u) {   // low bf16 of packed pair
    return __uint_as_float(u << 16);
}
static __device__ __forceinline__ float bfh(unsigned u) {   // high bf16 of packed pair
    return __uint_as_float(u & 0xffff0000u);
}

// ---------------- CSR build ----------------

__global__ void k_count(const int* __restrict__ dst, int* __restrict__ cnt) {
    int e = blockIdx.x * blockDim.x + threadIdx.x;
    if (e < N_EDGES) atomicAdd(&cnt[dst[e]], 1);
}

__global__ void k_scan1(const int* __restrict__ cnt, int* __restrict__ excl,
                        int* __restrict__ bsum) {
    __shared__ int s[1024];
    int i = blockIdx.x * 1024 + threadIdx.x;
    int v = (i < N_NODES) ? cnt[i] : 0;
    s[threadIdx.x] = v;
    __syncthreads();
    for (int off = 1; off < 1024; off <<= 1) {
        int t = (threadIdx.x >= off) ? s[threadIdx.x - off] : 0;
        __syncthreads();
        s[threadIdx.x] += t;
        __syncthreads();
    }
    if (i < N_NODES) excl[i] = s[threadIdx.x] - v;
    if (threadIdx.x == 1023) bsum[blockIdx.x] = s[1023];
}

__global__ void k_scan2(int* __restrict__ bsum, int nb) {
    int tid = threadIdx.x;
    int v = (tid < nb) ? bsum[tid] : 0;
    int orig = v;
    for (int off = 1; off < 64; off <<= 1) {
        int t = __shfl_up(v, off);
        if (tid >= off) v += t;
    }
    if (tid < nb) bsum[tid] = v - orig;
}

__global__ void k_scan3(const int* __restrict__ cnt, const int* __restrict__ bsum,
                        int* __restrict__ row_off, int* __restrict__ cursor,
                        float* __restrict__ dis) {
    int i = blockIdx.x * 1024 + threadIdx.x;
    if (i < N_NODES) {
        int ro = row_off[i] + bsum[blockIdx.x];
        row_off[i] = ro;
        cursor[i] = ro;
        dis[i] = rsqrtf((float)(cnt[i] + 1));
    }
    if (i == 0) row_off[N_NODES] = N_EDGES;
}

// packed CSR entry: {int src, float w} in 8B -> one scatter store per edge
__global__ void k_fill(const int* __restrict__ src, const int* __restrict__ dstp,
                       const float* __restrict__ dis, int* __restrict__ cursor,
                       int2* __restrict__ csr) {
    int e = blockIdx.x * blockDim.x + threadIdx.x;
    if (e < N_EDGES) {
        int s = src[e], d = dstp[e];
        int pos = atomicAdd(&cursor[d], 1);
        csr[pos] = make_int2(s, __float_as_int(dis[s] * dis[d]));
    }
}

// ---------------- GEMM: C[n,128](bf16) = A[n,128](f32) @ W[128,128](f32) ----
__global__ __launch_bounds__(256) void k_gemm(const float* __restrict__ A,
                                              const float* __restrict__ Wg,
                                              unsigned short* __restrict__ C,
                                              int nrows) {
    __shared__ float Wl[DIM * DIM];
    const float4* Wg4 = (const float4*)Wg;
    float4* Wl4 = (float4*)Wl;
#pragma unroll
    for (int i = 0; i < 16; ++i)
        Wl4[threadIdx.x + 256 * i] = Wg4[threadIdx.x + 256 * i];
    __syncthreads();

    int cq = threadIdx.x & 31;
    int rg = threadIdx.x >> 5;
    int r0 = blockIdx.x * 32 + rg * 4;

    const float4* A4 = (const float4*)A;
    float4 acc[4];
    int rc[4];
#pragma unroll
    for (int j = 0; j < 4; ++j) {
        acc[j] = make_float4(0.f, 0.f, 0.f, 0.f);
        int r = r0 + j;
        rc[j] = (r < nrows) ? r : 0;
    }

    for (int k = 0; k < DIM; k += 4) {
        float4 w0 = Wl4[(k + 0) * 32 + cq];
        float4 w1 = Wl4[(k + 1) * 32 + cq];
        float4 w2 = Wl4[(k + 2) * 32 + cq];
        float4 w3 = Wl4[(k + 3) * 32 + cq];
#pragma unroll
        for (int j = 0; j < 4; ++j) {
            float4 av = A4[(size_t)rc[j] * 32 + (k >> 2)];
            acc[j].x = fmaf(av.x, w0.x, fmaf(av.y, w1.x, fmaf(av.z, w2.x, fmaf(av.w, w3.x, acc[j].x))));
            acc[j].y = fmaf(av.x, w0.y, fmaf(av.y, w1.y, fmaf(av.z, w2.y, fmaf(av.w, w3.y, acc[j].y))));
            acc[j].z = fmaf(av.x, w0.z, fmaf(av.y, w1.z, fmaf(av.z, w2.z, fmaf(av.w, w3.z, acc[j].z))));
            acc[j].w = fmaf(av.x, w0.w, fmaf(av.y, w1.w, fmaf(av.z, w2.w, fmaf(av.w, w3.w, acc[j].w))));
        }
    }

    ushort4* C4 = (ushort4*)C;
#pragma unroll
    for (int j = 0; j < 4; ++j) {
        int r = r0 + j;
        if (r < nrows) {
            ushort4 o;
            o.x = f2bf(acc[j].x); o.y = f2bf(acc[j].y);
            o.z = f2bf(acc[j].z); o.w = f2bf(acc[j].w);
            C4[(size_t)r * 32 + cq] = o;
        }
    }
}

// ---------------- Aggregation (pull, bf16 gather, f32 out) ----------------
__global__ __launch_bounds__(256) void k_agg(const uint2* __restrict__ Hb,
                                             const int* __restrict__ row_off,
                                             const int2* __restrict__ csr,
                                             const float* __restrict__ dis,
                                             const float* __restrict__ bias,
                                             float* __restrict__ out) {
    int lane = threadIdx.x & 31;
    int node = blockIdx.x * 8 + (threadIdx.x >> 5);
    if (node >= N_NODES) return;

    float dn = dis[node];
    float wself = dn * dn;
    uint2 hp = Hb[(size_t)node * 32 + lane];
    float4 a0, a1, a2, a3;
    a0.x = wself * bfl(hp.x); a0.y = wself * bfh(hp.x);
    a0.z = wself * bfl(hp.y); a0.w = wself * bfh(hp.y);
    a1 = make_float4(0.f, 0.f, 0.f, 0.f);
    a2 = a1; a3 = a1;

    int e = row_off[node], e1 = row_off[node + 1];
    for (; e + 4 <= e1; e += 4) {
        int2 q0 = csr[e];     int2 q1 = csr[e + 1];
        int2 q2 = csr[e + 2]; int2 q3 = csr[e + 3];
        uint2 g0 = Hb[(size_t)q0.x * 32 + lane];
        uint2 g1 = Hb[(size_t)q1.x * 32 + lane];
        uint2 g2 = Hb[(size_t)q2.x * 32 + lane];
        uint2 g3 = Hb[(size_t)q3.x * 32 + lane];
        float w0 = __int_as_float(q0.y), w1 = __int_as_float(q1.y);
        float w2 = __int_as_float(q2.y), w3 = __int_as_float(q3.y);
        a0.x = fmaf(w0, bfl(g0.x), a0.x); a0.y = fmaf(w0, bfh(g0.x), a0.y);
        a0.z = fmaf(w0, bfl(g0.y), a0.z); a0.w = fmaf(w0, bfh(g0.y), a0.w);
        a1.x = fmaf(w1, bfl(g1.x), a1.x); a1.y = fmaf(w1, bfh(g1.x), a1.y);
        a1.z = fmaf(w1, bfl(g1.y), a1.z); a1.w = fmaf(w1, bfh(g1.y), a1.w);
        a2.x = fmaf(w2, bfl(g2.x), a2.x); a2.y = fmaf(w2, bfh(g2.x), a2.y);
        a2.z = fmaf(w2, bfl(g2.y), a2.z); a2.w = fmaf(w2, bfh(g2.y), a2.w);
        a3.x = fmaf(w3, bfl(g3.x), a3.x); a3.y = fmaf(w3, bfh(g3.x), a3.y);
        a3.z = fmaf(w3, bfl(g3.y), a3.z); a3.w = fmaf(w3, bfh(g3.y), a3.w);
    }
    for (; e < e1; ++e) {
        int2 q = csr[e];
        uint2 g = Hb[(size_t)q.x * 32 + lane];
        float w = __int_as_float(q.y);
        a0.x = fmaf(w, bfl(g.x), a0.x); a0.y = fmaf(w, bfh(g.x), a0.y);
        a0.z = fmaf(w, bfl(g.y), a0.z); a0.w = fmaf(w, bfh(g.y), a0.w);
    }

    float4 b = ((const float4*)bias)[lane];
    float4 r;
    r.x = fmaxf(a0.x + a1.x + a2.x + a3.x + b.x, 0.f);
    r.y = fmaxf(a0.y + a1.y + a2.y + a3.y + b.y, 0.f);
    r.z = fmaxf(a0.z + a1.z + a2.z + a3.z + b.z, 0.f);
    r.w = fmaxf(a0.w + a1.w + a2.w + a3.w + b.w, 0.f);
    ((float4*)out)[(size_t)node * 32 + lane] = r;
}

// ---------------- Mean pool (parallel + ILP-4) ----------------
// 1024 blocks x 128 threads; chunk = 49 nodes/block. batch sorted, so the
// quad fast-path (g0==curg && g3==curg) covers all but ~64 boundary nodes.
__global__ __launch_bounds__(128) void k_pool(const float* __restrict__ h,
                                              const int* __restrict__ batch,
                                              float* __restrict__ pool,
                                              float* __restrict__ pcnt) {
    int chunk = (N_NODES + POOL_BLOCKS - 1) / POOL_BLOCKS;
    int n0 = blockIdx.x * chunk;
    int n1 = min(n0 + chunk, N_NODES);
    if (n0 >= n1) return;
    int c = threadIdx.x;
    int curg = batch[n0];
    float acc = 0.f;
    int count = 0;
    int n = n0;
    for (; n + 4 <= n1; ) {
        int g0 = batch[n], g3 = batch[n + 3];
        if (g0 == curg && g3 == curg) {
            float v0 = h[(size_t)(n + 0) * DIM + c];
            float v1 = h[(size_t)(n + 1) * DIM + c];
            float v2 = h[(size_t)(n + 2) * DIM + c];
            float v3 = h[(size_t)(n + 3) * DIM + c];
            acc += (v0 + v1) + (v2 + v3);
            count += 4;
            n += 4;
        } else {
            int g = g0;
            if (g != curg) {
                atomicAdd(&pool[curg * DIM + c], acc);
                if (c == 0) atomicAdd(&pcnt[curg], (float)count);
                acc = 0.f; count = 0; curg = g;
            }
            acc += h[(size_t)n * DIM + c];
            count++;
            n += 1;
        }
    }
    for (; n < n1; ++n) {
        int g = batch[n];
        if (g != curg) {
            atomicAdd(&pool[curg * DIM + c], acc);
            if (c == 0) atomicAdd(&pcnt[curg], (float)count);
            acc = 0.f; count = 0; curg = g;
        }
        acc += h[(size_t)n * DIM + c];
        count++;
    }
    atomicAdd(&pool[curg * DIM + c], acc);
    if (c == 0) atomicAdd(&pcnt[curg], (float)count);
}

// ---------------- Final FC ----------------
__global__ void k_fc(const float* __restrict__ pool, const float* __restrict__ pcnt,
                     const float* __restrict__ Wfc, const float* __restrict__ bfc,
                     float* __restrict__ out) {
    int id = blockIdx.x * blockDim.x + threadIdx.x;
    if (id >= N_GRAPHS * OUTD) return;
    int g = id >> 4, o = id & 15;
    float inv = 1.0f / fmaxf(pcnt[g], 1.0f);
    float acc = bfc[o];
    const float* p = pool + g * DIM;
    for (int c = 0; c < DIM; ++c)
        acc = fmaf(p[c] * inv, Wfc[c * OUTD + o], acc);
    out[id] = acc;
}

// ---------------- launch ----------------

extern "C" void kernel_launch(void* const* d_in, const int* in_sizes, int n_in,
                              void* d_out, int out_size, void* d_ws, size_t ws_size,
                              hipStream_t stream) {
    const float* x    = (const float*)d_in[0];
    const int*   ei   = (const int*)d_in[1];
    const int*   batch= (const int*)d_in[2];
    const float* W1   = (const float*)d_in[3];
    const float* b1   = (const float*)d_in[4];
    const float* W2   = (const float*)d_in[5];
    const float* b2   = (const float*)d_in[6];
    const float* Wfc  = (const float*)d_in[7];
    const float* bfc  = (const float*)d_in[8];
    float* out = (float*)d_out;

    char* ws = (char*)d_ws;
    size_t off = 0;
    auto alloc = [&](size_t bytes) -> char* {
        char* p = ws + off;
        off = (off + bytes + 255) & ~(size_t)255;
        return p;
    };
    int*   cnt     = (int*)  alloc((size_t)N_NODES * 4);
    int*   row_off = (int*)  alloc((size_t)(N_NODES + 1) * 4);
    int*   cursor  = (int*)  alloc((size_t)N_NODES * 4);
    float* dis     = (float*)alloc((size_t)N_NODES * 4);
    int*   bsum    = (int*)  alloc(64 * 4);
    int2*  csr     = (int2*) alloc((size_t)N_EDGES * 8);
    float* pool    = (float*)alloc((size_t)N_GRAPHS * DIM * 4);
    float* pcnt    = (float*)alloc((size_t)N_GRAPHS * 4);
    unsigned short* Hb = (unsigned short*)alloc((size_t)N_NODES * DIM * 2); // bf16
    float* F1      = (float*)alloc((size_t)N_NODES * DIM * 4);              // f32

    const int* src = ei;
    const int* dst = ei + N_EDGES;

    hipMemsetAsync(cnt,  0, (size_t)N_NODES * 4, stream);
    hipMemsetAsync(pool, 0, (size_t)N_GRAPHS * DIM * 4, stream);
    hipMemsetAsync(pcnt, 0, (size_t)N_GRAPHS * 4, stream);

    int nb = (N_NODES + 1023) / 1024;  // 49
    k_count<<<(N_EDGES + 255) / 256, 256, 0, stream>>>(dst, cnt);
    k_scan1<<<nb, 1024, 0, stream>>>(cnt, row_off, bsum);
    k_scan2<<<1, 64, 0, stream>>>(bsum, nb);
    k_scan3<<<nb, 1024, 0, stream>>>(cnt, bsum, row_off, cursor, dis);
    k_fill<<<(N_EDGES + 255) / 256, 256, 0, stream>>>(src, dst, dis, cursor, csr);

    // layer 1: gemm (f32 in, bf16 out) -> agg (bf16 gather, f32 out)
    k_gemm<<<(N_NODES + 31) / 32, 256, 0, stream>>>(x, W1, Hb, N_NODES);
    k_agg<<<(N_NODES + 7) / 8, 256, 0, stream>>>((const uint2*)Hb, row_off, csr, dis, b1, F1);
    // layer 2
    k_gemm<<<(N_NODES + 31) / 32, 256, 0, stream>>>(F1, W2, Hb, N_NODES);
    k_agg<<<(N_NODES + 7) / 8, 256, 0, stream>>>((const uint2*)Hb, row_off, csr, dis, b2, F1);
    // pool + fc
    k_pool<<<POOL_BLOCKS, DIM, 0, stream>>>(F1, batch, pool, pcnt);
    k_fc<<<(N_GRAPHS * OUTD + 255) / 256, 256, 0, stream>>>(pool, pcnt, Wfc, bfc, out);
}

// Round 4
// 327.572 us; speedup vs baseline: 1.3337x; 1.0172x over previous
//
#include <hip/hip_runtime.h>
#include <math.h>

#define N_NODES 50000
#define N_EDGES 800000
#define N_GRAPHS 64
#define DIM 128
#define OUTD 16
#define POOL_BLOCKS 1024

// ---- bf16 helpers (round-to-nearest-even; values are finite) ----
static __device__ __forceinline__ unsigned short f2bf(float f) {
    unsigned u = __float_as_uint(f);
    u += 0x7fffu + ((u >> 16) & 1u);
    return (unsigned short)(u >> 16);
}
static __device__ __forceinline__ float bfl(unsigned u) {   // low bf16 of packed pair
    return __uint_as_float(u << 16);
}
static __device__ __forceinline__ float bfh(unsigned u) {   // high bf16 of packed pair
    return __uint_as_float(u & 0xffff0000u);
}

// ---------------- CSR build ----------------

__global__ void k_count(const int* __restrict__ dst, int* __restrict__ cnt) {
    int e = blockIdx.x * blockDim.x + threadIdx.x;
    if (e < N_EDGES) atomicAdd(&cnt[dst[e]], 1);
}

__global__ void k_scan1(const int* __restrict__ cnt, int* __restrict__ excl,
                        int* __restrict__ bsum) {
    __shared__ int s[1024];
    int i = blockIdx.x * 1024 + threadIdx.x;
    int v = (i < N_NODES) ? cnt[i] : 0;
    s[threadIdx.x] = v;
    __syncthreads();
    for (int off = 1; off < 1024; off <<= 1) {
        int t = (threadIdx.x >= off) ? s[threadIdx.x - off] : 0;
        __syncthreads();
        s[threadIdx.x] += t;
        __syncthreads();
    }
    if (i < N_NODES) excl[i] = s[threadIdx.x] - v;
    if (threadIdx.x == 1023) bsum[blockIdx.x] = s[1023];
}

// single-wave exclusive scan of block sums; also zero pool/pcnt (saves 2 memsets)
__global__ void k_scan2(int* __restrict__ bsum, int nb,
                        float* __restrict__ pool, float* __restrict__ pcnt) {
    int tid = threadIdx.x;
    int v = (tid < nb) ? bsum[tid] : 0;
    int orig = v;
    for (int off = 1; off < 64; off <<= 1) {
        int t = __shfl_up(v, off);
        if (tid >= off) v += t;
    }
    if (tid < nb) bsum[tid] = v - orig;
    for (int i = tid; i < N_GRAPHS * DIM; i += 64) pool[i] = 0.f;
    if (tid < N_GRAPHS) pcnt[tid] = 0.f;
}

__global__ void k_scan3(const int* __restrict__ cnt, const int* __restrict__ bsum,
                        int* __restrict__ row_off, int* __restrict__ cursor,
                        float* __restrict__ dis) {
    int i = blockIdx.x * 1024 + threadIdx.x;
    if (i < N_NODES) {
        int ro = row_off[i] + bsum[blockIdx.x];
        row_off[i] = ro;
        cursor[i] = ro;
        dis[i] = rsqrtf((float)(cnt[i] + 1));
    }
    if (i == 0) row_off[N_NODES] = N_EDGES;
}

// CSR fill: 4B entry (src only) -> halves scatter-line traffic. 2 edges/thread.
__global__ void k_fill(const int* __restrict__ src, const int* __restrict__ dstp,
                       int* __restrict__ cursor, int* __restrict__ csr_src) {
    int t = blockIdx.x * blockDim.x + threadIdx.x;
    int e = t * 2;
    if (e + 1 < N_EDGES) {   // N_EDGES even -> always pairs
        int2 s = *(const int2*)(src + e);
        int2 d = *(const int2*)(dstp + e);
        int p0 = atomicAdd(&cursor[d.x], 1);
        int p1 = atomicAdd(&cursor[d.y], 1);
        csr_src[p0] = s.x;
        csr_src[p1] = s.y;
    }
}

// ---------------- GEMM: C[n,128](bf16) = A[n,128](f32) @ W[128,128](f32) ----
__global__ __launch_bounds__(256) void k_gemm(const float* __restrict__ A,
                                              const float* __restrict__ Wg,
                                              unsigned short* __restrict__ C,
                                              int nrows) {
    __shared__ float Wl[DIM * DIM];
    const float4* Wg4 = (const float4*)Wg;
    float4* Wl4 = (float4*)Wl;
#pragma unroll
    for (int i = 0; i < 16; ++i)
        Wl4[threadIdx.x + 256 * i] = Wg4[threadIdx.x + 256 * i];
    __syncthreads();

    int cq = threadIdx.x & 31;
    int rg = threadIdx.x >> 5;
    int r0 = blockIdx.x * 32 + rg * 4;

    const float4* A4 = (const float4*)A;
    float4 acc[4];
    int rc[4];
#pragma unroll
    for (int j = 0; j < 4; ++j) {
        acc[j] = make_float4(0.f, 0.f, 0.f, 0.f);
        int r = r0 + j;
        rc[j] = (r < nrows) ? r : 0;
    }

    for (int k = 0; k < DIM; k += 4) {
        float4 w0 = Wl4[(k + 0) * 32 + cq];
        float4 w1 = Wl4[(k + 1) * 32 + cq];
        float4 w2 = Wl4[(k + 2) * 32 + cq];
        float4 w3 = Wl4[(k + 3) * 32 + cq];
#pragma unroll
        for (int j = 0; j < 4; ++j) {
            float4 av = A4[(size_t)rc[j] * 32 + (k >> 2)];
            acc[j].x = fmaf(av.x, w0.x, fmaf(av.y, w1.x, fmaf(av.z, w2.x, fmaf(av.w, w3.x, acc[j].x))));
            acc[j].y = fmaf(av.x, w0.y, fmaf(av.y, w1.y, fmaf(av.z, w2.y, fmaf(av.w, w3.y, acc[j].y))));
            acc[j].z = fmaf(av.x, w0.z, fmaf(av.y, w1.z, fmaf(av.z, w2.z, fmaf(av.w, w3.z, acc[j].z))));
            acc[j].w = fmaf(av.x, w0.w, fmaf(av.y, w1.w, fmaf(av.z, w2.w, fmaf(av.w, w3.w, acc[j].w))));
        }
    }

    ushort4* C4 = (ushort4*)C;
#pragma unroll
    for (int j = 0; j < 4; ++j) {
        int r = r0 + j;
        if (r < nrows) {
            ushort4 o;
            o.x = f2bf(acc[j].x); o.y = f2bf(acc[j].y);
            o.z = f2bf(acc[j].z); o.w = f2bf(acc[j].w);
            C4[(size_t)r * 32 + cq] = o;
        }
    }
}

// ---------------- Aggregation (pull, bf16 gather, f32 out) ----------------
// 32 lanes/node, 4 channels (8B bf16)/lane. w = dis[src]*dis[node] computed
// on the fly (dis is L2-resident, loads lane-uniform). Unroll x4 for MLP.
__global__ __launch_bounds__(256) void k_agg(const uint2* __restrict__ Hb,
                                             const int* __restrict__ row_off,
                                             const int* __restrict__ csr_src,
                                             const float* __restrict__ dis,
                                             const float* __restrict__ bias,
                                             float* __restrict__ out) {
    int lane = threadIdx.x & 31;
    int node = blockIdx.x * 8 + (threadIdx.x >> 5);
    if (node >= N_NODES) return;

    float dn = dis[node];
    float wself = dn * dn;
    uint2 hp = Hb[(size_t)node * 32 + lane];
    float4 a0, a1, a2, a3;
    a0.x = wself * bfl(hp.x); a0.y = wself * bfh(hp.x);
    a0.z = wself * bfl(hp.y); a0.w = wself * bfh(hp.y);
    a1 = make_float4(0.f, 0.f, 0.f, 0.f);
    a2 = a1; a3 = a1;

    int e = row_off[node], e1 = row_off[node + 1];
    for (; e + 4 <= e1; e += 4) {
        int s0 = csr_src[e];     int s1 = csr_src[e + 1];
        int s2 = csr_src[e + 2]; int s3 = csr_src[e + 3];
        uint2 g0 = Hb[(size_t)s0 * 32 + lane];
        uint2 g1 = Hb[(size_t)s1 * 32 + lane];
        uint2 g2 = Hb[(size_t)s2 * 32 + lane];
        uint2 g3 = Hb[(size_t)s3 * 32 + lane];
        float w0 = dn * dis[s0], w1 = dn * dis[s1];
        float w2 = dn * dis[s2], w3 = dn * dis[s3];
        a0.x = fmaf(w0, bfl(g0.x), a0.x); a0.y = fmaf(w0, bfh(g0.x), a0.y);
        a0.z = fmaf(w0, bfl(g0.y), a0.z); a0.w = fmaf(w0, bfh(g0.y), a0.w);
        a1.x = fmaf(w1, bfl(g1.x), a1.x); a1.y = fmaf(w1, bfh(g1.x), a1.y);
        a1.z = fmaf(w1, bfl(g1.y), a1.z); a1.w = fmaf(w1, bfh(g1.y), a1.w);
        a2.x = fmaf(w2, bfl(g2.x), a2.x); a2.y = fmaf(w2, bfh(g2.x), a2.y);
        a2.z = fmaf(w2, bfl(g2.y), a2.z); a2.w = fmaf(w2, bfh(g2.y), a2.w);
        a3.x = fmaf(w3, bfl(g3.x), a3.x); a3.y = fmaf(w3, bfh(g3.x), a3.y);
        a3.z = fmaf(w3, bfl(g3.y), a3.z); a3.w = fmaf(w3, bfh(g3.y), a3.w);
    }
    for (; e < e1; ++e) {
        int s = csr_src[e];
        uint2 g = Hb[(size_t)s * 32 + lane];
        float w = dn * dis[s];
        a0.x = fmaf(w, bfl(g.x), a0.x); a0.y = fmaf(w, bfh(g.x), a0.y);
        a0.z = fmaf(w, bfl(g.y), a0.z); a0.w = fmaf(w, bfh(g.y), a0.w);
    }

    float4 b = ((const float4*)bias)[lane];
    float4 r;
    r.x = fmaxf(a0.x + a1.x + a2.x + a3.x + b.x, 0.f);
    r.y = fmaxf(a0.y + a1.y + a2.y + a3.y + b.y, 0.f);
    r.z = fmaxf(a0.z + a1.z + a2.z + a3.z + b.z, 0.f);
    r.w = fmaxf(a0.w + a1.w + a2.w + a3.w + b.w, 0.f);
    ((float4*)out)[(size_t)node * 32 + lane] = r;
}

// ---------------- Mean pool (parallel + ILP-4) ----------------
__global__ __launch_bounds__(128) void k_pool(const float* __restrict__ h,
                                              const int* __restrict__ batch,
                                              float* __restrict__ pool,
                                              float* __restrict__ pcnt) {
    int chunk = (N_NODES + POOL_BLOCKS - 1) / POOL_BLOCKS;
    int n0 = blockIdx.x * chunk;
    int n1 = min(n0 + chunk, N_NODES);
    if (n0 >= n1) return;
    int c = threadIdx.x;
    int curg = batch[n0];
    float acc = 0.f;
    int count = 0;
    int n = n0;
    for (; n + 4 <= n1; ) {
        int g0 = batch[n], g3 = batch[n + 3];
        if (g0 == curg && g3 == curg) {
            float v0 = h[(size_t)(n + 0) * DIM + c];
            float v1 = h[(size_t)(n + 1) * DIM + c];
            float v2 = h[(size_t)(n + 2) * DIM + c];
            float v3 = h[(size_t)(n + 3) * DIM + c];
            acc += (v0 + v1) + (v2 + v3);
            count += 4;
            n += 4;
        } else {
            int g = g0;
            if (g != curg) {
                atomicAdd(&pool[curg * DIM + c], acc);
                if (c == 0) atomicAdd(&pcnt[curg], (float)count);
                acc = 0.f; count = 0; curg = g;
            }
            acc += h[(size_t)n * DIM + c];
            count++;
            n += 1;
        }
    }
    for (; n < n1; ++n) {
        int g = batch[n];
        if (g != curg) {
            atomicAdd(&pool[curg * DIM + c], acc);
            if (c == 0) atomicAdd(&pcnt[curg], (float)count);
            acc = 0.f; count = 0; curg = g;
        }
        acc += h[(size_t)n * DIM + c];
        count++;
    }
    atomicAdd(&pool[curg * DIM + c], acc);
    if (c == 0) atomicAdd(&pcnt[curg], (float)count);
}

// ---------------- Final FC ----------------
__global__ void k_fc(const float* __restrict__ pool, const float* __restrict__ pcnt,
                     const float* __restrict__ Wfc, const float* __restrict__ bfc,
                     float* __restrict__ out) {
    int id = blockIdx.x * blockDim.x + threadIdx.x;
    if (id >= N_GRAPHS * OUTD) return;
    int g = id >> 4, o = id & 15;
    float inv = 1.0f / fmaxf(pcnt[g], 1.0f);
    float acc = bfc[o];
    const float* p = pool + g * DIM;
    for (int c = 0; c < DIM; ++c)
        acc = fmaf(p[c] * inv, Wfc[c * OUTD + o], acc);
    out[id] = acc;
}

// ---------------- launch ----------------

extern "C" void kernel_launch(void* const* d_in, const int* in_sizes, int n_in,
                              void* d_out, int out_size, void* d_ws, size_t ws_size,
                              hipStream_t stream) {
    const float* x    = (const float*)d_in[0];
    const int*   ei   = (const int*)d_in[1];
    const int*   batch= (const int*)d_in[2];
    const float* W1   = (const float*)d_in[3];
    const float* b1   = (const float*)d_in[4];
    const float* W2   = (const float*)d_in[5];
    const float* b2   = (const float*)d_in[6];
    const float* Wfc  = (const float*)d_in[7];
    const float* bfc  = (const float*)d_in[8];
    float* out = (float*)d_out;

    char* ws = (char*)d_ws;
    size_t off = 0;
    auto alloc = [&](size_t bytes) -> char* {
        char* p = ws + off;
        off = (off + bytes + 255) & ~(size_t)255;
        return p;
    };
    int*   cnt     = (int*)  alloc((size_t)N_NODES * 4);
    int*   row_off = (int*)  alloc((size_t)(N_NODES + 1) * 4);
    int*   cursor  = (int*)  alloc((size_t)N_NODES * 4);
    float* dis     = (float*)alloc((size_t)N_NODES * 4);
    int*   bsum    = (int*)  alloc(64 * 4);
    int*   csr_src = (int*)  alloc((size_t)N_EDGES * 4);
    float* pool    = (float*)alloc((size_t)N_GRAPHS * DIM * 4);
    float* pcnt    = (float*)alloc((size_t)N_GRAPHS * 4);
    unsigned short* Hb = (unsigned short*)alloc((size_t)N_NODES * DIM * 2); // bf16
    float* F1      = (float*)alloc((size_t)N_NODES * DIM * 4);              // f32

    const int* src = ei;
    const int* dst = ei + N_EDGES;

    hipMemsetAsync(cnt, 0, (size_t)N_NODES * 4, stream);

    int nb = (N_NODES + 1023) / 1024;  // 49
    k_count<<<(N_EDGES + 255) / 256, 256, 0, stream>>>(dst, cnt);
    k_scan1<<<nb, 1024, 0, stream>>>(cnt, row_off, bsum);
    k_scan2<<<1, 64, 0, stream>>>(bsum, nb, pool, pcnt);
    k_scan3<<<nb, 1024, 0, stream>>>(cnt, bsum, row_off, cursor, dis);
    k_fill<<<(N_EDGES / 2 + 255) / 256, 256, 0, stream>>>(src, dst, cursor, csr_src);

    // layer 1: gemm (f32 in, bf16 out) -> agg (bf16 gather, f32 out)
    k_gemm<<<(N_NODES + 31) / 32, 256, 0, stream>>>(x, W1, Hb, N_NODES);
    k_agg<<<(N_NODES + 7) / 8, 256, 0, stream>>>((const uint2*)Hb, row_off, csr_src, dis, b1, F1);
    // layer 2
    k_gemm<<<(N_NODES + 31) / 32, 256, 0, stream>>>(F1, W2, Hb, N_NODES);
    k_agg<<<(N_NODES + 7) / 8, 256, 0, stream>>>((const uint2*)Hb, row_off, csr_src, dis, b2, F1);
    // pool + fc
    k_pool<<<POOL_BLOCKS, DIM, 0, stream>>>(F1, batch, pool, pcnt);
    k_fc<<<(N_GRAPHS * OUTD + 255) / 256, 256, 0, stream>>>(pool, pcnt, Wfc, bfc, out);
}

// Round 5
// 312.184 us; speedup vs baseline: 1.3994x; 1.0493x over previous
//
#include <hip/hip_runtime.h>
#include <math.h>

#define N_NODES 50000
#define N_EDGES 800000
#define N_GRAPHS 64
#define DIM 128
#define OUTD 16
#define POOL_BLOCKS 1024

// bucketed CSR build: 256 nodes per bucket
#define BSHIFT 8
#define BNODES 256
#define NBUCK ((N_NODES + BNODES - 1) / BNODES)   // 196
#define TILE 2048                                  // edges per k_binA block
#define RCAP 8192                                  // LDS stage capacity (entries)

// ---- bf16 helpers (round-to-nearest-even; values are finite) ----
static __device__ __forceinline__ unsigned short f2bf(float f) {
    unsigned u = __float_as_uint(f);
    u += 0x7fffu + ((u >> 16) & 1u);
    return (unsigned short)(u >> 16);
}
static __device__ __forceinline__ float bfl(unsigned u) {
    return __uint_as_float(u << 16);
}
static __device__ __forceinline__ float bfh(unsigned u) {
    return __uint_as_float(u & 0xffff0000u);
}

// ---------------- degree count + scan ----------------

__global__ void k_count(const int* __restrict__ dst, int* __restrict__ cnt) {
    int e = blockIdx.x * blockDim.x + threadIdx.x;
    if (e < N_EDGES) atomicAdd(&cnt[dst[e]], 1);
}

__global__ void k_scan1(const int* __restrict__ cnt, int* __restrict__ excl,
                        int* __restrict__ bsum) {
    __shared__ int s[1024];
    int i = blockIdx.x * 1024 + threadIdx.x;
    int v = (i < N_NODES) ? cnt[i] : 0;
    s[threadIdx.x] = v;
    __syncthreads();
    for (int off = 1; off < 1024; off <<= 1) {
        int t = (threadIdx.x >= off) ? s[threadIdx.x - off] : 0;
        __syncthreads();
        s[threadIdx.x] += t;
        __syncthreads();
    }
    if (i < N_NODES) excl[i] = s[threadIdx.x] - v;
    if (threadIdx.x == 1023) bsum[blockIdx.x] = s[1023];
}

// single-wave exclusive scan of block sums; also zero pool/pcnt
__global__ void k_scan2(int* __restrict__ bsum, int nb,
                        float* __restrict__ pool, float* __restrict__ pcnt) {
    int tid = threadIdx.x;
    int v = (tid < nb) ? bsum[tid] : 0;
    int orig = v;
    for (int off = 1; off < 64; off <<= 1) {
        int t = __shfl_up(v, off);
        if (tid >= off) v += t;
    }
    if (tid < nb) bsum[tid] = v - orig;
    for (int i = tid; i < N_GRAPHS * DIM; i += 64) pool[i] = 0.f;
    if (tid < N_GRAPHS) pcnt[tid] = 0.f;
}

// finalize row_off, seed per-bucket cursors (= region bases), emit dis
__global__ void k_scan3(const int* __restrict__ cnt, const int* __restrict__ bsum,
                        int* __restrict__ row_off, int* __restrict__ bucket_cursor,
                        float* __restrict__ dis) {
    int i = blockIdx.x * 1024 + threadIdx.x;
    if (i < N_NODES) {
        int ro = row_off[i] + bsum[blockIdx.x];
        row_off[i] = ro;
        if ((i & (BNODES - 1)) == 0) bucket_cursor[i >> BSHIFT] = ro;
        dis[i] = rsqrtf((float)(cnt[i] + 1));
    }
    if (i == 0) row_off[N_NODES] = N_EDGES;
}

// ---------------- Pass A: bin edges into coarse dst-buckets ----------------
// Tile of 2048 edges: LDS count per bucket -> one global atomicAdd per
// (block,bucket) -> scatter (src,dst) pairs; same-bucket entries contiguous.
__global__ __launch_bounds__(256) void k_binA(const int* __restrict__ src,
                                              const int* __restrict__ dstp,
                                              int* __restrict__ bucket_cursor,
                                              int2* __restrict__ bucket_arr) {
    __shared__ int cnt[NBUCK];
    __shared__ int base[NBUCK];
    int tile0 = blockIdx.x * TILE;
    for (int i = threadIdx.x; i < NBUCK; i += 256) cnt[i] = 0;
    __syncthreads();
#pragma unroll
    for (int j = 0; j < TILE / 256; ++j) {
        int e = tile0 + j * 256 + threadIdx.x;
        if (e < N_EDGES) atomicAdd(&cnt[dstp[e] >> BSHIFT], 1);
    }
    __syncthreads();
    for (int i = threadIdx.x; i < NBUCK; i += 256) {
        int c = cnt[i];
        base[i] = c ? atomicAdd(&bucket_cursor[i], c) : 0;
        cnt[i] = 0;   // reuse as local cursor
    }
    __syncthreads();
#pragma unroll
    for (int j = 0; j < TILE / 256; ++j) {
        int e = tile0 + j * 256 + threadIdx.x;
        if (e < N_EDGES) {
            int d = dstp[e];
            int b = d >> BSHIFT;
            int p = base[b] + atomicAdd(&cnt[b], 1);
            bucket_arr[p] = make_int2(src[e], d);
        }
    }
}

// ---------------- Pass B: fine scatter within bucket via LDS --------------
// Block = bucket. Region [row_off[n0], row_off[n1]) in both bucket_arr (input
// order) and csr_src (final). LDS cursors seeded from row_off; staged scatter
// in LDS; coalesced write-out.
__global__ __launch_bounds__(256) void k_binB(const int2* __restrict__ bucket_arr,
                                              const int* __restrict__ row_off,
                                              int* __restrict__ csr_src) {
    __shared__ int stage[RCAP];
    __shared__ int cur[BNODES];
    int n0 = blockIdx.x << BSHIFT;
    int n1 = min(n0 + BNODES, N_NODES);
    int rbase = row_off[n0];
    int len = row_off[n1] - rbase;
    for (int i = threadIdx.x; i < n1 - n0; i += 256)
        cur[i] = row_off[n0 + i] - rbase;
    __syncthreads();
    for (int i = threadIdx.x; i < len; i += 256) {
        int2 ed = bucket_arr[rbase + i];
        int p = atomicAdd(&cur[ed.y - n0], 1);
        if (p < RCAP) stage[p] = ed.x;
        else csr_src[rbase + p] = ed.x;   // overflow fallback (never in practice)
    }
    __syncthreads();
    int lim = min(len, RCAP);
    for (int i = threadIdx.x; i < lim; i += 256)
        csr_src[rbase + i] = stage[i];
}

// ---------------- GEMM: C[n,128](bf16) = A[n,128](f32) @ W[128,128](f32) ----
__global__ __launch_bounds__(256) void k_gemm(const float* __restrict__ A,
                                              const float* __restrict__ Wg,
                                              unsigned short* __restrict__ C,
                                              int nrows) {
    __shared__ float Wl[DIM * DIM];
    const float4* Wg4 = (const float4*)Wg;
    float4* Wl4 = (float4*)Wl;
#pragma unroll
    for (int i = 0; i < 16; ++i)
        Wl4[threadIdx.x + 256 * i] = Wg4[threadIdx.x + 256 * i];
    __syncthreads();

    int cq = threadIdx.x & 31;
    int rg = threadIdx.x >> 5;
    int r0 = blockIdx.x * 32 + rg * 4;

    const float4* A4 = (const float4*)A;
    float4 acc[4];
    int rc[4];
#pragma unroll
    for (int j = 0; j < 4; ++j) {
        acc[j] = make_float4(0.f, 0.f, 0.f, 0.f);
        int r = r0 + j;
        rc[j] = (r < nrows) ? r : 0;
    }

    for (int k = 0; k < DIM; k += 4) {
        float4 w0 = Wl4[(k + 0) * 32 + cq];
        float4 w1 = Wl4[(k + 1) * 32 + cq];
        float4 w2 = Wl4[(k + 2) * 32 + cq];
        float4 w3 = Wl4[(k + 3) * 32 + cq];
#pragma unroll
        for (int j = 0; j < 4; ++j) {
            float4 av = A4[(size_t)rc[j] * 32 + (k >> 2)];
            acc[j].x = fmaf(av.x, w0.x, fmaf(av.y, w1.x, fmaf(av.z, w2.x, fmaf(av.w, w3.x, acc[j].x))));
            acc[j].y = fmaf(av.x, w0.y, fmaf(av.y, w1.y, fmaf(av.z, w2.y, fmaf(av.w, w3.y, acc[j].y))));
            acc[j].z = fmaf(av.x, w0.z, fmaf(av.y, w1.z, fmaf(av.z, w2.z, fmaf(av.w, w3.z, acc[j].z))));
            acc[j].w = fmaf(av.x, w0.w, fmaf(av.y, w1.w, fmaf(av.z, w2.w, fmaf(av.w, w3.w, acc[j].w))));
        }
    }

    ushort4* C4 = (ushort4*)C;
#pragma unroll
    for (int j = 0; j < 4; ++j) {
        int r = r0 + j;
        if (r < nrows) {
            ushort4 o;
            o.x = f2bf(acc[j].x); o.y = f2bf(acc[j].y);
            o.z = f2bf(acc[j].z); o.w = f2bf(acc[j].w);
            C4[(size_t)r * 32 + cq] = o;
        }
    }
}

// ---------------- Aggregation (pull, bf16 gather, f32 out) ----------------
__global__ __launch_bounds__(256) void k_agg(const uint2* __restrict__ Hb,
                                             const int* __restrict__ row_off,
                                             const int* __restrict__ csr_src,
                                             const float* __restrict__ dis,
                                             const float* __restrict__ bias,
                                             float* __restrict__ out) {
    int lane = threadIdx.x & 31;
    int node = blockIdx.x * 8 + (threadIdx.x >> 5);
    if (node >= N_NODES) return;

    float dn = dis[node];
    float wself = dn * dn;
    uint2 hp = Hb[(size_t)node * 32 + lane];
    float4 a0, a1, a2, a3;
    a0.x = wself * bfl(hp.x); a0.y = wself * bfh(hp.x);
    a0.z = wself * bfl(hp.y); a0.w = wself * bfh(hp.y);
    a1 = make_float4(0.f, 0.f, 0.f, 0.f);
    a2 = a1; a3 = a1;

    int e = row_off[node], e1 = row_off[node + 1];
    for (; e + 4 <= e1; e += 4) {
        int s0 = csr_src[e];     int s1 = csr_src[e + 1];
        int s2 = csr_src[e + 2]; int s3 = csr_src[e + 3];
        uint2 g0 = Hb[(size_t)s0 * 32 + lane];
        uint2 g1 = Hb[(size_t)s1 * 32 + lane];
        uint2 g2 = Hb[(size_t)s2 * 32 + lane];
        uint2 g3 = Hb[(size_t)s3 * 32 + lane];
        float w0 = dn * dis[s0], w1 = dn * dis[s1];
        float w2 = dn * dis[s2], w3 = dn * dis[s3];
        a0.x = fmaf(w0, bfl(g0.x), a0.x); a0.y = fmaf(w0, bfh(g0.x), a0.y);
        a0.z = fmaf(w0, bfl(g0.y), a0.z); a0.w = fmaf(w0, bfh(g0.y), a0.w);
        a1.x = fmaf(w1, bfl(g1.x), a1.x); a1.y = fmaf(w1, bfh(g1.x), a1.y);
        a1.z = fmaf(w1, bfl(g1.y), a1.z); a1.w = fmaf(w1, bfh(g1.y), a1.w);
        a2.x = fmaf(w2, bfl(g2.x), a2.x); a2.y = fmaf(w2, bfh(g2.x), a2.y);
        a2.z = fmaf(w2, bfl(g2.y), a2.z); a2.w = fmaf(w2, bfh(g2.y), a2.w);
        a3.x = fmaf(w3, bfl(g3.x), a3.x); a3.y = fmaf(w3, bfh(g3.x), a3.y);
        a3.z = fmaf(w3, bfl(g3.y), a3.z); a3.w = fmaf(w3, bfh(g3.y), a3.w);
    }
    for (; e < e1; ++e) {
        int s = csr_src[e];
        uint2 g = Hb[(size_t)s * 32 + lane];
        float w = dn * dis[s];
        a0.x = fmaf(w, bfl(g.x), a0.x); a0.y = fmaf(w, bfh(g.x), a0.y);
        a0.z = fmaf(w, bfl(g.y), a0.z); a0.w = fmaf(w, bfh(g.y), a0.w);
    }

    float4 b = ((const float4*)bias)[lane];
    float4 r;
    r.x = fmaxf(a0.x + a1.x + a2.x + a3.x + b.x, 0.f);
    r.y = fmaxf(a0.y + a1.y + a2.y + a3.y + b.y, 0.f);
    r.z = fmaxf(a0.z + a1.z + a2.z + a3.z + b.z, 0.f);
    r.w = fmaxf(a0.w + a1.w + a2.w + a3.w + b.w, 0.f);
    ((float4*)out)[(size_t)node * 32 + lane] = r;
}

// ---------------- Mean pool (parallel + ILP-4) ----------------
__global__ __launch_bounds__(128) void k_pool(const float* __restrict__ h,
                                              const int* __restrict__ batch,
                                              float* __restrict__ pool,
                                              float* __restrict__ pcnt) {
    int chunk = (N_NODES + POOL_BLOCKS - 1) / POOL_BLOCKS;
    int n0 = blockIdx.x * chunk;
    int n1 = min(n0 + chunk, N_NODES);
    if (n0 >= n1) return;
    int c = threadIdx.x;
    int curg = batch[n0];
    float acc = 0.f;
    int count = 0;
    int n = n0;
    for (; n + 4 <= n1; ) {
        int g0 = batch[n], g3 = batch[n + 3];
        if (g0 == curg && g3 == curg) {
            float v0 = h[(size_t)(n + 0) * DIM + c];
            float v1 = h[(size_t)(n + 1) * DIM + c];
            float v2 = h[(size_t)(n + 2) * DIM + c];
            float v3 = h[(size_t)(n + 3) * DIM + c];
            acc += (v0 + v1) + (v2 + v3);
            count += 4;
            n += 4;
        } else {
            int g = g0;
            if (g != curg) {
                atomicAdd(&pool[curg * DIM + c], acc);
                if (c == 0) atomicAdd(&pcnt[curg], (float)count);
                acc = 0.f; count = 0; curg = g;
            }
            acc += h[(size_t)n * DIM + c];
            count++;
            n += 1;
        }
    }
    for (; n < n1; ++n) {
        int g = batch[n];
        if (g != curg) {
            atomicAdd(&pool[curg * DIM + c], acc);
            if (c == 0) atomicAdd(&pcnt[curg], (float)count);
            acc = 0.f; count = 0; curg = g;
        }
        acc += h[(size_t)n * DIM + c];
        count++;
    }
    atomicAdd(&pool[curg * DIM + c], acc);
    if (c == 0) atomicAdd(&pcnt[curg], (float)count);
}

// ---------------- Final FC ----------------
__global__ void k_fc(const float* __restrict__ pool, const float* __restrict__ pcnt,
                     const float* __restrict__ Wfc, const float* __restrict__ bfc,
                     float* __restrict__ out) {
    int id = blockIdx.x * blockDim.x + threadIdx.x;
    if (id >= N_GRAPHS * OUTD) return;
    int g = id >> 4, o = id & 15;
    float inv = 1.0f / fmaxf(pcnt[g], 1.0f);
    float acc = bfc[o];
    const float* p = pool + g * DIM;
    for (int c = 0; c < DIM; ++c)
        acc = fmaf(p[c] * inv, Wfc[c * OUTD + o], acc);
    out[id] = acc;
}

// ---------------- launch ----------------

extern "C" void kernel_launch(void* const* d_in, const int* in_sizes, int n_in,
                              void* d_out, int out_size, void* d_ws, size_t ws_size,
                              hipStream_t stream) {
    const float* x    = (const float*)d_in[0];
    const int*   ei   = (const int*)d_in[1];
    const int*   batch= (const int*)d_in[2];
    const float* W1   = (const float*)d_in[3];
    const float* b1   = (const float*)d_in[4];
    const float* W2   = (const float*)d_in[5];
    const float* b2   = (const float*)d_in[6];
    const float* Wfc  = (const float*)d_in[7];
    const float* bfc  = (const float*)d_in[8];
    float* out = (float*)d_out;

    char* ws = (char*)d_ws;
    size_t off = 0;
    auto alloc = [&](size_t bytes) -> char* {
        char* p = ws + off;
        off = (off + bytes + 255) & ~(size_t)255;
        return p;
    };
    int*   cnt      = (int*)  alloc((size_t)N_NODES * 4);
    int*   row_off  = (int*)  alloc((size_t)(N_NODES + 1) * 4);
    int*   bcursor  = (int*)  alloc((size_t)NBUCK * 4);
    float* dis      = (float*)alloc((size_t)N_NODES * 4);
    int*   bsum     = (int*)  alloc(64 * 4);
    int*   csr_src  = (int*)  alloc((size_t)N_EDGES * 4);
    int2*  barr     = (int2*) alloc((size_t)N_EDGES * 8);
    float* pool     = (float*)alloc((size_t)N_GRAPHS * DIM * 4);
    float* pcnt     = (float*)alloc((size_t)N_GRAPHS * 4);
    unsigned short* Hb = (unsigned short*)alloc((size_t)N_NODES * DIM * 2);
    float* F1       = (float*)alloc((size_t)N_NODES * DIM * 4);

    const int* src = ei;
    const int* dst = ei + N_EDGES;

    hipMemsetAsync(cnt, 0, (size_t)N_NODES * 4, stream);

    int nb = (N_NODES + 1023) / 1024;  // 49
    k_count<<<(N_EDGES + 255) / 256, 256, 0, stream>>>(dst, cnt);
    k_scan1<<<nb, 1024, 0, stream>>>(cnt, row_off, bsum);
    k_scan2<<<1, 64, 0, stream>>>(bsum, nb, pool, pcnt);
    k_scan3<<<nb, 1024, 0, stream>>>(cnt, bsum, row_off, bcursor, dis);
    k_binA<<<(N_EDGES + TILE - 1) / TILE, 256, 0, stream>>>(src, dst, bcursor, barr);
    k_binB<<<NBUCK, 256, 0, stream>>>(barr, row_off, csr_src);

    // layer 1
    k_gemm<<<(N_NODES + 31) / 32, 256, 0, stream>>>(x, W1, Hb, N_NODES);
    k_agg<<<(N_NODES + 7) / 8, 256, 0, stream>>>((const uint2*)Hb, row_off, csr_src, dis, b1, F1);
    // layer 2
    k_gemm<<<(N_NODES + 31) / 32, 256, 0, stream>>>(F1, W2, Hb, N_NODES);
    k_agg<<<(N_NODES + 7) / 8, 256, 0, stream>>>((const uint2*)Hb, row_off, csr_src, dis, b2, F1);
    // pool + fc
    k_pool<<<POOL_BLOCKS, DIM, 0, stream>>>(F1, batch, pool, pcnt);
    k_fc<<<(N_GRAPHS * OUTD + 255) / 256, 256, 0, stream>>>(pool, pcnt, Wfc, bfc, out);
}

// Round 6
// 282.449 us; speedup vs baseline: 1.5468x; 1.1053x over previous
//
#include <hip/hip_runtime.h>
#include <math.h>

#define N_NODES 50000
#define N_EDGES 800000
#define N_GRAPHS 64
#define DIM 128
#define OUTD 16
#define POOL_BLOCKS 1024

// bucketed CSR build: 256 nodes per bucket
#define BSHIFT 8
#define BNODES 256
#define NBUCK ((N_NODES + BNODES - 1) / BNODES)   // 196
#define TILE 2048                                  // edges per k_binA block
#define RCAP 8192                                  // LDS stage capacity (entries)

typedef __attribute__((ext_vector_type(8))) short short8;
typedef __attribute__((ext_vector_type(4))) float f32x4;

// ---- bf16 helpers (round-to-nearest-even; values are finite) ----
static __device__ __forceinline__ unsigned short f2bf(float f) {
    unsigned u = __float_as_uint(f);
    u += 0x7fffu + ((u >> 16) & 1u);
    return (unsigned short)(u >> 16);
}
static __device__ __forceinline__ float bfl(unsigned u) {
    return __uint_as_float(u << 16);
}
static __device__ __forceinline__ float bfh(unsigned u) {
    return __uint_as_float(u & 0xffff0000u);
}

// ---------------- degree count + scan ----------------

__global__ void k_count(const int* __restrict__ dst, int* __restrict__ cnt) {
    int e = blockIdx.x * blockDim.x + threadIdx.x;
    if (e < N_EDGES) atomicAdd(&cnt[dst[e]], 1);
}

__global__ void k_scan1(const int* __restrict__ cnt, int* __restrict__ excl,
                        int* __restrict__ bsum) {
    __shared__ int s[1024];
    int i = blockIdx.x * 1024 + threadIdx.x;
    int v = (i < N_NODES) ? cnt[i] : 0;
    s[threadIdx.x] = v;
    __syncthreads();
    for (int off = 1; off < 1024; off <<= 1) {
        int t = (threadIdx.x >= off) ? s[threadIdx.x - off] : 0;
        __syncthreads();
        s[threadIdx.x] += t;
        __syncthreads();
    }
    if (i < N_NODES) excl[i] = s[threadIdx.x] - v;
    if (threadIdx.x == 1023) bsum[blockIdx.x] = s[1023];
}

// single-wave exclusive scan of block sums; also zero pool/pcnt
__global__ void k_scan2(int* __restrict__ bsum, int nb,
                        float* __restrict__ pool, float* __restrict__ pcnt) {
    int tid = threadIdx.x;
    int v = (tid < nb) ? bsum[tid] : 0;
    int orig = v;
    for (int off = 1; off < 64; off <<= 1) {
        int t = __shfl_up(v, off);
        if (tid >= off) v += t;
    }
    if (tid < nb) bsum[tid] = v - orig;
    for (int i = tid; i < N_GRAPHS * DIM; i += 64) pool[i] = 0.f;
    if (tid < N_GRAPHS) pcnt[tid] = 0.f;
}

// finalize row_off, seed per-bucket cursors (= region bases), emit dis
__global__ void k_scan3(const int* __restrict__ cnt, const int* __restrict__ bsum,
                        int* __restrict__ row_off, int* __restrict__ bucket_cursor,
                        float* __restrict__ dis) {
    int i = blockIdx.x * 1024 + threadIdx.x;
    if (i < N_NODES) {
        int ro = row_off[i] + bsum[blockIdx.x];
        row_off[i] = ro;
        if ((i & (BNODES - 1)) == 0) bucket_cursor[i >> BSHIFT] = ro;
        dis[i] = rsqrtf((float)(cnt[i] + 1));
    }
    if (i == 0) row_off[N_NODES] = N_EDGES;
}

// ---------------- Pass A: bin edges into coarse dst-buckets ----------------
__global__ __launch_bounds__(256) void k_binA(const int* __restrict__ src,
                                              const int* __restrict__ dstp,
                                              int* __restrict__ bucket_cursor,
                                              int2* __restrict__ bucket_arr) {
    __shared__ int cnt[NBUCK];
    __shared__ int base[NBUCK];
    int tile0 = blockIdx.x * TILE;
    for (int i = threadIdx.x; i < NBUCK; i += 256) cnt[i] = 0;
    __syncthreads();
#pragma unroll
    for (int j = 0; j < TILE / 256; ++j) {
        int e = tile0 + j * 256 + threadIdx.x;
        if (e < N_EDGES) atomicAdd(&cnt[dstp[e] >> BSHIFT], 1);
    }
    __syncthreads();
    for (int i = threadIdx.x; i < NBUCK; i += 256) {
        int c = cnt[i];
        base[i] = c ? atomicAdd(&bucket_cursor[i], c) : 0;
        cnt[i] = 0;   // reuse as local cursor
    }
    __syncthreads();
#pragma unroll
    for (int j = 0; j < TILE / 256; ++j) {
        int e = tile0 + j * 256 + threadIdx.x;
        if (e < N_EDGES) {
            int d = dstp[e];
            int b = d >> BSHIFT;
            int p = base[b] + atomicAdd(&cnt[b], 1);
            bucket_arr[p] = make_int2(src[e], d);
        }
    }
}

// ---------------- Pass B: fine scatter within bucket via LDS --------------
__global__ __launch_bounds__(256) void k_binB(const int2* __restrict__ bucket_arr,
                                              const int* __restrict__ row_off,
                                              int* __restrict__ csr_src) {
    __shared__ int stage[RCAP];
    __shared__ int cur[BNODES];
    int n0 = blockIdx.x << BSHIFT;
    int n1 = min(n0 + BNODES, N_NODES);
    int rbase = row_off[n0];
    int len = row_off[n1] - rbase;
    for (int i = threadIdx.x; i < n1 - n0; i += 256)
        cur[i] = row_off[n0 + i] - rbase;
    __syncthreads();
    for (int i = threadIdx.x; i < len; i += 256) {
        int2 ed = bucket_arr[rbase + i];
        int p = atomicAdd(&cur[ed.y - n0], 1);
        if (p < RCAP) stage[p] = ed.x;
        else csr_src[rbase + p] = ed.x;
    }
    __syncthreads();
    int lim = min(len, RCAP);
    for (int i = threadIdx.x; i < lim; i += 256)
        csr_src[rbase + i] = stage[i];
}

// ---------------- MFMA GEMM: C[n,128](bf16) = A[n,128](f32) @ W[128,128](f32)
// Block = 4 waves = 64 rows. W staged once per block into LDS in B-fragment
// order: entry (kstep,ct,lane) = 16B short8 holding W[k0+quad*8+j][ct*16+(lane&15)]
// (quad=lane>>4, j=0..7). Wave computes 16 rows x 128 cols via 4x8 MFMAs.
__global__ __launch_bounds__(256) void k_gemm(const float* __restrict__ A,
                                              const float* __restrict__ Wg,
                                              unsigned short* __restrict__ C,
                                              int nrows) {
    __shared__ unsigned int Wl[DIM * DIM / 2];   // 32 KB (bf16 pairs)
    {
        // thread t: k-pair p = t&63 (kp=2p), n-half per wave nq = t>>6 (32 n's).
        // n-block rotation by (p>>2) keeps LDS write conflicts at 2-way (free).
        int t = threadIdx.x;
        int p = t & 63;
        int kp = p * 2;
        int n0 = (t >> 6) * 32;
        int kstep = kp >> 5;
        int quad = (kp >> 3) & 3;
        int jw = (kp & 7) >> 1;              // word offset within 16B entry
        const float* r0 = Wg + (size_t)kp * DIM;
        const float* r1 = r0 + DIM;
        int rot = (p >> 2) & 7;
#pragma unroll
        for (int i4 = 0; i4 < 8; ++i4) {
            int nb = ((i4 + rot) & 7) * 4;   // n-block within the 32-n half
            int n = n0 + nb;
            float4 lo = *(const float4*)(r0 + n);
            float4 hi = *(const float4*)(r1 + n);
            const float* lp = &lo.x;
            const float* hp = &hi.x;
#pragma unroll
            for (int ii = 0; ii < 4; ++ii) {
                int nn = n + ii;
                int ct = nn >> 4;
                int l  = quad * 16 + (nn & 15);
                unsigned vlo = f2bf(lp[ii]);
                unsigned vhi = f2bf(hp[ii]);
                Wl[(((kstep * 8 + ct) * 64) + l) * 4 + jw] = vlo | (vhi << 16);
            }
        }
    }
    __syncthreads();

    int wid  = threadIdx.x >> 6;
    int lane = threadIdx.x & 63;
    int row0 = blockIdx.x * 64 + wid * 16;
    if (row0 >= nrows) return;     // 16 | N_NODES -> waves fully valid or skipped

    int m = lane & 15;
    int quad = lane >> 4;
    const float* arow = A + (size_t)(row0 + m) * DIM + quad * 8;

    short8 afrag[4];
#pragma unroll
    for (int ks = 0; ks < 4; ++ks) {
        float4 lo = *(const float4*)(arow + ks * 32);
        float4 hi = *(const float4*)(arow + ks * 32 + 4);
        short8 f;
        f[0] = (short)f2bf(lo.x); f[1] = (short)f2bf(lo.y);
        f[2] = (short)f2bf(lo.z); f[3] = (short)f2bf(lo.w);
        f[4] = (short)f2bf(hi.x); f[5] = (short)f2bf(hi.y);
        f[6] = (short)f2bf(hi.z); f[7] = (short)f2bf(hi.w);
        afrag[ks] = f;
    }

    f32x4 acc[8];
#pragma unroll
    for (int ct = 0; ct < 8; ++ct) acc[ct] = (f32x4){0.f, 0.f, 0.f, 0.f};

    const short8* Wf = (const short8*)Wl;    // one entry = 16B
#pragma unroll
    for (int ks = 0; ks < 4; ++ks) {
#pragma unroll
        for (int ct = 0; ct < 8; ++ct) {
            short8 b = Wf[(ks * 8 + ct) * 64 + lane];
            acc[ct] = __builtin_amdgcn_mfma_f32_16x16x32_bf16(afrag[ks], b, acc[ct], 0, 0, 0);
        }
    }

    // C/D layout: row = quad*4 + reg, col = ct*16 + m
    unsigned short* crow = C + (size_t)row0 * DIM;
#pragma unroll
    for (int ct = 0; ct < 8; ++ct) {
#pragma unroll
        for (int reg = 0; reg < 4; ++reg) {
            crow[(size_t)(quad * 4 + reg) * DIM + ct * 16 + m] = f2bf(acc[ct][reg]);
        }
    }
}

// ---------------- Aggregation (pull, bf16 gather, f32 out) ----------------
__global__ __launch_bounds__(256) void k_agg(const uint2* __restrict__ Hb,
                                             const int* __restrict__ row_off,
                                             const int* __restrict__ csr_src,
                                             const float* __restrict__ dis,
                                             const float* __restrict__ bias,
                                             float* __restrict__ out) {
    int lane = threadIdx.x & 31;
    int node = blockIdx.x * 8 + (threadIdx.x >> 5);
    if (node >= N_NODES) return;

    float dn = dis[node];
    float wself = dn * dn;
    uint2 hp = Hb[(size_t)node * 32 + lane];
    float4 a0, a1, a2, a3;
    a0.x = wself * bfl(hp.x); a0.y = wself * bfh(hp.x);
    a0.z = wself * bfl(hp.y); a0.w = wself * bfh(hp.y);
    a1 = make_float4(0.f, 0.f, 0.f, 0.f);
    a2 = a1; a3 = a1;

    int e = row_off[node], e1 = row_off[node + 1];
    for (; e + 4 <= e1; e += 4) {
        int s0 = csr_src[e];     int s1 = csr_src[e + 1];
        int s2 = csr_src[e + 2]; int s3 = csr_src[e + 3];
        uint2 g0 = Hb[(size_t)s0 * 32 + lane];
        uint2 g1 = Hb[(size_t)s1 * 32 + lane];
        uint2 g2 = Hb[(size_t)s2 * 32 + lane];
        uint2 g3 = Hb[(size_t)s3 * 32 + lane];
        float w0 = dn * dis[s0], w1 = dn * dis[s1];
        float w2 = dn * dis[s2], w3 = dn * dis[s3];
        a0.x = fmaf(w0, bfl(g0.x), a0.x); a0.y = fmaf(w0, bfh(g0.x), a0.y);
        a0.z = fmaf(w0, bfl(g0.y), a0.z); a0.w = fmaf(w0, bfh(g0.y), a0.w);
        a1.x = fmaf(w1, bfl(g1.x), a1.x); a1.y = fmaf(w1, bfh(g1.x), a1.y);
        a1.z = fmaf(w1, bfl(g1.y), a1.z); a1.w = fmaf(w1, bfh(g1.y), a1.w);
        a2.x = fmaf(w2, bfl(g2.x), a2.x); a2.y = fmaf(w2, bfh(g2.x), a2.y);
        a2.z = fmaf(w2, bfl(g2.y), a2.z); a2.w = fmaf(w2, bfh(g2.y), a2.w);
        a3.x = fmaf(w3, bfl(g3.x), a3.x); a3.y = fmaf(w3, bfh(g3.x), a3.y);
        a3.z = fmaf(w3, bfl(g3.y), a3.z); a3.w = fmaf(w3, bfh(g3.y), a3.w);
    }
    for (; e < e1; ++e) {
        int s = csr_src[e];
        uint2 g = Hb[(size_t)s * 32 + lane];
        float w = dn * dis[s];
        a0.x = fmaf(w, bfl(g.x), a0.x); a0.y = fmaf(w, bfh(g.x), a0.y);
        a0.z = fmaf(w, bfl(g.y), a0.z); a0.w = fmaf(w, bfh(g.y), a0.w);
    }

    float4 b = ((const float4*)bias)[lane];
    float4 r;
    r.x = fmaxf(a0.x + a1.x + a2.x + a3.x + b.x, 0.f);
    r.y = fmaxf(a0.y + a1.y + a2.y + a3.y + b.y, 0.f);
    r.z = fmaxf(a0.z + a1.z + a2.z + a3.z + b.z, 0.f);
    r.w = fmaxf(a0.w + a1.w + a2.w + a3.w + b.w, 0.f);
    ((float4*)out)[(size_t)node * 32 + lane] = r;
}

// ---------------- Mean pool (parallel + ILP-4) ----------------
__global__ __launch_bounds__(128) void k_pool(const float* __restrict__ h,
                                              const int* __restrict__ batch,
                                              float* __restrict__ pool,
                                              float* __restrict__ pcnt) {
    int chunk = (N_NODES + POOL_BLOCKS - 1) / POOL_BLOCKS;
    int n0 = blockIdx.x * chunk;
    int n1 = min(n0 + chunk, N_NODES);
    if (n0 >= n1) return;
    int c = threadIdx.x;
    int curg = batch[n0];
    float acc = 0.f;
    int count = 0;
    int n = n0;
    for (; n + 4 <= n1; ) {
        int g0 = batch[n], g3 = batch[n + 3];
        if (g0 == curg && g3 == curg) {
            float v0 = h[(size_t)(n + 0) * DIM + c];
            float v1 = h[(size_t)(n + 1) * DIM + c];
            float v2 = h[(size_t)(n + 2) * DIM + c];
            float v3 = h[(size_t)(n + 3) * DIM + c];
            acc += (v0 + v1) + (v2 + v3);
            count += 4;
            n += 4;
        } else {
            int g = g0;
            if (g != curg) {
                atomicAdd(&pool[curg * DIM + c], acc);
                if (c == 0) atomicAdd(&pcnt[curg], (float)count);
                acc = 0.f; count = 0; curg = g;
            }
            acc += h[(size_t)n * DIM + c];
            count++;
            n += 1;
        }
    }
    for (; n < n1; ++n) {
        int g = batch[n];
        if (g != curg) {
            atomicAdd(&pool[curg * DIM + c], acc);
            if (c == 0) atomicAdd(&pcnt[curg], (float)count);
            acc = 0.f; count = 0; curg = g;
        }
        acc += h[(size_t)n * DIM + c];
        count++;
    }
    atomicAdd(&pool[curg * DIM + c], acc);
    if (c == 0) atomicAdd(&pcnt[curg], (float)count);
}

// ---------------- Final FC ----------------
__global__ void k_fc(const float* __restrict__ pool, const float* __restrict__ pcnt,
                     const float* __restrict__ Wfc, const float* __restrict__ bfc,
                     float* __restrict__ out) {
    int id = blockIdx.x * blockDim.x + threadIdx.x;
    if (id >= N_GRAPHS * OUTD) return;
    int g = id >> 4, o = id & 15;
    float inv = 1.0f / fmaxf(pcnt[g], 1.0f);
    float acc = bfc[o];
    const float* p = pool + g * DIM;
    for (int c = 0; c < DIM; ++c)
        acc = fmaf(p[c] * inv, Wfc[c * OUTD + o], acc);
    out[id] = acc;
}

// ---------------- launch ----------------

extern "C" void kernel_launch(void* const* d_in, const int* in_sizes, int n_in,
                              void* d_out, int out_size, void* d_ws, size_t ws_size,
                              hipStream_t stream) {
    const float* x    = (const float*)d_in[0];
    const int*   ei   = (const int*)d_in[1];
    const int*   batch= (const int*)d_in[2];
    const float* W1   = (const float*)d_in[3];
    const float* b1   = (const float*)d_in[4];
    const float* W2   = (const float*)d_in[5];
    const float* b2   = (const float*)d_in[6];
    const float* Wfc  = (const float*)d_in[7];
    const float* bfc  = (const float*)d_in[8];
    float* out = (float*)d_out;

    char* ws = (char*)d_ws;
    size_t off = 0;
    auto alloc = [&](size_t bytes) -> char* {
        char* p = ws + off;
        off = (off + bytes + 255) & ~(size_t)255;
        return p;
    };
    int*   cnt      = (int*)  alloc((size_t)N_NODES * 4);
    int*   row_off  = (int*)  alloc((size_t)(N_NODES + 1) * 4);
    int*   bcursor  = (int*)  alloc((size_t)NBUCK * 4);
    float* dis      = (float*)alloc((size_t)N_NODES * 4);
    int*   bsum     = (int*)  alloc(64 * 4);
    int*   csr_src  = (int*)  alloc((size_t)N_EDGES * 4);
    int2*  barr     = (int2*) alloc((size_t)N_EDGES * 8);
    float* pool     = (float*)alloc((size_t)N_GRAPHS * DIM * 4);
    float* pcnt     = (float*)alloc((size_t)N_GRAPHS * 4);
    unsigned short* Hb = (unsigned short*)alloc((size_t)N_NODES * DIM * 2);
    float* F1       = (float*)alloc((size_t)N_NODES * DIM * 4);

    const int* src = ei;
    const int* dst = ei + N_EDGES;

    hipMemsetAsync(cnt, 0, (size_t)N_NODES * 4, stream);

    int nb = (N_NODES + 1023) / 1024;  // 49
    k_count<<<(N_EDGES + 255) / 256, 256, 0, stream>>>(dst, cnt);
    k_scan1<<<nb, 1024, 0, stream>>>(cnt, row_off, bsum);
    k_scan2<<<1, 64, 0, stream>>>(bsum, nb, pool, pcnt);
    k_scan3<<<nb, 1024, 0, stream>>>(cnt, bsum, row_off, bcursor, dis);
    k_binA<<<(N_EDGES + TILE - 1) / TILE, 256, 0, stream>>>(src, dst, bcursor, barr);
    k_binB<<<NBUCK, 256, 0, stream>>>(barr, row_off, csr_src);

    int gemm_grid = (N_NODES + 63) / 64;   // 782
    // layer 1
    k_gemm<<<gemm_grid, 256, 0, stream>>>(x, W1, Hb, N_NODES);
    k_agg<<<(N_NODES + 7) / 8, 256, 0, stream>>>((const uint2*)Hb, row_off, csr_src, dis, b1, F1);
    // layer 2
    k_gemm<<<gemm_grid, 256, 0, stream>>>(F1, W2, Hb, N_NODES);
    k_agg<<<(N_NODES + 7) / 8, 256, 0, stream>>>((const uint2*)Hb, row_off, csr_src, dis, b2, F1);
    // pool + fc
    k_pool<<<POOL_BLOCKS, DIM, 0, stream>>>(F1, batch, pool, pcnt);
    k_fc<<<(N_GRAPHS * OUTD + 255) / 256, 256, 0, stream>>>(pool, pcnt, Wfc, bfc, out);
}

// Round 7
// 279.230 us; speedup vs baseline: 1.5646x; 1.0115x over previous
//
#include <hip/hip_runtime.h>
#include <math.h>

#define N_NODES 50000
#define N_EDGES 800000
#define N_GRAPHS 64
#define DIM 128
#define OUTD 16
#define POOL_BLOCKS 1024

// bucketed CSR build: 256 nodes per bucket
#define BSHIFT 8
#define BNODES 256
#define NBUCK ((N_NODES + BNODES - 1) / BNODES)   // 196
#define TILE 2048                                  // edges per k_binA block
#define RCAP 8192                                  // LDS stage capacity (entries)

typedef __attribute__((ext_vector_type(8))) short short8;
typedef __attribute__((ext_vector_type(4))) float f32x4;

// ---- bf16 helpers (round-to-nearest-even; values are finite) ----
static __device__ __forceinline__ unsigned short f2bf(float f) {
    unsigned u = __float_as_uint(f);
    u += 0x7fffu + ((u >> 16) & 1u);
    return (unsigned short)(u >> 16);
}
static __device__ __forceinline__ float bfl(unsigned u) {
    return __uint_as_float(u << 16);
}
static __device__ __forceinline__ float bfh(unsigned u) {
    return __uint_as_float(u & 0xffff0000u);
}

// ---------------- degree count + scan ----------------

__global__ void k_count(const int* __restrict__ dst, int* __restrict__ cnt) {
    int e = blockIdx.x * blockDim.x + threadIdx.x;
    if (e < N_EDGES) atomicAdd(&cnt[dst[e]], 1);
}

__global__ void k_scan1(const int* __restrict__ cnt, int* __restrict__ excl,
                        int* __restrict__ bsum) {
    __shared__ int s[1024];
    int i = blockIdx.x * 1024 + threadIdx.x;
    int v = (i < N_NODES) ? cnt[i] : 0;
    s[threadIdx.x] = v;
    __syncthreads();
    for (int off = 1; off < 1024; off <<= 1) {
        int t = (threadIdx.x >= off) ? s[threadIdx.x - off] : 0;
        __syncthreads();
        s[threadIdx.x] += t;
        __syncthreads();
    }
    if (i < N_NODES) excl[i] = s[threadIdx.x] - v;
    if (threadIdx.x == 1023) bsum[blockIdx.x] = s[1023];
}

// single-wave exclusive scan of block sums; also zero pool/pcnt
__global__ void k_scan2(int* __restrict__ bsum, int nb,
                        float* __restrict__ pool, float* __restrict__ pcnt) {
    int tid = threadIdx.x;
    int v = (tid < nb) ? bsum[tid] : 0;
    int orig = v;
    for (int off = 1; off < 64; off <<= 1) {
        int t = __shfl_up(v, off);
        if (tid >= off) v += t;
    }
    if (tid < nb) bsum[tid] = v - orig;
    for (int i = tid; i < N_GRAPHS * DIM; i += 64) pool[i] = 0.f;
    if (tid < N_GRAPHS) pcnt[tid] = 0.f;
}

// finalize row_off, seed per-bucket cursors (= region bases), emit dis
__global__ void k_scan3(const int* __restrict__ cnt, const int* __restrict__ bsum,
                        int* __restrict__ row_off, int* __restrict__ bucket_cursor,
                        float* __restrict__ dis) {
    int i = blockIdx.x * 1024 + threadIdx.x;
    if (i < N_NODES) {
        int ro = row_off[i] + bsum[blockIdx.x];
        row_off[i] = ro;
        if ((i & (BNODES - 1)) == 0) bucket_cursor[i >> BSHIFT] = ro;
        dis[i] = rsqrtf((float)(cnt[i] + 1));
    }
    if (i == 0) row_off[N_NODES] = N_EDGES;
}

// ---------------- Pass A: bin edges into coarse dst-buckets ----------------
// Packed 4B entry: src (16 bits, N_NODES<65536) | (dst&255)<<16.
__global__ __launch_bounds__(256) void k_binA(const int* __restrict__ src,
                                              const int* __restrict__ dstp,
                                              int* __restrict__ bucket_cursor,
                                              unsigned* __restrict__ bucket_arr) {
    __shared__ int cnt[NBUCK];
    __shared__ int base[NBUCK];
    int tile0 = blockIdx.x * TILE;
    for (int i = threadIdx.x; i < NBUCK; i += 256) cnt[i] = 0;
    __syncthreads();
#pragma unroll
    for (int j = 0; j < TILE / 256; ++j) {
        int e = tile0 + j * 256 + threadIdx.x;
        if (e < N_EDGES) atomicAdd(&cnt[dstp[e] >> BSHIFT], 1);
    }
    __syncthreads();
    for (int i = threadIdx.x; i < NBUCK; i += 256) {
        int c = cnt[i];
        base[i] = c ? atomicAdd(&bucket_cursor[i], c) : 0;
        cnt[i] = 0;   // reuse as local cursor
    }
    __syncthreads();
#pragma unroll
    for (int j = 0; j < TILE / 256; ++j) {
        int e = tile0 + j * 256 + threadIdx.x;
        if (e < N_EDGES) {
            int d = dstp[e];
            int b = d >> BSHIFT;
            int p = base[b] + atomicAdd(&cnt[b], 1);
            bucket_arr[p] = (unsigned)src[e] | ((unsigned)(d & 255) << 16);
        }
    }
}

// ---------------- Pass B: fine scatter within bucket via LDS --------------
__global__ __launch_bounds__(256) void k_binB(const unsigned* __restrict__ bucket_arr,
                                              const int* __restrict__ row_off,
                                              int* __restrict__ csr_src) {
    __shared__ int stage[RCAP];
    __shared__ int cur[BNODES];
    int n0 = blockIdx.x << BSHIFT;
    int n1 = min(n0 + BNODES, N_NODES);
    int rbase = row_off[n0];
    int len = row_off[n1] - rbase;
    for (int i = threadIdx.x; i < n1 - n0; i += 256)
        cur[i] = row_off[n0 + i] - rbase;
    __syncthreads();
    for (int i = threadIdx.x; i < len; i += 256) {
        unsigned ed = bucket_arr[rbase + i];
        int s = (int)(ed & 0xffffu);
        int dl = (int)(ed >> 16);
        int p = atomicAdd(&cur[dl], 1);
        if (p < RCAP) stage[p] = s;
        else csr_src[rbase + p] = s;
    }
    __syncthreads();
    int lim = min(len, RCAP);
    for (int i = threadIdx.x; i < lim; i += 256)
        csr_src[rbase + i] = stage[i];
}

// ---------------- MFMA GEMM: C[n,128](bf16) = A[n,128](f32) @ W[128,128](f32)
__global__ __launch_bounds__(256) void k_gemm(const float* __restrict__ A,
                                              const float* __restrict__ Wg,
                                              unsigned short* __restrict__ C,
                                              int nrows) {
    __shared__ unsigned int Wl[DIM * DIM / 2];   // 32 KB (bf16 pairs)
    {
        int t = threadIdx.x;
        int p = t & 63;
        int kp = p * 2;
        int n0 = (t >> 6) * 32;
        int kstep = kp >> 5;
        int quad = (kp >> 3) & 3;
        int jw = (kp & 7) >> 1;
        const float* r0 = Wg + (size_t)kp * DIM;
        const float* r1 = r0 + DIM;
        int rot = (p >> 2) & 7;
#pragma unroll
        for (int i4 = 0; i4 < 8; ++i4) {
            int nb = ((i4 + rot) & 7) * 4;
            int n = n0 + nb;
            float4 lo = *(const float4*)(r0 + n);
            float4 hi = *(const float4*)(r1 + n);
            const float* lp = &lo.x;
            const float* hp = &hi.x;
#pragma unroll
            for (int ii = 0; ii < 4; ++ii) {
                int nn = n + ii;
                int ct = nn >> 4;
                int l  = quad * 16 + (nn & 15);
                unsigned vlo = f2bf(lp[ii]);
                unsigned vhi = f2bf(hp[ii]);
                Wl[(((kstep * 8 + ct) * 64) + l) * 4 + jw] = vlo | (vhi << 16);
            }
        }
    }
    __syncthreads();

    int wid  = threadIdx.x >> 6;
    int lane = threadIdx.x & 63;
    int row0 = blockIdx.x * 64 + wid * 16;
    if (row0 >= nrows) return;

    int m = lane & 15;
    int quad = lane >> 4;
    const float* arow = A + (size_t)(row0 + m) * DIM + quad * 8;

    short8 afrag[4];
#pragma unroll
    for (int ks = 0; ks < 4; ++ks) {
        float4 lo = *(const float4*)(arow + ks * 32);
        float4 hi = *(const float4*)(arow + ks * 32 + 4);
        short8 f;
        f[0] = (short)f2bf(lo.x); f[1] = (short)f2bf(lo.y);
        f[2] = (short)f2bf(lo.z); f[3] = (short)f2bf(lo.w);
        f[4] = (short)f2bf(hi.x); f[5] = (short)f2bf(hi.y);
        f[6] = (short)f2bf(hi.z); f[7] = (short)f2bf(hi.w);
        afrag[ks] = f;
    }

    f32x4 acc[8];
#pragma unroll
    for (int ct = 0; ct < 8; ++ct) acc[ct] = (f32x4){0.f, 0.f, 0.f, 0.f};

    const short8* Wf = (const short8*)Wl;
#pragma unroll
    for (int ks = 0; ks < 4; ++ks) {
#pragma unroll
        for (int ct = 0; ct < 8; ++ct) {
            short8 b = Wf[(ks * 8 + ct) * 64 + lane];
            acc[ct] = __builtin_amdgcn_mfma_f32_16x16x32_bf16(afrag[ks], b, acc[ct], 0, 0, 0);
        }
    }

    unsigned short* crow = C + (size_t)row0 * DIM;
#pragma unroll
    for (int ct = 0; ct < 8; ++ct) {
#pragma unroll
        for (int reg = 0; reg < 4; ++reg) {
            crow[(size_t)(quad * 4 + reg) * DIM + ct * 16 + m] = f2bf(acc[ct][reg]);
        }
    }
}

// ---------------- Aggregation (pull, bf16 gather, f32 out) ----------------
// 16 lanes/node, 16B (8 bf16 channels) per lane; 16 nodes per 256-block.
// Edge loop unrolled x4 with independent accumulators -> up to 16 gathers
// in flight per wave (4 node-groups x 4).
__global__ __launch_bounds__(256) void k_agg(const uint4* __restrict__ Hb4,
                                             const int* __restrict__ row_off,
                                             const int* __restrict__ csr_src,
                                             const float* __restrict__ dis,
                                             const float* __restrict__ bias,
                                             float* __restrict__ out) {
    int lane = threadIdx.x & 15;
    int node = blockIdx.x * 16 + (threadIdx.x >> 4);
    if (node >= N_NODES) return;

    float dn = dis[node];
    float wself = dn * dn;
    uint4 hp = Hb4[(size_t)node * 16 + lane];
    float a0[8], a1[8], a2[8], a3[8];
    a0[0] = wself * bfl(hp.x); a0[1] = wself * bfh(hp.x);
    a0[2] = wself * bfl(hp.y); a0[3] = wself * bfh(hp.y);
    a0[4] = wself * bfl(hp.z); a0[5] = wself * bfh(hp.z);
    a0[6] = wself * bfl(hp.w); a0[7] = wself * bfh(hp.w);
#pragma unroll
    for (int j = 0; j < 8; ++j) { a1[j] = 0.f; a2[j] = 0.f; a3[j] = 0.f; }

    int e = row_off[node], e1 = row_off[node + 1];
    for (; e + 4 <= e1; e += 4) {
        int s0 = csr_src[e];     int s1 = csr_src[e + 1];
        int s2 = csr_src[e + 2]; int s3 = csr_src[e + 3];
        uint4 g0 = Hb4[(size_t)s0 * 16 + lane];
        uint4 g1 = Hb4[(size_t)s1 * 16 + lane];
        uint4 g2 = Hb4[(size_t)s2 * 16 + lane];
        uint4 g3 = Hb4[(size_t)s3 * 16 + lane];
        float w0 = dn * dis[s0], w1 = dn * dis[s1];
        float w2 = dn * dis[s2], w3 = dn * dis[s3];
        a0[0] = fmaf(w0, bfl(g0.x), a0[0]); a0[1] = fmaf(w0, bfh(g0.x), a0[1]);
        a0[2] = fmaf(w0, bfl(g0.y), a0[2]); a0[3] = fmaf(w0, bfh(g0.y), a0[3]);
        a0[4] = fmaf(w0, bfl(g0.z), a0[4]); a0[5] = fmaf(w0, bfh(g0.z), a0[5]);
        a0[6] = fmaf(w0, bfl(g0.w), a0[6]); a0[7] = fmaf(w0, bfh(g0.w), a0[7]);
        a1[0] = fmaf(w1, bfl(g1.x), a1[0]); a1[1] = fmaf(w1, bfh(g1.x), a1[1]);
        a1[2] = fmaf(w1, bfl(g1.y), a1[2]); a1[3] = fmaf(w1, bfh(g1.y), a1[3]);
        a1[4] = fmaf(w1, bfl(g1.z), a1[4]); a1[5] = fmaf(w1, bfh(g1.z), a1[5]);
        a1[6] = fmaf(w1, bfl(g1.w), a1[6]); a1[7] = fmaf(w1, bfh(g1.w), a1[7]);
        a2[0] = fmaf(w2, bfl(g2.x), a2[0]); a2[1] = fmaf(w2, bfh(g2.x), a2[1]);
        a2[2] = fmaf(w2, bfl(g2.y), a2[2]); a2[3] = fmaf(w2, bfh(g2.y), a2[3]);
        a2[4] = fmaf(w2, bfl(g2.z), a2[4]); a2[5] = fmaf(w2, bfh(g2.z), a2[5]);
        a2[6] = fmaf(w2, bfl(g2.w), a2[6]); a2[7] = fmaf(w2, bfh(g2.w), a2[7]);
        a3[0] = fmaf(w3, bfl(g3.x), a3[0]); a3[1] = fmaf(w3, bfh(g3.x), a3[1]);
        a3[2] = fmaf(w3, bfl(g3.y), a3[2]); a3[3] = fmaf(w3, bfh(g3.y), a3[3]);
        a3[4] = fmaf(w3, bfl(g3.z), a3[4]); a3[5] = fmaf(w3, bfh(g3.z), a3[5]);
        a3[6] = fmaf(w3, bfl(g3.w), a3[6]); a3[7] = fmaf(w3, bfh(g3.w), a3[7]);
    }
    for (; e < e1; ++e) {
        int s = csr_src[e];
        uint4 g = Hb4[(size_t)s * 16 + lane];
        float w = dn * dis[s];
        a0[0] = fmaf(w, bfl(g.x), a0[0]); a0[1] = fmaf(w, bfh(g.x), a0[1]);
        a0[2] = fmaf(w, bfl(g.y), a0[2]); a0[3] = fmaf(w, bfh(g.y), a0[3]);
        a0[4] = fmaf(w, bfl(g.z), a0[4]); a0[5] = fmaf(w, bfh(g.z), a0[5]);
        a0[6] = fmaf(w, bfl(g.w), a0[6]); a0[7] = fmaf(w, bfh(g.w), a0[7]);
    }

    float4 b0 = ((const float4*)bias)[lane * 2];
    float4 b1v = ((const float4*)bias)[lane * 2 + 1];
    float r[8];
    r[0] = a0[0] + a1[0] + a2[0] + a3[0] + b0.x;
    r[1] = a0[1] + a1[1] + a2[1] + a3[1] + b0.y;
    r[2] = a0[2] + a1[2] + a2[2] + a3[2] + b0.z;
    r[3] = a0[3] + a1[3] + a2[3] + a3[3] + b0.w;
    r[4] = a0[4] + a1[4] + a2[4] + a3[4] + b1v.x;
    r[5] = a0[5] + a1[5] + a2[5] + a3[5] + b1v.y;
    r[6] = a0[6] + a1[6] + a2[6] + a3[6] + b1v.z;
    r[7] = a0[7] + a1[7] + a2[7] + a3[7] + b1v.w;
    float4* o4 = (float4*)(out + (size_t)node * DIM + lane * 8);
    o4[0] = make_float4(fmaxf(r[0], 0.f), fmaxf(r[1], 0.f), fmaxf(r[2], 0.f), fmaxf(r[3], 0.f));
    o4[1] = make_float4(fmaxf(r[4], 0.f), fmaxf(r[5], 0.f), fmaxf(r[6], 0.f), fmaxf(r[7], 0.f));
}

// ---------------- Mean pool (parallel + ILP-4) ----------------
__global__ __launch_bounds__(128) void k_pool(const float* __restrict__ h,
                                              const int* __restrict__ batch,
                                              float* __restrict__ pool,
                                              float* __restrict__ pcnt) {
    int chunk = (N_NODES + POOL_BLOCKS - 1) / POOL_BLOCKS;
    int n0 = blockIdx.x * chunk;
    int n1 = min(n0 + chunk, N_NODES);
    if (n0 >= n1) return;
    int c = threadIdx.x;
    int curg = batch[n0];
    float acc = 0.f;
    int count = 0;
    int n = n0;
    for (; n + 4 <= n1; ) {
        int g0 = batch[n], g3 = batch[n + 3];
        if (g0 == curg && g3 == curg) {
            float v0 = h[(size_t)(n + 0) * DIM + c];
            float v1 = h[(size_t)(n + 1) * DIM + c];
            float v2 = h[(size_t)(n + 2) * DIM + c];
            float v3 = h[(size_t)(n + 3) * DIM + c];
            acc += (v0 + v1) + (v2 + v3);
            count += 4;
            n += 4;
        } else {
            int g = g0;
            if (g != curg) {
                atomicAdd(&pool[curg * DIM + c], acc);
                if (c == 0) atomicAdd(&pcnt[curg], (float)count);
                acc = 0.f; count = 0; curg = g;
            }
            acc += h[(size_t)n * DIM + c];
            count++;
            n += 1;
        }
    }
    for (; n < n1; ++n) {
        int g = batch[n];
        if (g != curg) {
            atomicAdd(&pool[curg * DIM + c], acc);
            if (c == 0) atomicAdd(&pcnt[curg], (float)count);
            acc = 0.f; count = 0; curg = g;
        }
        acc += h[(size_t)n * DIM + c];
        count++;
    }
    atomicAdd(&pool[curg * DIM + c], acc);
    if (c == 0) atomicAdd(&pcnt[curg], (float)count);
}

// ---------------- Final FC ----------------
__global__ void k_fc(const float* __restrict__ pool, const float* __restrict__ pcnt,
                     const float* __restrict__ Wfc, const float* __restrict__ bfc,
                     float* __restrict__ out) {
    int id = blockIdx.x * blockDim.x + threadIdx.x;
    if (id >= N_GRAPHS * OUTD) return;
    int g = id >> 4, o = id & 15;
    float inv = 1.0f / fmaxf(pcnt[g], 1.0f);
    float acc = bfc[o];
    const float* p = pool + g * DIM;
    for (int c = 0; c < DIM; ++c)
        acc = fmaf(p[c] * inv, Wfc[c * OUTD + o], acc);
    out[id] = acc;
}

// ---------------- launch ----------------

extern "C" void kernel_launch(void* const* d_in, const int* in_sizes, int n_in,
                              void* d_out, int out_size, void* d_ws, size_t ws_size,
                              hipStream_t stream) {
    const float* x    = (const float*)d_in[0];
    const int*   ei   = (const int*)d_in[1];
    const int*   batch= (const int*)d_in[2];
    const float* W1   = (const float*)d_in[3];
    const float* b1   = (const float*)d_in[4];
    const float* W2   = (const float*)d_in[5];
    const float* b2   = (const float*)d_in[6];
    const float* Wfc  = (const float*)d_in[7];
    const float* bfc  = (const float*)d_in[8];
    float* out = (float*)d_out;

    char* ws = (char*)d_ws;
    size_t off = 0;
    auto alloc = [&](size_t bytes) -> char* {
        char* p = ws + off;
        off = (off + bytes + 255) & ~(size_t)255;
        return p;
    };
    int*      cnt      = (int*)     alloc((size_t)N_NODES * 4);
    int*      row_off  = (int*)     alloc((size_t)(N_NODES + 1) * 4);
    int*      bcursor  = (int*)     alloc((size_t)NBUCK * 4);
    float*    dis      = (float*)   alloc((size_t)N_NODES * 4);
    int*      bsum     = (int*)     alloc(64 * 4);
    int*      csr_src  = (int*)     alloc((size_t)N_EDGES * 4);
    unsigned* barr     = (unsigned*)alloc((size_t)N_EDGES * 4);
    float*    pool     = (float*)   alloc((size_t)N_GRAPHS * DIM * 4);
    float*    pcnt     = (float*)   alloc((size_t)N_GRAPHS * 4);
    unsigned short* Hb = (unsigned short*)alloc((size_t)N_NODES * DIM * 2);
    float*    F1       = (float*)   alloc((size_t)N_NODES * DIM * 4);

    const int* src = ei;
    const int* dst = ei + N_EDGES;

    hipMemsetAsync(cnt, 0, (size_t)N_NODES * 4, stream);

    int nb = (N_NODES + 1023) / 1024;  // 49
    k_count<<<(N_EDGES + 255) / 256, 256, 0, stream>>>(dst, cnt);
    k_scan1<<<nb, 1024, 0, stream>>>(cnt, row_off, bsum);
    k_scan2<<<1, 64, 0, stream>>>(bsum, nb, pool, pcnt);
    k_scan3<<<nb, 1024, 0, stream>>>(cnt, bsum, row_off, bcursor, dis);
    k_binA<<<(N_EDGES + TILE - 1) / TILE, 256, 0, stream>>>(src, dst, bcursor, barr);
    k_binB<<<NBUCK, 256, 0, stream>>>(barr, row_off, csr_src);

    int gemm_grid = (N_NODES + 63) / 64;   // 782
    int agg_grid  = (N_NODES + 15) / 16;   // 3125
    // layer 1
    k_gemm<<<gemm_grid, 256, 0, stream>>>(x, W1, Hb, N_NODES);
    k_agg<<<agg_grid, 256, 0, stream>>>((const uint4*)Hb, row_off, csr_src, dis, b1, F1);
    // layer 2
    k_gemm<<<gemm_grid, 256, 0, stream>>>(F1, W2, Hb, N_NODES);
    k_agg<<<agg_grid, 256, 0, stream>>>((const uint4*)Hb, row_off, csr_src, dis, b2, F1);
    // pool + fc
    k_pool<<<POOL_BLOCKS, DIM, 0, stream>>>(F1, batch, pool, pcnt);
    k_fc<<<(N_GRAPHS * OUTD + 255) / 256, 256, 0, stream>>>(pool, pcnt, Wfc, bfc, out);
}

// Round 8
// 273.402 us; speedup vs baseline: 1.5979x; 1.0213x over previous
//
#include <hip/hip_runtime.h>
#include <math.h>

#define N_NODES 50000
#define N_EDGES 800000
#define N_GRAPHS 64
#define DIM 128
#define OUTD 16
#define POOL_BLOCKS 1024

// bucketed CSR build: 256 nodes per bucket
#define BSHIFT 8
#define BNODES 256
#define NBUCK ((N_NODES + BNODES - 1) / BNODES)   // 196
#define TILE 2048                                  // edges per k_binA block
#define RCAP 8192                                  // LDS stage capacity (entries)

typedef __attribute__((ext_vector_type(8))) short short8;
typedef __attribute__((ext_vector_type(4))) float f32x4;

// ---- bf16 helpers (round-to-nearest-even; values are finite) ----
static __device__ __forceinline__ unsigned short f2bf(float f) {
    unsigned u = __float_as_uint(f);
    u += 0x7fffu + ((u >> 16) & 1u);
    return (unsigned short)(u >> 16);
}
static __device__ __forceinline__ float bfl(unsigned u) {
    return __uint_as_float(u << 16);
}
static __device__ __forceinline__ float bfh(unsigned u) {
    return __uint_as_float(u & 0xffff0000u);
}

// ---------------- degree count + scan ----------------

__global__ void k_count(const int* __restrict__ dst, int* __restrict__ cnt) {
    int e = blockIdx.x * blockDim.x + threadIdx.x;
    if (e < N_EDGES) atomicAdd(&cnt[dst[e]], 1);
}

__global__ void k_scan1(const int* __restrict__ cnt, int* __restrict__ excl,
                        int* __restrict__ bsum) {
    __shared__ int s[1024];
    int i = blockIdx.x * 1024 + threadIdx.x;
    int v = (i < N_NODES) ? cnt[i] : 0;
    s[threadIdx.x] = v;
    __syncthreads();
    for (int off = 1; off < 1024; off <<= 1) {
        int t = (threadIdx.x >= off) ? s[threadIdx.x - off] : 0;
        __syncthreads();
        s[threadIdx.x] += t;
        __syncthreads();
    }
    if (i < N_NODES) excl[i] = s[threadIdx.x] - v;
    if (threadIdx.x == 1023) bsum[blockIdx.x] = s[1023];
}

// single-wave exclusive scan of block sums; also zero pool/pcnt
__global__ void k_scan2(int* __restrict__ bsum, int nb,
                        float* __restrict__ pool, float* __restrict__ pcnt) {
    int tid = threadIdx.x;
    int v = (tid < nb) ? bsum[tid] : 0;
    int orig = v;
    for (int off = 1; off < 64; off <<= 1) {
        int t = __shfl_up(v, off);
        if (tid >= off) v += t;
    }
    if (tid < nb) bsum[tid] = v - orig;
    for (int i = tid; i < N_GRAPHS * DIM; i += 64) pool[i] = 0.f;
    if (tid < N_GRAPHS) pcnt[tid] = 0.f;
}

// finalize row_off, seed per-bucket cursors (= region bases), emit dis
__global__ void k_scan3(const int* __restrict__ cnt, const int* __restrict__ bsum,
                        int* __restrict__ row_off, int* __restrict__ bucket_cursor,
                        float* __restrict__ dis) {
    int i = blockIdx.x * 1024 + threadIdx.x;
    if (i < N_NODES) {
        int ro = row_off[i] + bsum[blockIdx.x];
        row_off[i] = ro;
        if ((i & (BNODES - 1)) == 0) bucket_cursor[i >> BSHIFT] = ro;
        dis[i] = rsqrtf((float)(cnt[i] + 1));
    }
    if (i == 0) row_off[N_NODES] = N_EDGES;
}

// ---------------- Pass A: bin edges into coarse dst-buckets ----------------
// Packed 4B entry: src (16 bits, N_NODES<65536) | (dst&255)<<16.
__global__ __launch_bounds__(256) void k_binA(const int* __restrict__ src,
                                              const int* __restrict__ dstp,
                                              int* __restrict__ bucket_cursor,
                                              unsigned* __restrict__ bucket_arr) {
    __shared__ int cnt[NBUCK];
    __shared__ int base[NBUCK];
    int tile0 = blockIdx.x * TILE;
    for (int i = threadIdx.x; i < NBUCK; i += 256) cnt[i] = 0;
    __syncthreads();
#pragma unroll
    for (int j = 0; j < TILE / 256; ++j) {
        int e = tile0 + j * 256 + threadIdx.x;
        if (e < N_EDGES) atomicAdd(&cnt[dstp[e] >> BSHIFT], 1);
    }
    __syncthreads();
    for (int i = threadIdx.x; i < NBUCK; i += 256) {
        int c = cnt[i];
        base[i] = c ? atomicAdd(&bucket_cursor[i], c) : 0;
        cnt[i] = 0;   // reuse as local cursor
    }
    __syncthreads();
#pragma unroll
    for (int j = 0; j < TILE / 256; ++j) {
        int e = tile0 + j * 256 + threadIdx.x;
        if (e < N_EDGES) {
            int d = dstp[e];
            int b = d >> BSHIFT;
            int p = base[b] + atomicAdd(&cnt[b], 1);
            bucket_arr[p] = (unsigned)src[e] | ((unsigned)(d & 255) << 16);
        }
    }
}

// ---------------- Pass B: fine scatter within bucket via LDS --------------
// Output CSR entry: src(16b) | bf16(dis[src]*dis[dst])<<16 — agg needs no
// per-edge dis loads.
__global__ __launch_bounds__(256) void k_binB(const unsigned* __restrict__ bucket_arr,
                                              const int* __restrict__ row_off,
                                              const float* __restrict__ dis,
                                              unsigned* __restrict__ csr) {
    __shared__ unsigned stage[RCAP];
    __shared__ int cur[BNODES];
    int n0 = blockIdx.x << BSHIFT;
    int n1 = min(n0 + BNODES, N_NODES);
    int rbase = row_off[n0];
    int len = row_off[n1] - rbase;
    for (int i = threadIdx.x; i < n1 - n0; i += 256)
        cur[i] = row_off[n0 + i] - rbase;
    __syncthreads();
    for (int i = threadIdx.x; i < len; i += 256) {
        unsigned ed = bucket_arr[rbase + i];
        int s  = (int)(ed & 0xffffu);
        int dl = (int)(ed >> 16);
        float w = dis[s] * dis[n0 + dl];
        unsigned packed = (unsigned)s | ((unsigned)f2bf(w) << 16);
        int p = atomicAdd(&cur[dl], 1);
        if (p < RCAP) stage[p] = packed;
        else csr[rbase + p] = packed;
    }
    __syncthreads();
    int lim = min(len, RCAP);
    for (int i = threadIdx.x; i < lim; i += 256)
        csr[rbase + i] = stage[i];
}

// ---------------- MFMA GEMM: C[n,128](bf16) = A[n,128](f32) @ W[128,128](f32)
// Block = 4 waves; 32 rows/wave (2 M-tiles share each B-fragment -> half the
// LDS reads per MFMA). Epilogue stages C in LDS (row stride 272B) and writes
// coalesced dwordx4 (8 stores/wave vs 32 scalar b16 stores).
__global__ __launch_bounds__(256) void k_gemm(const float* __restrict__ A,
                                              const float* __restrict__ Wg,
                                              unsigned short* __restrict__ C,
                                              int nrows) {
    __shared__ unsigned smem[34816 / 4];   // W stage (32KB) reused for C stage (34.8KB)
    unsigned* Wl = smem;
    {
        int t = threadIdx.x;
        int p = t & 63;
        int kp = p * 2;
        int n0 = (t >> 6) * 32;
        int kstep = kp >> 5;
        int quad = (kp >> 3) & 3;
        int jw = (kp & 7) >> 1;
        const float* r0 = Wg + (size_t)kp * DIM;
        const float* r1 = r0 + DIM;
        int rot = (p >> 2) & 7;
#pragma unroll
        for (int i4 = 0; i4 < 8; ++i4) {
            int nb = ((i4 + rot) & 7) * 4;
            int n = n0 + nb;
            float4 lo = *(const float4*)(r0 + n);
            float4 hi = *(const float4*)(r1 + n);
            const float* lp = &lo.x;
            const float* hp = &hi.x;
#pragma unroll
            for (int ii = 0; ii < 4; ++ii) {
                int nn = n + ii;
                int ct = nn >> 4;
                int l  = quad * 16 + (nn & 15);
                unsigned vlo = f2bf(lp[ii]);
                unsigned vhi = f2bf(hp[ii]);
                Wl[(((kstep * 8 + ct) * 64) + l) * 4 + jw] = vlo | (vhi << 16);
            }
        }
    }
    __syncthreads();

    int wid  = threadIdx.x >> 6;
    int lane = threadIdx.x & 63;
    int m    = lane & 15;
    int quad = lane >> 4;
    int row0 = blockIdx.x * 128 + wid * 32;

    // A fragments for rows m and m+16 (loads clamped; stores guarded)
    int rA = row0 + m;      if (rA >= nrows) rA = nrows - 1;
    int rB = row0 + 16 + m; if (rB >= nrows) rB = nrows - 1;
    const float* arowA = A + (size_t)rA * DIM + quad * 8;
    const float* arowB = A + (size_t)rB * DIM + quad * 8;

    short8 af0[4], af1[4];
#pragma unroll
    for (int ks = 0; ks < 4; ++ks) {
        float4 lo = *(const float4*)(arowA + ks * 32);
        float4 hi = *(const float4*)(arowA + ks * 32 + 4);
        short8 f;
        f[0] = (short)f2bf(lo.x); f[1] = (short)f2bf(lo.y);
        f[2] = (short)f2bf(lo.z); f[3] = (short)f2bf(lo.w);
        f[4] = (short)f2bf(hi.x); f[5] = (short)f2bf(hi.y);
        f[6] = (short)f2bf(hi.z); f[7] = (short)f2bf(hi.w);
        af0[ks] = f;
        lo = *(const float4*)(arowB + ks * 32);
        hi = *(const float4*)(arowB + ks * 32 + 4);
        f[0] = (short)f2bf(lo.x); f[1] = (short)f2bf(lo.y);
        f[2] = (short)f2bf(lo.z); f[3] = (short)f2bf(lo.w);
        f[4] = (short)f2bf(hi.x); f[5] = (short)f2bf(hi.y);
        f[6] = (short)f2bf(hi.z); f[7] = (short)f2bf(hi.w);
        af1[ks] = f;
    }

    f32x4 acc0[8], acc1[8];
#pragma unroll
    for (int ct = 0; ct < 8; ++ct) {
        acc0[ct] = (f32x4){0.f, 0.f, 0.f, 0.f};
        acc1[ct] = (f32x4){0.f, 0.f, 0.f, 0.f};
    }

    const short8* Wf = (const short8*)Wl;
#pragma unroll
    for (int ks = 0; ks < 4; ++ks) {
#pragma unroll
        for (int ct = 0; ct < 8; ++ct) {
            short8 b = Wf[(ks * 8 + ct) * 64 + lane];
            acc0[ct] = __builtin_amdgcn_mfma_f32_16x16x32_bf16(af0[ks], b, acc0[ct], 0, 0, 0);
            acc1[ct] = __builtin_amdgcn_mfma_f32_16x16x32_bf16(af1[ks], b, acc1[ct], 0, 0, 0);
        }
    }

    __syncthreads();   // done reading Wl; reuse LDS for C staging
    // wave region: 32 rows x 272B (stride 136 ushorts)
    unsigned short* cs = (unsigned short*)smem + wid * 4352;
#pragma unroll
    for (int ct = 0; ct < 8; ++ct) {
#pragma unroll
        for (int reg = 0; reg < 4; ++reg) {
            cs[(quad * 4 + reg) * 136 + ct * 16 + m]        = f2bf(acc0[ct][reg]);
            cs[(16 + quad * 4 + reg) * 136 + ct * 16 + m]   = f2bf(acc1[ct][reg]);
        }
    }
    // readout: iteration i covers rows i*4+quad; lane chunk m covers 16B
    const unsigned char* cb = (const unsigned char*)smem + wid * 8704;
#pragma unroll
    for (int i = 0; i < 8; ++i) {
        int rg = i * 4 + quad;
        int r = row0 + rg;
        if (r < nrows) {
            uint4 v = *(const uint4*)(cb + rg * 272 + m * 16);
            *((uint4*)(C + (size_t)r * DIM) + m) = v;
        }
    }
}

// ---------------- Aggregation (pull, bf16 gather, f32 out) ----------------
// 16 lanes/node, 16B (8 bf16 channels)/lane. CSR entry = src | w(bf16)<<16:
// no per-edge dis loads.
__global__ __launch_bounds__(256) void k_agg(const uint4* __restrict__ Hb4,
                                             const int* __restrict__ row_off,
                                             const unsigned* __restrict__ csr,
                                             const float* __restrict__ dis,
                                             const float* __restrict__ bias,
                                             float* __restrict__ out) {
    int lane = threadIdx.x & 15;
    int node = blockIdx.x * 16 + (threadIdx.x >> 4);
    if (node >= N_NODES) return;

    float dn = dis[node];
    float wself = dn * dn;
    uint4 hp = Hb4[(size_t)node * 16 + lane];
    float a0[8], a1[8], a2[8], a3[8];
    a0[0] = wself * bfl(hp.x); a0[1] = wself * bfh(hp.x);
    a0[2] = wself * bfl(hp.y); a0[3] = wself * bfh(hp.y);
    a0[4] = wself * bfl(hp.z); a0[5] = wself * bfh(hp.z);
    a0[6] = wself * bfl(hp.w); a0[7] = wself * bfh(hp.w);
#pragma unroll
    for (int j = 0; j < 8; ++j) { a1[j] = 0.f; a2[j] = 0.f; a3[j] = 0.f; }

    int e = row_off[node], e1 = row_off[node + 1];
    for (; e + 4 <= e1; e += 4) {
        unsigned q0 = csr[e];     unsigned q1 = csr[e + 1];
        unsigned q2 = csr[e + 2]; unsigned q3 = csr[e + 3];
        uint4 g0 = Hb4[(size_t)(q0 & 0xffffu) * 16 + lane];
        uint4 g1 = Hb4[(size_t)(q1 & 0xffffu) * 16 + lane];
        uint4 g2 = Hb4[(size_t)(q2 & 0xffffu) * 16 + lane];
        uint4 g3 = Hb4[(size_t)(q3 & 0xffffu) * 16 + lane];
        float w0 = bfh(q0), w1 = bfh(q1), w2 = bfh(q2), w3 = bfh(q3);
        a0[0] = fmaf(w0, bfl(g0.x), a0[0]); a0[1] = fmaf(w0, bfh(g0.x), a0[1]);
        a0[2] = fmaf(w0, bfl(g0.y), a0[2]); a0[3] = fmaf(w0, bfh(g0.y), a0[3]);
        a0[4] = fmaf(w0, bfl(g0.z), a0[4]); a0[5] = fmaf(w0, bfh(g0.z), a0[5]);
        a0[6] = fmaf(w0, bfl(g0.w), a0[6]); a0[7] = fmaf(w0, bfh(g0.w), a0[7]);
        a1[0] = fmaf(w1, bfl(g1.x), a1[0]); a1[1] = fmaf(w1, bfh(g1.x), a1[1]);
        a1[2] = fmaf(w1, bfl(g1.y), a1[2]); a1[3] = fmaf(w1, bfh(g1.y), a1[3]);
        a1[4] = fmaf(w1, bfl(g1.z), a1[4]); a1[5] = fmaf(w1, bfh(g1.z), a1[5]);
        a1[6] = fmaf(w1, bfl(g1.w), a1[6]); a1[7] = fmaf(w1, bfh(g1.w), a1[7]);
        a2[0] = fmaf(w2, bfl(g2.x), a2[0]); a2[1] = fmaf(w2, bfh(g2.x), a2[1]);
        a2[2] = fmaf(w2, bfl(g2.y), a2[2]); a2[3] = fmaf(w2, bfh(g2.y), a2[3]);
        a2[4] = fmaf(w2, bfl(g2.z), a2[4]); a2[5] = fmaf(w2, bfh(g2.z), a2[5]);
        a2[6] = fmaf(w2, bfl(g2.w), a2[6]); a2[7] = fmaf(w2, bfh(g2.w), a2[7]);
        a3[0] = fmaf(w3, bfl(g3.x), a3[0]); a3[1] = fmaf(w3, bfh(g3.x), a3[1]);
        a3[2] = fmaf(w3, bfl(g3.y), a3[2]); a3[3] = fmaf(w3, bfh(g3.y), a3[3]);
        a3[4] = fmaf(w3, bfl(g3.z), a3[4]); a3[5] = fmaf(w3, bfh(g3.z), a3[5]);
        a3[6] = fmaf(w3, bfl(g3.w), a3[6]); a3[7] = fmaf(w3, bfh(g3.w), a3[7]);
    }
    for (; e < e1; ++e) {
        unsigned q = csr[e];
        uint4 g = Hb4[(size_t)(q & 0xffffu) * 16 + lane];
        float w = bfh(q);
        a0[0] = fmaf(w, bfl(g.x), a0[0]); a0[1] = fmaf(w, bfh(g.x), a0[1]);
        a0[2] = fmaf(w, bfl(g.y), a0[2]); a0[3] = fmaf(w, bfh(g.y), a0[3]);
        a0[4] = fmaf(w, bfl(g.z), a0[4]); a0[5] = fmaf(w, bfh(g.z), a0[5]);
        a0[6] = fmaf(w, bfl(g.w), a0[6]); a0[7] = fmaf(w, bfh(g.w), a0[7]);
    }

    float4 b0 = ((const float4*)bias)[lane * 2];
    float4 b1v = ((const float4*)bias)[lane * 2 + 1];
    float r[8];
    r[0] = a0[0] + a1[0] + a2[0] + a3[0] + b0.x;
    r[1] = a0[1] + a1[1] + a2[1] + a3[1] + b0.y;
    r[2] = a0[2] + a1[2] + a2[2] + a3[2] + b0.z;
    r[3] = a0[3] + a1[3] + a2[3] + a3[3] + b0.w;
    r[4] = a0[4] + a1[4] + a2[4] + a3[4] + b1v.x;
    r[5] = a0[5] + a1[5] + a2[5] + a3[5] + b1v.y;
    r[6] = a0[6] + a1[6] + a2[6] + a3[6] + b1v.z;
    r[7] = a0[7] + a1[7] + a2[7] + a3[7] + b1v.w;
    float4* o4 = (float4*)(out + (size_t)node * DIM + lane * 8);
    o4[0] = make_float4(fmaxf(r[0], 0.f), fmaxf(r[1], 0.f), fmaxf(r[2], 0.f), fmaxf(r[3], 0.f));
    o4[1] = make_float4(fmaxf(r[4], 0.f), fmaxf(r[5], 0.f), fmaxf(r[6], 0.f), fmaxf(r[7], 0.f));
}

// ---------------- Mean pool (parallel + ILP-4) ----------------
__global__ __launch_bounds__(128) void k_pool(const float* __restrict__ h,
                                              const int* __restrict__ batch,
                                              float* __restrict__ pool,
                                              float* __restrict__ pcnt) {
    int chunk = (N_NODES + POOL_BLOCKS - 1) / POOL_BLOCKS;
    int n0 = blockIdx.x * chunk;
    int n1 = min(n0 + chunk, N_NODES);
    if (n0 >= n1) return;
    int c = threadIdx.x;
    int curg = batch[n0];
    float acc = 0.f;
    int count = 0;
    int n = n0;
    for (; n + 4 <= n1; ) {
        int g0 = batch[n], g3 = batch[n + 3];
        if (g0 == curg && g3 == curg) {
            float v0 = h[(size_t)(n + 0) * DIM + c];
            float v1 = h[(size_t)(n + 1) * DIM + c];
            float v2 = h[(size_t)(n + 2) * DIM + c];
            float v3 = h[(size_t)(n + 3) * DIM + c];
            acc += (v0 + v1) + (v2 + v3);
            count += 4;
            n += 4;
        } else {
            int g = g0;
            if (g != curg) {
                atomicAdd(&pool[curg * DIM + c], acc);
                if (c == 0) atomicAdd(&pcnt[curg], (float)count);
                acc = 0.f; count = 0; curg = g;
            }
            acc += h[(size_t)n * DIM + c];
            count++;
            n += 1;
        }
    }
    for (; n < n1; ++n) {
        int g = batch[n];
        if (g != curg) {
            atomicAdd(&pool[curg * DIM + c], acc);
            if (c == 0) atomicAdd(&pcnt[curg], (float)count);
            acc = 0.f; count = 0; curg = g;
        }
        acc += h[(size_t)n * DIM + c];
        count++;
    }
    atomicAdd(&pool[curg * DIM + c], acc);
    if (c == 0) atomicAdd(&pcnt[curg], (float)count);
}

// ---------------- Final FC ----------------
__global__ void k_fc(const float* __restrict__ pool, const float* __restrict__ pcnt,
                     const float* __restrict__ Wfc, const float* __restrict__ bfc,
                     float* __restrict__ out) {
    int id = blockIdx.x * blockDim.x + threadIdx.x;
    if (id >= N_GRAPHS * OUTD) return;
    int g = id >> 4, o = id & 15;
    float inv = 1.0f / fmaxf(pcnt[g], 1.0f);
    float acc = bfc[o];
    const float* p = pool + g * DIM;
    for (int c = 0; c < DIM; ++c)
        acc = fmaf(p[c] * inv, Wfc[c * OUTD + o], acc);
    out[id] = acc;
}

// ---------------- launch ----------------

extern "C" void kernel_launch(void* const* d_in, const int* in_sizes, int n_in,
                              void* d_out, int out_size, void* d_ws, size_t ws_size,
                              hipStream_t stream) {
    const float* x    = (const float*)d_in[0];
    const int*   ei   = (const int*)d_in[1];
    const int*   batch= (const int*)d_in[2];
    const float* W1   = (const float*)d_in[3];
    const float* b1   = (const float*)d_in[4];
    const float* W2   = (const float*)d_in[5];
    const float* b2   = (const float*)d_in[6];
    const float* Wfc  = (const float*)d_in[7];
    const float* bfc  = (const float*)d_in[8];
    float* out = (float*)d_out;

    char* ws = (char*)d_ws;
    size_t off = 0;
    auto alloc = [&](size_t bytes) -> char* {
        char* p = ws + off;
        off = (off + bytes + 255) & ~(size_t)255;
        return p;
    };
    int*      cnt      = (int*)     alloc((size_t)N_NODES * 4);
    int*      row_off  = (int*)     alloc((size_t)(N_NODES + 1) * 4);
    int*      bcursor  = (int*)     alloc((size_t)NBUCK * 4);
    float*    dis      = (float*)   alloc((size_t)N_NODES * 4);
    int*      bsum     = (int*)     alloc(64 * 4);
    unsigned* csr      = (unsigned*)alloc((size_t)N_EDGES * 4);
    unsigned* barr     = (unsigned*)alloc((size_t)N_EDGES * 4);
    float*    pool     = (float*)   alloc((size_t)N_GRAPHS * DIM * 4);
    float*    pcnt     = (float*)   alloc((size_t)N_GRAPHS * 4);
    unsigned short* Hb = (unsigned short*)alloc((size_t)N_NODES * DIM * 2);
    float*    F1       = (float*)   alloc((size_t)N_NODES * DIM * 4);

    const int* src = ei;
    const int* dst = ei + N_EDGES;

    hipMemsetAsync(cnt, 0, (size_t)N_NODES * 4, stream);

    int nb = (N_NODES + 1023) / 1024;  // 49
    k_count<<<(N_EDGES + 255) / 256, 256, 0, stream>>>(dst, cnt);
    k_scan1<<<nb, 1024, 0, stream>>>(cnt, row_off, bsum);
    k_scan2<<<1, 64, 0, stream>>>(bsum, nb, pool, pcnt);
    k_scan3<<<nb, 1024, 0, stream>>>(cnt, bsum, row_off, bcursor, dis);
    k_binA<<<(N_EDGES + TILE - 1) / TILE, 256, 0, stream>>>(src, dst, bcursor, barr);
    k_binB<<<NBUCK, 256, 0, stream>>>(barr, row_off, dis, csr);

    int gemm_grid = (N_NODES + 127) / 128;  // 391
    int agg_grid  = (N_NODES + 15) / 16;    // 3125
    // layer 1
    k_gemm<<<gemm_grid, 256, 0, stream>>>(x, W1, Hb, N_NODES);
    k_agg<<<agg_grid, 256, 0, stream>>>((const uint4*)Hb, row_off, csr, dis, b1, F1);
    // layer 2
    k_gemm<<<gemm_grid, 256, 0, stream>>>(F1, W2, Hb, N_NODES);
    k_agg<<<agg_grid, 256, 0, stream>>>((const uint4*)Hb, row_off, csr, dis, b2, F1);
    // pool + fc
    k_pool<<<POOL_BLOCKS, DIM, 0, stream>>>(F1, batch, pool, pcnt);
    k_fc<<<(N_GRAPHS * OUTD + 255) / 256, 256, 0, stream>>>(pool, pcnt, Wfc, bfc, out);
}

// Round 9
// 234.951 us; speedup vs baseline: 1.8595x; 1.1637x over previous
//
#include <hip/hip_runtime.h>
#include <math.h>

#define N_NODES 50000
#define N_EDGES 800000
#define N_GRAPHS 64
#define DIM 128
#define OUTD 16
#define POOL_BLOCKS 1024

// bucketed CSR build: 256 nodes per bucket
#define BSHIFT 8
#define BNODES 256
#define NBUCK ((N_NODES + BNODES - 1) / BNODES)   // 196
#define TILE 2048                                  // edges per binning block
#define RCAP 8192                                  // LDS stage capacity (entries)

typedef __attribute__((ext_vector_type(8))) short short8;
typedef __attribute__((ext_vector_type(4))) float f32x4;

// ---- bf16 helpers (round-to-nearest-even; values are finite) ----
static __device__ __forceinline__ unsigned short f2bf(float f) {
    unsigned u = __float_as_uint(f);
    u += 0x7fffu + ((u >> 16) & 1u);
    return (unsigned short)(u >> 16);
}
static __device__ __forceinline__ float bfl(unsigned u) {
    return __uint_as_float(u << 16);
}
static __device__ __forceinline__ float bfh(unsigned u) {
    return __uint_as_float(u & 0xffff0000u);
}
static __device__ __forceinline__ float b2f(unsigned short u) {
    return __uint_as_float((unsigned)u << 16);
}

// ---------------- coarse bucket count ----------------
__global__ __launch_bounds__(256) void k_cnt(const int* __restrict__ dstp,
                                             int* __restrict__ bucket_tot) {
    __shared__ int c[NBUCK];
    int tid = threadIdx.x;
    for (int i = tid; i < NBUCK; i += 256) c[i] = 0;
    __syncthreads();
    int tile0 = blockIdx.x * TILE;
#pragma unroll
    for (int j = 0; j < TILE / 256; ++j) {
        int e = tile0 + j * 256 + tid;
        if (e < N_EDGES) atomicAdd(&c[dstp[e] >> BSHIFT], 1);
    }
    __syncthreads();
    for (int i = tid; i < NBUCK; i += 256)
        if (c[i]) atomicAdd(&bucket_tot[i], c[i]);
}

// single-block scan of bucket totals -> bases + cursors; zero pool/pcnt
__global__ __launch_bounds__(256) void k_scanB(const int* __restrict__ tot,
                                               int* __restrict__ base,
                                               int* __restrict__ cursor,
                                               float* __restrict__ pool,
                                               float* __restrict__ pcnt) {
    __shared__ int s[256];
    int tid = threadIdx.x;
    int v = (tid < NBUCK) ? tot[tid] : 0;
    s[tid] = v;
    __syncthreads();
    for (int off = 1; off < 256; off <<= 1) {
        int t = (tid >= off) ? s[tid - off] : 0;
        __syncthreads();
        s[tid] += t;
        __syncthreads();
    }
    if (tid < NBUCK) {
        int b = s[tid] - v;
        base[tid] = b;
        cursor[tid] = b;
    }
    if (tid == 0) base[NBUCK] = N_EDGES;
    for (int i = tid; i < N_GRAPHS * DIM; i += 256) pool[i] = 0.f;
    if (tid < N_GRAPHS) pcnt[tid] = 0.f;
}

// ---------------- Pass A: bin edges into coarse dst-buckets ----------------
// Packed 4B entry: src (16 bits, N_NODES<65536) | (dst&255)<<16.
__global__ __launch_bounds__(256) void k_binA(const int* __restrict__ src,
                                              const int* __restrict__ dstp,
                                              int* __restrict__ bucket_cursor,
                                              unsigned* __restrict__ bucket_arr) {
    __shared__ int cnt[NBUCK];
    __shared__ int base[NBUCK];
    int tile0 = blockIdx.x * TILE;
    for (int i = threadIdx.x; i < NBUCK; i += 256) cnt[i] = 0;
    __syncthreads();
#pragma unroll
    for (int j = 0; j < TILE / 256; ++j) {
        int e = tile0 + j * 256 + threadIdx.x;
        if (e < N_EDGES) atomicAdd(&cnt[dstp[e] >> BSHIFT], 1);
    }
    __syncthreads();
    for (int i = threadIdx.x; i < NBUCK; i += 256) {
        int c = cnt[i];
        base[i] = c ? atomicAdd(&bucket_cursor[i], c) : 0;
        cnt[i] = 0;   // reuse as local cursor
    }
    __syncthreads();
#pragma unroll
    for (int j = 0; j < TILE / 256; ++j) {
        int e = tile0 + j * 256 + threadIdx.x;
        if (e < N_EDGES) {
            int d = dstp[e];
            int b = d >> BSHIFT;
            int p = base[b] + atomicAdd(&cnt[b], 1);
            bucket_arr[p] = (unsigned)src[e] | ((unsigned)(d & 255) << 16);
        }
    }
}

// ---------------- Pass B: fine scatter + per-node degree/rowoff/dis -------
// Block = bucket. LDS histogram -> block scan -> row_off/dis; then staged
// fine scatter; csr entries are 2B (src only).
__global__ __launch_bounds__(256) void k_binB(const unsigned* __restrict__ barr,
                                              const int* __restrict__ base,
                                              int* __restrict__ row_off,
                                              float* __restrict__ dis,
                                              unsigned short* __restrict__ csr) {
    __shared__ unsigned raw[RCAP];
    __shared__ unsigned short stage[RCAP];
    __shared__ int hist[BNODES];
    __shared__ int scn[BNODES];
    int tid = threadIdx.x;
    int b = blockIdx.x;
    int n0 = b << BSHIFT;
    int rbase = base[b];
    int len = base[b + 1] - rbase;

    hist[tid] = 0;
    __syncthreads();
    for (int i = tid; i < len; i += 256) {
        unsigned ed = barr[rbase + i];
        if (i < RCAP) raw[i] = ed;
        atomicAdd(&hist[ed >> 16], 1);
    }
    __syncthreads();
    int v = hist[tid];
    scn[tid] = v;
    __syncthreads();
    for (int off = 1; off < 256; off <<= 1) {
        int t = (tid >= off) ? scn[tid - off] : 0;
        __syncthreads();
        scn[tid] += t;
        __syncthreads();
    }
    int excl = scn[tid] - v;
    int n = n0 + tid;
    if (n < N_NODES) {
        row_off[n] = rbase + excl;
        dis[n] = rsqrtf((float)(v + 1));   // +1 = self-loop
    }
    if (b == NBUCK - 1 && tid == 0) row_off[N_NODES] = N_EDGES;
    hist[tid] = excl;   // reuse as cursor
    __syncthreads();
    for (int i = tid; i < len; i += 256) {
        unsigned ed = (i < RCAP) ? raw[i] : barr[rbase + i];
        int p = atomicAdd(&hist[ed >> 16], 1);
        unsigned short sv = (unsigned short)(ed & 0xffffu);
        if (p < RCAP) stage[p] = sv;
        else csr[rbase + p] = sv;
    }
    __syncthreads();
    int lim = min(len, RCAP);
    for (int i = tid; i < lim; i += 256)
        csr[rbase + i] = stage[i];
}

// ---------------- MFMA GEMM: C[n,128](bf16) = A[n,128] @ W[128,128](f32) ---
// BF16IN=0: A is f32; BF16IN=1: A is bf16 (direct short8 frag loads).
template <int BF16IN>
__global__ __launch_bounds__(256) void k_gemm(const void* __restrict__ Av,
                                              const float* __restrict__ Wg,
                                              unsigned short* __restrict__ C,
                                              int nrows) {
    __shared__ unsigned smem[34816 / 4];   // W stage (32KB) reused for C stage (34.8KB)
    unsigned* Wl = smem;
    {
        int t = threadIdx.x;
        int p = t & 63;
        int kp = p * 2;
        int n0 = (t >> 6) * 32;
        int kstep = kp >> 5;
        int quad = (kp >> 3) & 3;
        int jw = (kp & 7) >> 1;
        const float* r0 = Wg + (size_t)kp * DIM;
        const float* r1 = r0 + DIM;
        int rot = (p >> 2) & 7;
#pragma unroll
        for (int i4 = 0; i4 < 8; ++i4) {
            int nb = ((i4 + rot) & 7) * 4;
            int n = n0 + nb;
            float4 lo = *(const float4*)(r0 + n);
            float4 hi = *(const float4*)(r1 + n);
            const float* lp = &lo.x;
            const float* hp = &hi.x;
#pragma unroll
            for (int ii = 0; ii < 4; ++ii) {
                int nn = n + ii;
                int ct = nn >> 4;
                int l  = quad * 16 + (nn & 15);
                unsigned vlo = f2bf(lp[ii]);
                unsigned vhi = f2bf(hp[ii]);
                Wl[(((kstep * 8 + ct) * 64) + l) * 4 + jw] = vlo | (vhi << 16);
            }
        }
    }
    __syncthreads();

    int wid  = threadIdx.x >> 6;
    int lane = threadIdx.x & 63;
    int m    = lane & 15;
    int quad = lane >> 4;
    int row0 = blockIdx.x * 128 + wid * 32;
    if (row0 >= nrows) return;

    int rA = row0 + m;      if (rA >= nrows) rA = nrows - 1;
    int rB = row0 + 16 + m; if (rB >= nrows) rB = nrows - 1;

    short8 af0[4], af1[4];
    if (BF16IN) {
        const unsigned short* arowA = (const unsigned short*)Av + (size_t)rA * DIM + quad * 8;
        const unsigned short* arowB = (const unsigned short*)Av + (size_t)rB * DIM + quad * 8;
#pragma unroll
        for (int ks = 0; ks < 4; ++ks) {
            af0[ks] = *(const short8*)(arowA + ks * 32);
            af1[ks] = *(const short8*)(arowB + ks * 32);
        }
    } else {
        const float* arowA = (const float*)Av + (size_t)rA * DIM + quad * 8;
        const float* arowB = (const float*)Av + (size_t)rB * DIM + quad * 8;
#pragma unroll
        for (int ks = 0; ks < 4; ++ks) {
            float4 lo = *(const float4*)(arowA + ks * 32);
            float4 hi = *(const float4*)(arowA + ks * 32 + 4);
            short8 f;
            f[0] = (short)f2bf(lo.x); f[1] = (short)f2bf(lo.y);
            f[2] = (short)f2bf(lo.z); f[3] = (short)f2bf(lo.w);
            f[4] = (short)f2bf(hi.x); f[5] = (short)f2bf(hi.y);
            f[6] = (short)f2bf(hi.z); f[7] = (short)f2bf(hi.w);
            af0[ks] = f;
            lo = *(const float4*)(arowB + ks * 32);
            hi = *(const float4*)(arowB + ks * 32 + 4);
            f[0] = (short)f2bf(lo.x); f[1] = (short)f2bf(lo.y);
            f[2] = (short)f2bf(lo.z); f[3] = (short)f2bf(lo.w);
            f[4] = (short)f2bf(hi.x); f[5] = (short)f2bf(hi.y);
            f[6] = (short)f2bf(hi.z); f[7] = (short)f2bf(hi.w);
            af1[ks] = f;
        }
    }

    f32x4 acc0[8], acc1[8];
#pragma unroll
    for (int ct = 0; ct < 8; ++ct) {
        acc0[ct] = (f32x4){0.f, 0.f, 0.f, 0.f};
        acc1[ct] = (f32x4){0.f, 0.f, 0.f, 0.f};
    }

    const short8* Wf = (const short8*)Wl;
#pragma unroll
    for (int ks = 0; ks < 4; ++ks) {
#pragma unroll
        for (int ct = 0; ct < 8; ++ct) {
            short8 bfrag = Wf[(ks * 8 + ct) * 64 + lane];
            acc0[ct] = __builtin_amdgcn_mfma_f32_16x16x32_bf16(af0[ks], bfrag, acc0[ct], 0, 0, 0);
            acc1[ct] = __builtin_amdgcn_mfma_f32_16x16x32_bf16(af1[ks], bfrag, acc1[ct], 0, 0, 0);
        }
    }

    __syncthreads();   // done reading Wl; reuse LDS for C staging
    unsigned short* cs = (unsigned short*)smem + wid * 4352;  // 32 rows x 136 ushorts
#pragma unroll
    for (int ct = 0; ct < 8; ++ct) {
#pragma unroll
        for (int reg = 0; reg < 4; ++reg) {
            cs[(quad * 4 + reg) * 136 + ct * 16 + m]      = f2bf(acc0[ct][reg]);
            cs[(16 + quad * 4 + reg) * 136 + ct * 16 + m] = f2bf(acc1[ct][reg]);
        }
    }
    const unsigned char* cb = (const unsigned char*)smem + wid * 8704;
#pragma unroll
    for (int i = 0; i < 8; ++i) {
        int rg = i * 4 + quad;
        int r = row0 + rg;
        if (r < nrows) {
            uint4 vv = *(const uint4*)(cb + rg * 272 + m * 16);
            *((uint4*)(C + (size_t)r * DIM) + m) = vv;
        }
    }
}

// ---------------- Aggregation (pull, bf16 gather, bf16 out) ----------------
// 16 lanes/node, 16B (8 bf16 channels)/lane; csr = 2B src; w = dn*dis[s].
__global__ __launch_bounds__(256) void k_agg(const uint4* __restrict__ Hb4,
                                             const int* __restrict__ row_off,
                                             const unsigned short* __restrict__ csr,
                                             const float* __restrict__ dis,
                                             const float* __restrict__ bias,
                                             uint4* __restrict__ out) {
    int lane = threadIdx.x & 15;
    int node = blockIdx.x * 16 + (threadIdx.x >> 4);
    if (node >= N_NODES) return;

    float dn = dis[node];
    float wself = dn * dn;
    uint4 hp = Hb4[(size_t)node * 16 + lane];
    float a0[8], a1[8], a2[8], a3[8];
    a0[0] = wself * bfl(hp.x); a0[1] = wself * bfh(hp.x);
    a0[2] = wself * bfl(hp.y); a0[3] = wself * bfh(hp.y);
    a0[4] = wself * bfl(hp.z); a0[5] = wself * bfh(hp.z);
    a0[6] = wself * bfl(hp.w); a0[7] = wself * bfh(hp.w);
#pragma unroll
    for (int j = 0; j < 8; ++j) { a1[j] = 0.f; a2[j] = 0.f; a3[j] = 0.f; }

    int e = row_off[node], e1 = row_off[node + 1];
    for (; e + 4 <= e1; e += 4) {
        int s0 = csr[e];     int s1 = csr[e + 1];
        int s2 = csr[e + 2]; int s3 = csr[e + 3];
        uint4 g0 = Hb4[(size_t)s0 * 16 + lane];
        uint4 g1 = Hb4[(size_t)s1 * 16 + lane];
        uint4 g2 = Hb4[(size_t)s2 * 16 + lane];
        uint4 g3 = Hb4[(size_t)s3 * 16 + lane];
        float w0 = dn * dis[s0], w1 = dn * dis[s1];
        float w2 = dn * dis[s2], w3 = dn * dis[s3];
        a0[0] = fmaf(w0, bfl(g0.x), a0[0]); a0[1] = fmaf(w0, bfh(g0.x), a0[1]);
        a0[2] = fmaf(w0, bfl(g0.y), a0[2]); a0[3] = fmaf(w0, bfh(g0.y), a0[3]);
        a0[4] = fmaf(w0, bfl(g0.z), a0[4]); a0[5] = fmaf(w0, bfh(g0.z), a0[5]);
        a0[6] = fmaf(w0, bfl(g0.w), a0[6]); a0[7] = fmaf(w0, bfh(g0.w), a0[7]);
        a1[0] = fmaf(w1, bfl(g1.x), a1[0]); a1[1] = fmaf(w1, bfh(g1.x), a1[1]);
        a1[2] = fmaf(w1, bfl(g1.y), a1[2]); a1[3] = fmaf(w1, bfh(g1.y), a1[3]);
        a1[4] = fmaf(w1, bfl(g1.z), a1[4]); a1[5] = fmaf(w1, bfh(g1.z), a1[5]);
        a1[6] = fmaf(w1, bfl(g1.w), a1[6]); a1[7] = fmaf(w1, bfh(g1.w), a1[7]);
        a2[0] = fmaf(w2, bfl(g2.x), a2[0]); a2[1] = fmaf(w2, bfh(g2.x), a2[1]);
        a2[2] = fmaf(w2, bfl(g2.y), a2[2]); a2[3] = fmaf(w2, bfh(g2.y), a2[3]);
        a2[4] = fmaf(w2, bfl(g2.z), a2[4]); a2[5] = fmaf(w2, bfh(g2.z), a2[5]);
        a2[6] = fmaf(w2, bfl(g2.w), a2[6]); a2[7] = fmaf(w2, bfh(g2.w), a2[7]);
        a3[0] = fmaf(w3, bfl(g3.x), a3[0]); a3[1] = fmaf(w3, bfh(g3.x), a3[1]);
        a3[2] = fmaf(w3, bfl(g3.y), a3[2]); a3[3] = fmaf(w3, bfh(g3.y), a3[3]);
        a3[4] = fmaf(w3, bfl(g3.z), a3[4]); a3[5] = fmaf(w3, bfh(g3.z), a3[5]);
        a3[6] = fmaf(w3, bfl(g3.w), a3[6]); a3[7] = fmaf(w3, bfh(g3.w), a3[7]);
    }
    for (; e < e1; ++e) {
        int s = csr[e];
        uint4 g = Hb4[(size_t)s * 16 + lane];
        float w = dn * dis[s];
        a0[0] = fmaf(w, bfl(g.x), a0[0]); a0[1] = fmaf(w, bfh(g.x), a0[1]);
        a0[2] = fmaf(w, bfl(g.y), a0[2]); a0[3] = fmaf(w, bfh(g.y), a0[3]);
        a0[4] = fmaf(w, bfl(g.z), a0[4]); a0[5] = fmaf(w, bfh(g.z), a0[5]);
        a0[6] = fmaf(w, bfl(g.w), a0[6]); a0[7] = fmaf(w, bfh(g.w), a0[7]);
    }

    float4 b0 = ((const float4*)bias)[lane * 2];
    float4 b1v = ((const float4*)bias)[lane * 2 + 1];
    float r[8];
    r[0] = fmaxf(a0[0] + a1[0] + a2[0] + a3[0] + b0.x, 0.f);
    r[1] = fmaxf(a0[1] + a1[1] + a2[1] + a3[1] + b0.y, 0.f);
    r[2] = fmaxf(a0[2] + a1[2] + a2[2] + a3[2] + b0.z, 0.f);
    r[3] = fmaxf(a0[3] + a1[3] + a2[3] + a3[3] + b0.w, 0.f);
    r[4] = fmaxf(a0[4] + a1[4] + a2[4] + a3[4] + b1v.x, 0.f);
    r[5] = fmaxf(a0[5] + a1[5] + a2[5] + a3[5] + b1v.y, 0.f);
    r[6] = fmaxf(a0[6] + a1[6] + a2[6] + a3[6] + b1v.z, 0.f);
    r[7] = fmaxf(a0[7] + a1[7] + a2[7] + a3[7] + b1v.w, 0.f);
    uint4 ov;
    ov.x = (unsigned)f2bf(r[0]) | ((unsigned)f2bf(r[1]) << 16);
    ov.y = (unsigned)f2bf(r[2]) | ((unsigned)f2bf(r[3]) << 16);
    ov.z = (unsigned)f2bf(r[4]) | ((unsigned)f2bf(r[5]) << 16);
    ov.w = (unsigned)f2bf(r[6]) | ((unsigned)f2bf(r[7]) << 16);
    out[(size_t)node * 16 + lane] = ov;
}

// ---------------- Mean pool (bf16 in, parallel + ILP-4) ----------------
__global__ __launch_bounds__(128) void k_pool(const unsigned short* __restrict__ h,
                                              const int* __restrict__ batch,
                                              float* __restrict__ pool,
                                              float* __restrict__ pcnt) {
    int chunk = (N_NODES + POOL_BLOCKS - 1) / POOL_BLOCKS;
    int n0 = blockIdx.x * chunk;
    int n1 = min(n0 + chunk, N_NODES);
    if (n0 >= n1) return;
    int c = threadIdx.x;
    int curg = batch[n0];
    float acc = 0.f;
    int count = 0;
    int n = n0;
    for (; n + 4 <= n1; ) {
        int g0 = batch[n], g3 = batch[n + 3];
        if (g0 == curg && g3 == curg) {
            float v0 = b2f(h[(size_t)(n + 0) * DIM + c]);
            float v1 = b2f(h[(size_t)(n + 1) * DIM + c]);
            float v2 = b2f(h[(size_t)(n + 2) * DIM + c]);
            float v3 = b2f(h[(size_t)(n + 3) * DIM + c]);
            acc += (v0 + v1) + (v2 + v3);
            count += 4;
            n += 4;
        } else {
            int g = g0;
            if (g != curg) {
                atomicAdd(&pool[curg * DIM + c], acc);
                if (c == 0) atomicAdd(&pcnt[curg], (float)count);
                acc = 0.f; count = 0; curg = g;
            }
            acc += b2f(h[(size_t)n * DIM + c]);
            count++;
            n += 1;
        }
    }
    for (; n < n1; ++n) {
        int g = batch[n];
        if (g != curg) {
            atomicAdd(&pool[curg * DIM + c], acc);
            if (c == 0) atomicAdd(&pcnt[curg], (float)count);
            acc = 0.f; count = 0; curg = g;
        }
        acc += b2f(h[(size_t)n * DIM + c]);
        count++;
    }
    atomicAdd(&pool[curg * DIM + c], acc);
    if (c == 0) atomicAdd(&pcnt[curg], (float)count);
}

// ---------------- Final FC ----------------
__global__ void k_fc(const float* __restrict__ pool, const float* __restrict__ pcnt,
                     const float* __restrict__ Wfc, const float* __restrict__ bfc,
                     float* __restrict__ out) {
    int id = blockIdx.x * blockDim.x + threadIdx.x;
    if (id >= N_GRAPHS * OUTD) return;
    int g = id >> 4, o = id & 15;
    float inv = 1.0f / fmaxf(pcnt[g], 1.0f);
    float acc = bfc[o];
    const float* p = pool + g * DIM;
    for (int c = 0; c < DIM; ++c)
        acc = fmaf(p[c] * inv, Wfc[c * OUTD + o], acc);
    out[id] = acc;
}

// ---------------- launch ----------------

extern "C" void kernel_launch(void* const* d_in, const int* in_sizes, int n_in,
                              void* d_out, int out_size, void* d_ws, size_t ws_size,
                              hipStream_t stream) {
    const float* x    = (const float*)d_in[0];
    const int*   ei   = (const int*)d_in[1];
    const int*   batch= (const int*)d_in[2];
    const float* W1   = (const float*)d_in[3];
    const float* b1   = (const float*)d_in[4];
    const float* W2   = (const float*)d_in[5];
    const float* b2   = (const float*)d_in[6];
    const float* Wfc  = (const float*)d_in[7];
    const float* bfc  = (const float*)d_in[8];
    float* out = (float*)d_out;

    char* ws = (char*)d_ws;
    size_t off = 0;
    auto alloc = [&](size_t bytes) -> char* {
        char* p = ws + off;
        off = (off + bytes + 255) & ~(size_t)255;
        return p;
    };
    int*      btot     = (int*)     alloc((size_t)NBUCK * 4);
    int*      bbase    = (int*)     alloc((size_t)(NBUCK + 1) * 4);
    int*      bcursor  = (int*)     alloc((size_t)NBUCK * 4);
    int*      row_off  = (int*)     alloc((size_t)(N_NODES + 1) * 4);
    float*    dis      = (float*)   alloc((size_t)N_NODES * 4);
    unsigned short* csr= (unsigned short*)alloc((size_t)N_EDGES * 2);
    unsigned* barr     = (unsigned*)alloc((size_t)N_EDGES * 4);
    float*    pool     = (float*)   alloc((size_t)N_GRAPHS * DIM * 4);
    float*    pcnt     = (float*)   alloc((size_t)N_GRAPHS * 4);
    unsigned short* Hb = (unsigned short*)alloc((size_t)N_NODES * DIM * 2);
    unsigned short* Hb2= (unsigned short*)alloc((size_t)N_NODES * DIM * 2);

    const int* src = ei;
    const int* dst = ei + N_EDGES;

    hipMemsetAsync(btot, 0, (size_t)NBUCK * 4, stream);

    int bin_grid = (N_EDGES + TILE - 1) / TILE;   // 391
    k_cnt<<<bin_grid, 256, 0, stream>>>(dst, btot);
    k_scanB<<<1, 256, 0, stream>>>(btot, bbase, bcursor, pool, pcnt);
    k_binA<<<bin_grid, 256, 0, stream>>>(src, dst, bcursor, barr);
    k_binB<<<NBUCK, 256, 0, stream>>>(barr, bbase, row_off, dis, csr);

    int gemm_grid = (N_NODES + 127) / 128;  // 391
    int agg_grid  = (N_NODES + 15) / 16;    // 3125
    // layer 1: gemm f32->bf16, agg bf16->bf16
    k_gemm<0><<<gemm_grid, 256, 0, stream>>>(x, W1, Hb, N_NODES);
    k_agg<<<agg_grid, 256, 0, stream>>>((const uint4*)Hb, row_off, csr, dis, b1, (uint4*)Hb2);
    // layer 2: gemm bf16->bf16, agg bf16->bf16
    k_gemm<1><<<gemm_grid, 256, 0, stream>>>(Hb2, W2, Hb, N_NODES);
    k_agg<<<agg_grid, 256, 0, stream>>>((const uint4*)Hb, row_off, csr, dis, b2, (uint4*)Hb2);
    // pool + fc
    k_pool<<<POOL_BLOCKS, DIM, 0, stream>>>(Hb2, batch, pool, pcnt);
    k_fc<<<(N_GRAPHS * OUTD + 255) / 256, 256, 0, stream>>>(pool, pcnt, Wfc, bfc, out);
}

// Round 10
// 219.502 us; speedup vs baseline: 1.9903x; 1.0704x over previous
//
#include <hip/hip_runtime.h>
#include <math.h>

#define N_NODES 50000
#define N_EDGES 800000
#define N_GRAPHS 64
#define DIM 128
#define OUTD 16
#define POOL_BLOCKS 1024

// bucketed CSR build: 256 nodes per bucket, STATIC bucket regions
#define BSHIFT 8
#define BNODES 256
#define NBUCK ((N_NODES + BNODES - 1) / BNODES)   // 196
#define TILE 2048                                  // edges per binning block
#define RCAP 8192                                  // LDS stage capacity (entries)
#define BSLOT 4864                                 // static region size (mean 4096 + 12 sigma)

typedef __attribute__((ext_vector_type(8))) short short8;
typedef __attribute__((ext_vector_type(4))) float f32x4;

// ---- bf16 helpers (round-to-nearest-even; values are finite) ----
static __device__ __forceinline__ unsigned short f2bf(float f) {
    unsigned u = __float_as_uint(f);
    u += 0x7fffu + ((u >> 16) & 1u);
    return (unsigned short)(u >> 16);
}
static __device__ __forceinline__ float bfl(unsigned u) {
    return __uint_as_float(u << 16);
}
static __device__ __forceinline__ float bfh(unsigned u) {
    return __uint_as_float(u & 0xffff0000u);
}
static __device__ __forceinline__ float b2f(unsigned short u) {
    return __uint_as_float((unsigned)u << 16);
}

// ---------------- init: static bucket cursors + zero pool/pcnt ----------------
__global__ __launch_bounds__(256) void k_init(int* __restrict__ cursor,
                                              float* __restrict__ pool,
                                              float* __restrict__ pcnt) {
    int tid = threadIdx.x;
    if (tid < NBUCK) cursor[tid] = tid * BSLOT;
    for (int i = tid; i < N_GRAPHS * DIM; i += 256) pool[i] = 0.f;
    if (tid < N_GRAPHS) pcnt[tid] = 0.f;
}

// ---------------- Pass A: bin edges into static coarse dst-buckets ----------
// Packed 4B entry: src (16 bits, N_NODES<65536) | (dst&255)<<16. int2 loads.
__global__ __launch_bounds__(256) void k_binA(const int* __restrict__ src,
                                              const int* __restrict__ dstp,
                                              int* __restrict__ bucket_cursor,
                                              unsigned* __restrict__ bucket_arr) {
    __shared__ int cnt[NBUCK];
    __shared__ int base[NBUCK];
    int tile0 = blockIdx.x * TILE;
    for (int i = threadIdx.x; i < NBUCK; i += 256) cnt[i] = 0;
    __syncthreads();
#pragma unroll
    for (int j = 0; j < TILE / 512; ++j) {
        int e = tile0 + j * 512 + threadIdx.x * 2;
        if (e < N_EDGES) {    // N_EDGES even, e even -> pair complete
            int2 d = *(const int2*)(dstp + e);
            atomicAdd(&cnt[d.x >> BSHIFT], 1);
            atomicAdd(&cnt[d.y >> BSHIFT], 1);
        }
    }
    __syncthreads();
    for (int i = threadIdx.x; i < NBUCK; i += 256) {
        int c = cnt[i];
        base[i] = c ? atomicAdd(&bucket_cursor[i], c) : 0;
        cnt[i] = 0;   // reuse as local cursor
    }
    __syncthreads();
#pragma unroll
    for (int j = 0; j < TILE / 512; ++j) {
        int e = tile0 + j * 512 + threadIdx.x * 2;
        if (e < N_EDGES) {
            int2 s = *(const int2*)(src + e);
            int2 d = *(const int2*)(dstp + e);
            int b0 = d.x >> BSHIFT, b1 = d.y >> BSHIFT;
            int p0 = base[b0] + atomicAdd(&cnt[b0], 1);
            bucket_arr[p0] = (unsigned)s.x | ((unsigned)(d.x & 255) << 16);
            int p1 = base[b1] + atomicAdd(&cnt[b1], 1);
            bucket_arr[p1] = (unsigned)s.y | ((unsigned)(d.y & 255) << 16);
        }
    }
}

// ---------------- bases: scan bucket counts (cursor - static base) ----------
__global__ __launch_bounds__(256) void k_bases(const int* __restrict__ cursor,
                                               int* __restrict__ base) {
    __shared__ int s[256];
    int tid = threadIdx.x;
    int v = (tid < NBUCK) ? (cursor[tid] - tid * BSLOT) : 0;
    s[tid] = v;
    __syncthreads();
    for (int off = 1; off < 256; off <<= 1) {
        int t = (tid >= off) ? s[tid - off] : 0;
        __syncthreads();
        s[tid] += t;
        __syncthreads();
    }
    if (tid <= NBUCK) base[tid] = s[tid] - v;   // tid==NBUCK: v=0 -> total = N_EDGES
}

// ---------------- Pass B: fine scatter + per-node degree/rowoff/dis -------
// Block = bucket. Reads static region barr[b*BSLOT .. +len); LDS histogram ->
// block scan -> row_off/dis; staged fine scatter; csr entries 2B (src only).
__global__ __launch_bounds__(256) void k_binB(const unsigned* __restrict__ barr,
                                              const int* __restrict__ base,
                                              int* __restrict__ row_off,
                                              float* __restrict__ dis,
                                              unsigned short* __restrict__ csr) {
    __shared__ unsigned raw[RCAP];
    __shared__ unsigned short stage[RCAP];
    __shared__ int hist[BNODES];
    __shared__ int scn[BNODES];
    int tid = threadIdx.x;
    int b = blockIdx.x;
    int n0 = b << BSHIFT;
    int rbase = base[b];
    int len = base[b + 1] - rbase;
    const unsigned* bin = barr + (size_t)b * BSLOT;

    hist[tid] = 0;
    __syncthreads();
    for (int i = tid; i < len; i += 256) {
        unsigned ed = bin[i];
        if (i < RCAP) raw[i] = ed;
        atomicAdd(&hist[ed >> 16], 1);
    }
    __syncthreads();
    int v = hist[tid];
    scn[tid] = v;
    __syncthreads();
    for (int off = 1; off < 256; off <<= 1) {
        int t = (tid >= off) ? scn[tid - off] : 0;
        __syncthreads();
        scn[tid] += t;
        __syncthreads();
    }
    int excl = scn[tid] - v;
    int n = n0 + tid;
    if (n < N_NODES) {
        row_off[n] = rbase + excl;
        dis[n] = rsqrtf((float)(v + 1));   // +1 = self-loop
    }
    if (b == NBUCK - 1 && tid == 0) row_off[N_NODES] = N_EDGES;
    hist[tid] = excl;   // reuse as cursor
    __syncthreads();
    for (int i = tid; i < len; i += 256) {
        unsigned ed = (i < RCAP) ? raw[i] : bin[i];
        int p = atomicAdd(&hist[ed >> 16], 1);
        unsigned short sv = (unsigned short)(ed & 0xffffu);
        if (p < RCAP) stage[p] = sv;
        else csr[rbase + p] = sv;
    }
    __syncthreads();
    int lim = min(len, RCAP);
    for (int i = tid; i < lim; i += 256)
        csr[rbase + i] = stage[i];
}

// ---------------- MFMA GEMM: C[n,128](bf16) = A[n,128] @ W[128,128](f32) ---
// 256 persistent blocks, tile loop: W staged ONCE per block. C staged in a
// separate LDS region (no post-MFMA barrier; each wave's region is private).
template <int BF16IN>
__global__ __launch_bounds__(256) void k_gemm(const void* __restrict__ Av,
                                              const float* __restrict__ Wg,
                                              unsigned short* __restrict__ C,
                                              int nrows) {
    __shared__ unsigned smemW[32768 / 4];
    __shared__ unsigned smemC[34816 / 4];
    unsigned* Wl = smemW;
    {
        int t = threadIdx.x;
        int p = t & 63;
        int kp = p * 2;
        int n0 = (t >> 6) * 32;
        int kstep = kp >> 5;
        int quad = (kp >> 3) & 3;
        int jw = (kp & 7) >> 1;
        const float* r0 = Wg + (size_t)kp * DIM;
        const float* r1 = r0 + DIM;
        int rot = (p >> 2) & 7;
#pragma unroll
        for (int i4 = 0; i4 < 8; ++i4) {
            int nb = ((i4 + rot) & 7) * 4;
            int n = n0 + nb;
            float4 lo = *(const float4*)(r0 + n);
            float4 hi = *(const float4*)(r1 + n);
            const float* lp = &lo.x;
            const float* hp = &hi.x;
#pragma unroll
            for (int ii = 0; ii < 4; ++ii) {
                int nn = n + ii;
                int ct = nn >> 4;
                int l  = quad * 16 + (nn & 15);
                unsigned vlo = f2bf(lp[ii]);
                unsigned vhi = f2bf(hp[ii]);
                Wl[(((kstep * 8 + ct) * 64) + l) * 4 + jw] = vlo | (vhi << 16);
            }
        }
    }
    __syncthreads();

    int wid  = threadIdx.x >> 6;
    int lane = threadIdx.x & 63;
    int m    = lane & 15;
    int quad = lane >> 4;
    const short8* Wf = (const short8*)Wl;
    unsigned short* cs = (unsigned short*)smemC + wid * 4352;  // 32 rows x 136 ushorts
    const unsigned char* cb = (const unsigned char*)smemC + wid * 8704;

    int ntiles = (nrows + 127) / 128;
    for (int tile = blockIdx.x; tile < ntiles; tile += gridDim.x) {
        int row0 = tile * 128 + wid * 32;
        if (row0 >= nrows) continue;

        int rA = row0 + m;      if (rA >= nrows) rA = nrows - 1;
        int rB = row0 + 16 + m; if (rB >= nrows) rB = nrows - 1;

        short8 af0[4], af1[4];
        if (BF16IN) {
            const unsigned short* arowA = (const unsigned short*)Av + (size_t)rA * DIM + quad * 8;
            const unsigned short* arowB = (const unsigned short*)Av + (size_t)rB * DIM + quad * 8;
#pragma unroll
            for (int ks = 0; ks < 4; ++ks) {
                af0[ks] = *(const short8*)(arowA + ks * 32);
                af1[ks] = *(const short8*)(arowB + ks * 32);
            }
        } else {
            const float* arowA = (const float*)Av + (size_t)rA * DIM + quad * 8;
            const float* arowB = (const float*)Av + (size_t)rB * DIM + quad * 8;
#pragma unroll
            for (int ks = 0; ks < 4; ++ks) {
                float4 lo = *(const float4*)(arowA + ks * 32);
                float4 hi = *(const float4*)(arowA + ks * 32 + 4);
                short8 f;
                f[0] = (short)f2bf(lo.x); f[1] = (short)f2bf(lo.y);
                f[2] = (short)f2bf(lo.z); f[3] = (short)f2bf(lo.w);
                f[4] = (short)f2bf(hi.x); f[5] = (short)f2bf(hi.y);
                f[6] = (short)f2bf(hi.z); f[7] = (short)f2bf(hi.w);
                af0[ks] = f;
                lo = *(const float4*)(arowB + ks * 32);
                hi = *(const float4*)(arowB + ks * 32 + 4);
                f[0] = (short)f2bf(lo.x); f[1] = (short)f2bf(lo.y);
                f[2] = (short)f2bf(lo.z); f[3] = (short)f2bf(lo.w);
                f[4] = (short)f2bf(hi.x); f[5] = (short)f2bf(hi.y);
                f[6] = (short)f2bf(hi.z); f[7] = (short)f2bf(hi.w);
                af1[ks] = f;
            }
        }

        f32x4 acc0[8], acc1[8];
#pragma unroll
        for (int ct = 0; ct < 8; ++ct) {
            acc0[ct] = (f32x4){0.f, 0.f, 0.f, 0.f};
            acc1[ct] = (f32x4){0.f, 0.f, 0.f, 0.f};
        }

#pragma unroll
        for (int ks = 0; ks < 4; ++ks) {
#pragma unroll
            for (int ct = 0; ct < 8; ++ct) {
                short8 bfrag = Wf[(ks * 8 + ct) * 64 + lane];
                acc0[ct] = __builtin_amdgcn_mfma_f32_16x16x32_bf16(af0[ks], bfrag, acc0[ct], 0, 0, 0);
                acc1[ct] = __builtin_amdgcn_mfma_f32_16x16x32_bf16(af1[ks], bfrag, acc1[ct], 0, 0, 0);
            }
        }

        // C staging: wave-private region, no barrier needed
#pragma unroll
        for (int ct = 0; ct < 8; ++ct) {
#pragma unroll
            for (int reg = 0; reg < 4; ++reg) {
                cs[(quad * 4 + reg) * 136 + ct * 16 + m]      = f2bf(acc0[ct][reg]);
                cs[(16 + quad * 4 + reg) * 136 + ct * 16 + m] = f2bf(acc1[ct][reg]);
            }
        }
#pragma unroll
        for (int i = 0; i < 8; ++i) {
            int rg = i * 4 + quad;
            int r = row0 + rg;
            if (r < nrows) {
                uint4 vv = *(const uint4*)(cb + rg * 272 + m * 16);
                *((uint4*)(C + (size_t)r * DIM) + m) = vv;
            }
        }
    }
}

// ---------------- Aggregation (pull, bf16 gather, bf16 out) ----------------
__global__ __launch_bounds__(256) void k_agg(const uint4* __restrict__ Hb4,
                                             const int* __restrict__ row_off,
                                             const unsigned short* __restrict__ csr,
                                             const float* __restrict__ dis,
                                             const float* __restrict__ bias,
                                             uint4* __restrict__ out) {
    int lane = threadIdx.x & 15;
    int node = blockIdx.x * 16 + (threadIdx.x >> 4);
    if (node >= N_NODES) return;

    float dn = dis[node];
    float wself = dn * dn;
    uint4 hp = Hb4[(size_t)node * 16 + lane];
    float a0[8], a1[8], a2[8], a3[8];
    a0[0] = wself * bfl(hp.x); a0[1] = wself * bfh(hp.x);
    a0[2] = wself * bfl(hp.y); a0[3] = wself * bfh(hp.y);
    a0[4] = wself * bfl(hp.z); a0[5] = wself * bfh(hp.z);
    a0[6] = wself * bfl(hp.w); a0[7] = wself * bfh(hp.w);
#pragma unroll
    for (int j = 0; j < 8; ++j) { a1[j] = 0.f; a2[j] = 0.f; a3[j] = 0.f; }

    int e = row_off[node], e1 = row_off[node + 1];
    for (; e + 4 <= e1; e += 4) {
        int s0 = csr[e];     int s1 = csr[e + 1];
        int s2 = csr[e + 2]; int s3 = csr[e + 3];
        uint4 g0 = Hb4[(size_t)s0 * 16 + lane];
        uint4 g1 = Hb4[(size_t)s1 * 16 + lane];
        uint4 g2 = Hb4[(size_t)s2 * 16 + lane];
        uint4 g3 = Hb4[(size_t)s3 * 16 + lane];
        float w0 = dn * dis[s0], w1 = dn * dis[s1];
        float w2 = dn * dis[s2], w3 = dn * dis[s3];
        a0[0] = fmaf(w0, bfl(g0.x), a0[0]); a0[1] = fmaf(w0, bfh(g0.x), a0[1]);
        a0[2] = fmaf(w0, bfl(g0.y), a0[2]); a0[3] = fmaf(w0, bfh(g0.y), a0[3]);
        a0[4] = fmaf(w0, bfl(g0.z), a0[4]); a0[5] = fmaf(w0, bfh(g0.z), a0[5]);
        a0[6] = fmaf(w0, bfl(g0.w), a0[6]); a0[7] = fmaf(w0, bfh(g0.w), a0[7]);
        a1[0] = fmaf(w1, bfl(g1.x), a1[0]); a1[1] = fmaf(w1, bfh(g1.x), a1[1]);
        a1[2] = fmaf(w1, bfl(g1.y), a1[2]); a1[3] = fmaf(w1, bfh(g1.y), a1[3]);
        a1[4] = fmaf(w1, bfl(g1.z), a1[4]); a1[5] = fmaf(w1, bfh(g1.z), a1[5]);
        a1[6] = fmaf(w1, bfl(g1.w), a1[6]); a1[7] = fmaf(w1, bfh(g1.w), a1[7]);
        a2[0] = fmaf(w2, bfl(g2.x), a2[0]); a2[1] = fmaf(w2, bfh(g2.x), a2[1]);
        a2[2] = fmaf(w2, bfl(g2.y), a2[2]); a2[3] = fmaf(w2, bfh(g2.y), a2[3]);
        a2[4] = fmaf(w2, bfl(g2.z), a2[4]); a2[5] = fmaf(w2, bfh(g2.z), a2[5]);
        a2[6] = fmaf(w2, bfl(g2.w), a2[6]); a2[7] = fmaf(w2, bfh(g2.w), a2[7]);
        a3[0] = fmaf(w3, bfl(g3.x), a3[0]); a3[1] = fmaf(w3, bfh(g3.x), a3[1]);
        a3[2] = fmaf(w3, bfl(g3.y), a3[2]); a3[3] = fmaf(w3, bfh(g3.y), a3[3]);
        a3[4] = fmaf(w3, bfl(g3.z), a3[4]); a3[5] = fmaf(w3, bfh(g3.z), a3[5]);
        a3[6] = fmaf(w3, bfl(g3.w), a3[6]); a3[7] = fmaf(w3, bfh(g3.w), a3[7]);
    }
    for (; e < e1; ++e) {
        int s = csr[e];
        uint4 g = Hb4[(size_t)s * 16 + lane];
        float w = dn * dis[s];
        a0[0] = fmaf(w, bfl(g.x), a0[0]); a0[1] = fmaf(w, bfh(g.x), a0[1]);
        a0[2] = fmaf(w, bfl(g.y), a0[2]); a0[3] = fmaf(w, bfh(g.y), a0[3]);
        a0[4] = fmaf(w, bfl(g.z), a0[4]); a0[5] = fmaf(w, bfh(g.z), a0[5]);
        a0[6] = fmaf(w, bfl(g.w), a0[6]); a0[7] = fmaf(w, bfh(g.w), a0[7]);
    }

    float4 b0 = ((const float4*)bias)[lane * 2];
    float4 b1v = ((const float4*)bias)[lane * 2 + 1];
    float r[8];
    r[0] = fmaxf(a0[0] + a1[0] + a2[0] + a3[0] + b0.x, 0.f);
    r[1] = fmaxf(a0[1] + a1[1] + a2[1] + a3[1] + b0.y, 0.f);
    r[2] = fmaxf(a0[2] + a1[2] + a2[2] + a3[2] + b0.z, 0.f);
    r[3] = fmaxf(a0[3] + a1[3] + a2[3] + a3[3] + b0.w, 0.f);
    r[4] = fmaxf(a0[4] + a1[4] + a2[4] + a3[4] + b1v.x, 0.f);
    r[5] = fmaxf(a0[5] + a1[5] + a2[5] + a3[5] + b1v.y, 0.f);
    r[6] = fmaxf(a0[6] + a1[6] + a2[6] + a3[6] + b1v.z, 0.f);
    r[7] = fmaxf(a0[7] + a1[7] + a2[7] + a3[7] + b1v.w, 0.f);
    uint4 ov;
    ov.x = (unsigned)f2bf(r[0]) | ((unsigned)f2bf(r[1]) << 16);
    ov.y = (unsigned)f2bf(r[2]) | ((unsigned)f2bf(r[3]) << 16);
    ov.z = (unsigned)f2bf(r[4]) | ((unsigned)f2bf(r[5]) << 16);
    ov.w = (unsigned)f2bf(r[6]) | ((unsigned)f2bf(r[7]) << 16);
    out[(size_t)node * 16 + lane] = ov;
}

// ---------------- Mean pool (bf16 in, parallel + ILP-4) ----------------
__global__ __launch_bounds__(128) void k_pool(const unsigned short* __restrict__ h,
                                              const int* __restrict__ batch,
                                              float* __restrict__ pool,
                                              float* __restrict__ pcnt) {
    int chunk = (N_NODES + POOL_BLOCKS - 1) / POOL_BLOCKS;
    int n0 = blockIdx.x * chunk;
    int n1 = min(n0 + chunk, N_NODES);
    if (n0 >= n1) return;
    int c = threadIdx.x;
    int curg = batch[n0];
    float acc = 0.f;
    int count = 0;
    int n = n0;
    for (; n + 4 <= n1; ) {
        int g0 = batch[n], g3 = batch[n + 3];
        if (g0 == curg && g3 == curg) {
            float v0 = b2f(h[(size_t)(n + 0) * DIM + c]);
            float v1 = b2f(h[(size_t)(n + 1) * DIM + c]);
            float v2 = b2f(h[(size_t)(n + 2) * DIM + c]);
            float v3 = b2f(h[(size_t)(n + 3) * DIM + c]);
            acc += (v0 + v1) + (v2 + v3);
            count += 4;
            n += 4;
        } else {
            int g = g0;
            if (g != curg) {
                atomicAdd(&pool[curg * DIM + c], acc);
                if (c == 0) atomicAdd(&pcnt[curg], (float)count);
                acc = 0.f; count = 0; curg = g;
            }
            acc += b2f(h[(size_t)n * DIM + c]);
            count++;
            n += 1;
        }
    }
    for (; n < n1; ++n) {
        int g = batch[n];
        if (g != curg) {
            atomicAdd(&pool[curg * DIM + c], acc);
            if (c == 0) atomicAdd(&pcnt[curg], (float)count);
            acc = 0.f; count = 0; curg = g;
        }
        acc += b2f(h[(size_t)n * DIM + c]);
        count++;
    }
    atomicAdd(&pool[curg * DIM + c], acc);
    if (c == 0) atomicAdd(&pcnt[curg], (float)count);
}

// ---------------- Final FC ----------------
__global__ void k_fc(const float* __restrict__ pool, const float* __restrict__ pcnt,
                     const float* __restrict__ Wfc, const float* __restrict__ bfc,
                     float* __restrict__ out) {
    int id = blockIdx.x * blockDim.x + threadIdx.x;
    if (id >= N_GRAPHS * OUTD) return;
    int g = id >> 4, o = id & 15;
    float inv = 1.0f / fmaxf(pcnt[g], 1.0f);
    float acc = bfc[o];
    const float* p = pool + g * DIM;
    for (int c = 0; c < DIM; ++c)
        acc = fmaf(p[c] * inv, Wfc[c * OUTD + o], acc);
    out[id] = acc;
}

// ---------------- launch ----------------

extern "C" void kernel_launch(void* const* d_in, const int* in_sizes, int n_in,
                              void* d_out, int out_size, void* d_ws, size_t ws_size,
                              hipStream_t stream) {
    const float* x    = (const float*)d_in[0];
    const int*   ei   = (const int*)d_in[1];
    const int*   batch= (const int*)d_in[2];
    const float* W1   = (const float*)d_in[3];
    const float* b1   = (const float*)d_in[4];
    const float* W2   = (const float*)d_in[5];
    const float* b2   = (const float*)d_in[6];
    const float* Wfc  = (const float*)d_in[7];
    const float* bfc  = (const float*)d_in[8];
    float* out = (float*)d_out;

    char* ws = (char*)d_ws;
    size_t off = 0;
    auto alloc = [&](size_t bytes) -> char* {
        char* p = ws + off;
        off = (off + bytes + 255) & ~(size_t)255;
        return p;
    };
    int*      bbase    = (int*)     alloc((size_t)(NBUCK + 1) * 4);
    int*      bcursor  = (int*)     alloc((size_t)NBUCK * 4);
    int*      row_off  = (int*)     alloc((size_t)(N_NODES + 1) * 4);
    float*    dis      = (float*)   alloc((size_t)N_NODES * 4);
    unsigned short* csr= (unsigned short*)alloc((size_t)N_EDGES * 2);
    unsigned* barr     = (unsigned*)alloc((size_t)NBUCK * BSLOT * 4);
    float*    pool     = (float*)   alloc((size_t)N_GRAPHS * DIM * 4);
    float*    pcnt     = (float*)   alloc((size_t)N_GRAPHS * 4);
    unsigned short* Hb = (unsigned short*)alloc((size_t)N_NODES * DIM * 2);
    unsigned short* Hb2= (unsigned short*)alloc((size_t)N_NODES * DIM * 2);

    const int* src = ei;
    const int* dst = ei + N_EDGES;

    int bin_grid = (N_EDGES + TILE - 1) / TILE;   // 391
    k_init<<<1, 256, 0, stream>>>(bcursor, pool, pcnt);
    k_binA<<<bin_grid, 256, 0, stream>>>(src, dst, bcursor, barr);
    k_bases<<<1, 256, 0, stream>>>(bcursor, bbase);
    k_binB<<<NBUCK, 256, 0, stream>>>(barr, bbase, row_off, dis, csr);

    int agg_grid = (N_NODES + 15) / 16;    // 3125
    // layer 1: gemm f32->bf16, agg bf16->bf16
    k_gemm<0><<<256, 256, 0, stream>>>(x, W1, Hb, N_NODES);
    k_agg<<<agg_grid, 256, 0, stream>>>((const uint4*)Hb, row_off, csr, dis, b1, (uint4*)Hb2);
    // layer 2: gemm bf16->bf16, agg bf16->bf16
    k_gemm<1><<<256, 256, 0, stream>>>(Hb2, W2, Hb, N_NODES);
    k_agg<<<agg_grid, 256, 0, stream>>>((const uint4*)Hb, row_off, csr, dis, b2, (uint4*)Hb2);
    // pool + fc
    k_pool<<<POOL_BLOCKS, DIM, 0, stream>>>(Hb2, batch, pool, pcnt);
    k_fc<<<(N_GRAPHS * OUTD + 255) / 256, 256, 0, stream>>>(pool, pcnt, Wfc, bfc, out);
}

// Round 11
// 207.908 us; speedup vs baseline: 2.1013x; 1.0558x over previous
//
#include <hip/hip_runtime.h>
#include <math.h>

#define N_NODES 50000
#define N_EDGES 800000
#define N_GRAPHS 64
#define DIM 128
#define OUTD 16
#define POOL_BLOCKS 1024

// bucketed CSR build: 256 nodes per bucket, STATIC bucket regions
#define BSHIFT 8
#define BNODES 256
#define NBUCK ((N_NODES + BNODES - 1) / BNODES)   // 196
#define TILE 2048                                  // edges per binning block
#define RCAP 8192                                  // LDS stage capacity (entries)
#define BSLOT 4864                                 // static region (mean 4096 + 12 sigma)
#define GEMMB 256                                  // persistent gemm blocks
#define BIN_GRID ((N_EDGES + TILE - 1) / TILE)     // 391

typedef __attribute__((ext_vector_type(8))) short short8;
typedef __attribute__((ext_vector_type(4))) float f32x4;

// ---- bf16 helpers (round-to-nearest-even; values are finite) ----
static __device__ __forceinline__ unsigned short f2bf(float f) {
    unsigned u = __float_as_uint(f);
    u += 0x7fffu + ((u >> 16) & 1u);
    return (unsigned short)(u >> 16);
}
static __device__ __forceinline__ float bfl(unsigned u) {
    return __uint_as_float(u << 16);
}
static __device__ __forceinline__ float bfh(unsigned u) {
    return __uint_as_float(u & 0xffff0000u);
}
static __device__ __forceinline__ float b2f(unsigned short u) {
    return __uint_as_float((unsigned)u << 16);
}

// ---------------- init: zero bucket counts + pool/pcnt ----------------
__global__ __launch_bounds__(256) void k_init(int* __restrict__ bcnt,
                                              float* __restrict__ pool,
                                              float* __restrict__ pcnt) {
    int tid = threadIdx.x;
    if (tid < NBUCK) bcnt[tid] = 0;
    for (int i = tid; i < N_GRAPHS * DIM; i += 256) pool[i] = 0.f;
    if (tid < N_GRAPHS) pcnt[tid] = 0.f;
}

// ---------------- shared GEMM body (W in LDS, MFMA, LDS C-stage) ----------
template <int BF16IN>
static __device__ __forceinline__ void gemm_body(const void* __restrict__ Av,
                                                 const float* __restrict__ Wg,
                                                 unsigned short* __restrict__ C,
                                                 int nrows,
                                                 unsigned* smemW, unsigned* smemC,
                                                 int tile0, int tstride) {
    unsigned* Wl = smemW;
    {
        int t = threadIdx.x;
        int p = t & 63;
        int kp = p * 2;
        int n0 = (t >> 6) * 32;
        int kstep = kp >> 5;
        int quad = (kp >> 3) & 3;
        int jw = (kp & 7) >> 1;
        const float* r0 = Wg + (size_t)kp * DIM;
        const float* r1 = r0 + DIM;
        int rot = (p >> 2) & 7;
#pragma unroll
        for (int i4 = 0; i4 < 8; ++i4) {
            int nb = ((i4 + rot) & 7) * 4;
            int n = n0 + nb;
            float4 lo = *(const float4*)(r0 + n);
            float4 hi = *(const float4*)(r1 + n);
            const float* lp = &lo.x;
            const float* hp = &hi.x;
#pragma unroll
            for (int ii = 0; ii < 4; ++ii) {
                int nn = n + ii;
                int ct = nn >> 4;
                int l  = quad * 16 + (nn & 15);
                unsigned vlo = f2bf(lp[ii]);
                unsigned vhi = f2bf(hp[ii]);
                Wl[(((kstep * 8 + ct) * 64) + l) * 4 + jw] = vlo | (vhi << 16);
            }
        }
    }
    __syncthreads();

    int wid  = threadIdx.x >> 6;
    int lane = threadIdx.x & 63;
    int m    = lane & 15;
    int quad = lane >> 4;
    const short8* Wf = (const short8*)Wl;
    unsigned short* cs = (unsigned short*)smemC + wid * 4352;  // 32 rows x 136 ushorts
    const unsigned char* cb = (const unsigned char*)smemC + wid * 8704;

    int ntiles = (nrows + 127) / 128;
    for (int tile = tile0; tile < ntiles; tile += tstride) {
        int row0 = tile * 128 + wid * 32;
        if (row0 >= nrows) continue;

        int rA = row0 + m;      if (rA >= nrows) rA = nrows - 1;
        int rB = row0 + 16 + m; if (rB >= nrows) rB = nrows - 1;

        short8 af0[4], af1[4];
        if (BF16IN) {
            const unsigned short* arowA = (const unsigned short*)Av + (size_t)rA * DIM + quad * 8;
            const unsigned short* arowB = (const unsigned short*)Av + (size_t)rB * DIM + quad * 8;
#pragma unroll
            for (int ks = 0; ks < 4; ++ks) {
                af0[ks] = *(const short8*)(arowA + ks * 32);
                af1[ks] = *(const short8*)(arowB + ks * 32);
            }
        } else {
            const float* arowA = (const float*)Av + (size_t)rA * DIM + quad * 8;
            const float* arowB = (const float*)Av + (size_t)rB * DIM + quad * 8;
#pragma unroll
            for (int ks = 0; ks < 4; ++ks) {
                float4 lo = *(const float4*)(arowA + ks * 32);
                float4 hi = *(const float4*)(arowA + ks * 32 + 4);
                short8 f;
                f[0] = (short)f2bf(lo.x); f[1] = (short)f2bf(lo.y);
                f[2] = (short)f2bf(lo.z); f[3] = (short)f2bf(lo.w);
                f[4] = (short)f2bf(hi.x); f[5] = (short)f2bf(hi.y);
                f[6] = (short)f2bf(hi.z); f[7] = (short)f2bf(hi.w);
                af0[ks] = f;
                lo = *(const float4*)(arowB + ks * 32);
                hi = *(const float4*)(arowB + ks * 32 + 4);
                f[0] = (short)f2bf(lo.x); f[1] = (short)f2bf(lo.y);
                f[2] = (short)f2bf(lo.z); f[3] = (short)f2bf(lo.w);
                f[4] = (short)f2bf(hi.x); f[5] = (short)f2bf(hi.y);
                f[6] = (short)f2bf(hi.z); f[7] = (short)f2bf(hi.w);
                af1[ks] = f;
            }
        }

        f32x4 acc0[8], acc1[8];
#pragma unroll
        for (int ct = 0; ct < 8; ++ct) {
            acc0[ct] = (f32x4){0.f, 0.f, 0.f, 0.f};
            acc1[ct] = (f32x4){0.f, 0.f, 0.f, 0.f};
        }

#pragma unroll
        for (int ks = 0; ks < 4; ++ks) {
#pragma unroll
            for (int ct = 0; ct < 8; ++ct) {
                short8 bfrag = Wf[(ks * 8 + ct) * 64 + lane];
                acc0[ct] = __builtin_amdgcn_mfma_f32_16x16x32_bf16(af0[ks], bfrag, acc0[ct], 0, 0, 0);
                acc1[ct] = __builtin_amdgcn_mfma_f32_16x16x32_bf16(af1[ks], bfrag, acc1[ct], 0, 0, 0);
            }
        }

        // C staging: wave-private region, no barrier needed
#pragma unroll
        for (int ct = 0; ct < 8; ++ct) {
#pragma unroll
            for (int reg = 0; reg < 4; ++reg) {
                cs[(quad * 4 + reg) * 136 + ct * 16 + m]      = f2bf(acc0[ct][reg]);
                cs[(16 + quad * 4 + reg) * 136 + ct * 16 + m] = f2bf(acc1[ct][reg]);
            }
        }
#pragma unroll
        for (int i = 0; i < 8; ++i) {
            int rg = i * 4 + quad;
            int r = row0 + rg;
            if (r < nrows) {
                uint4 vv = *(const uint4*)(cb + rg * 272 + m * 16);
                *((uint4*)(C + (size_t)r * DIM) + m) = vv;
            }
        }
    }
}

// ---------------- fused layer-1 GEMM + binA (independent work) ------------
// blocks [0,GEMMB): persistent gemm; blocks [GEMMB, GEMMB+BIN_GRID): binA.
__global__ __launch_bounds__(256) void k_fused1(const float* __restrict__ A,
                                                const float* __restrict__ Wg,
                                                unsigned short* __restrict__ C,
                                                int nrows,
                                                const int* __restrict__ src,
                                                const int* __restrict__ dstp,
                                                int* __restrict__ bcnt,
                                                unsigned* __restrict__ bucket_arr) {
    __shared__ unsigned smemW[32768 / 4];
    __shared__ unsigned smemC[34816 / 4];
    if (blockIdx.x >= GEMMB) {
        // ---- binA tile: packed 4B entry src | (dst&255)<<16, static regions ----
        int* cnt  = (int*)smemW;
        int* base = cnt + NBUCK;
        int tile0 = (blockIdx.x - GEMMB) * TILE;
        for (int i = threadIdx.x; i < NBUCK; i += 256) cnt[i] = 0;
        __syncthreads();
#pragma unroll
        for (int j = 0; j < TILE / 512; ++j) {
            int e = tile0 + j * 512 + threadIdx.x * 2;
            if (e < N_EDGES) {
                int2 d = *(const int2*)(dstp + e);
                atomicAdd(&cnt[d.x >> BSHIFT], 1);
                atomicAdd(&cnt[d.y >> BSHIFT], 1);
            }
        }
        __syncthreads();
        for (int i = threadIdx.x; i < NBUCK; i += 256) {
            int c = cnt[i];
            base[i] = i * BSLOT + (c ? atomicAdd(&bcnt[i], c) : 0);
            cnt[i] = 0;   // reuse as local cursor
        }
        __syncthreads();
#pragma unroll
        for (int j = 0; j < TILE / 512; ++j) {
            int e = tile0 + j * 512 + threadIdx.x * 2;
            if (e < N_EDGES) {
                int2 s = *(const int2*)(src + e);
                int2 d = *(const int2*)(dstp + e);
                int b0 = d.x >> BSHIFT, b1 = d.y >> BSHIFT;
                int p0 = base[b0] + atomicAdd(&cnt[b0], 1);
                bucket_arr[p0] = (unsigned)s.x | ((unsigned)(d.x & 255) << 16);
                int p1 = base[b1] + atomicAdd(&cnt[b1], 1);
                bucket_arr[p1] = (unsigned)s.y | ((unsigned)(d.y & 255) << 16);
            }
        }
        return;
    }
    gemm_body<0>(A, Wg, C, nrows, smemW, smemC, blockIdx.x, GEMMB);
}

// ---------------- layer-2 GEMM (bf16 input) ----------------
__global__ __launch_bounds__(256) void k_gemm2(const unsigned short* __restrict__ A,
                                               const float* __restrict__ Wg,
                                               unsigned short* __restrict__ C,
                                               int nrows) {
    __shared__ unsigned smemW[32768 / 4];
    __shared__ unsigned smemC[34816 / 4];
    gemm_body<1>(A, Wg, C, nrows, smemW, smemC, blockIdx.x, gridDim.x);
}

// ---------------- Pass B: bases scan + fine scatter + degree/rowoff/dis ----
// Block = bucket. Each block redundantly scans the 196 bucket counts (L2-hot)
// -> rbase; then LDS histogram -> row_off/dis; staged fine scatter; 2B csr.
__global__ __launch_bounds__(256) void k_binB(const unsigned* __restrict__ barr,
                                              const int* __restrict__ bcnt,
                                              int* __restrict__ row_off,
                                              float* __restrict__ dis,
                                              unsigned short* __restrict__ csr) {
    __shared__ unsigned raw[RCAP];
    __shared__ unsigned short stage[RCAP];
    __shared__ int hist[BNODES];
    __shared__ int scn[BNODES];
    __shared__ int borig[256], bscan[256];
    int tid = threadIdx.x;
    int b = blockIdx.x;
    int n0 = b << BSHIFT;

    // bucket-level prefix (redundant per block; 196 ints, trivial)
    int cv = (tid < NBUCK) ? bcnt[tid] : 0;
    borig[tid] = cv;
    bscan[tid] = cv;
    __syncthreads();
    for (int off = 1; off < 256; off <<= 1) {
        int t = (tid >= off) ? bscan[tid - off] : 0;
        __syncthreads();
        bscan[tid] += t;
        __syncthreads();
    }
    int rbase = bscan[b] - borig[b];
    int len = borig[b];
    const unsigned* bin = barr + (size_t)b * BSLOT;

    hist[tid] = 0;
    __syncthreads();
    for (int i = tid; i < len; i += 256) {
        unsigned ed = bin[i];
        if (i < RCAP) raw[i] = ed;
        atomicAdd(&hist[ed >> 16], 1);
    }
    __syncthreads();
    int v = hist[tid];
    scn[tid] = v;
    __syncthreads();
    for (int off = 1; off < 256; off <<= 1) {
        int t = (tid >= off) ? scn[tid - off] : 0;
        __syncthreads();
        scn[tid] += t;
        __syncthreads();
    }
    int excl = scn[tid] - v;
    int n = n0 + tid;
    if (n < N_NODES) {
        row_off[n] = rbase + excl;
        dis[n] = rsqrtf((float)(v + 1));   // +1 = self-loop
    }
    if (b == NBUCK - 1 && tid == 0) row_off[N_NODES] = N_EDGES;
    hist[tid] = excl;   // reuse as cursor
    __syncthreads();
    for (int i = tid; i < len; i += 256) {
        unsigned ed = (i < RCAP) ? raw[i] : bin[i];
        int p = atomicAdd(&hist[ed >> 16], 1);
        unsigned short sv = (unsigned short)(ed & 0xffffu);
        if (p < RCAP) stage[p] = sv;
        else csr[rbase + p] = sv;
    }
    __syncthreads();
    int lim = min(len, RCAP);
    for (int i = tid; i < lim; i += 256)
        csr[rbase + i] = stage[i];
}

// ---------------- Aggregation (pull, bf16 gather, bf16 out) ----------------
__global__ __launch_bounds__(256) void k_agg(const uint4* __restrict__ Hb4,
                                             const int* __restrict__ row_off,
                                             const unsigned short* __restrict__ csr,
                                             const float* __restrict__ dis,
                                             const float* __restrict__ bias,
                                             uint4* __restrict__ out) {
    int lane = threadIdx.x & 15;
    int node = blockIdx.x * 16 + (threadIdx.x >> 4);
    if (node >= N_NODES) return;

    float dn = dis[node];
    float wself = dn * dn;
    uint4 hp = Hb4[(size_t)node * 16 + lane];
    float a0[8], a1[8], a2[8], a3[8];
    a0[0] = wself * bfl(hp.x); a0[1] = wself * bfh(hp.x);
    a0[2] = wself * bfl(hp.y); a0[3] = wself * bfh(hp.y);
    a0[4] = wself * bfl(hp.z); a0[5] = wself * bfh(hp.z);
    a0[6] = wself * bfl(hp.w); a0[7] = wself * bfh(hp.w);
#pragma unroll
    for (int j = 0; j < 8; ++j) { a1[j] = 0.f; a2[j] = 0.f; a3[j] = 0.f; }

    int e = row_off[node], e1 = row_off[node + 1];
    for (; e + 4 <= e1; e += 4) {
        int s0 = csr[e];     int s1 = csr[e + 1];
        int s2 = csr[e + 2]; int s3 = csr[e + 3];
        uint4 g0 = Hb4[(size_t)s0 * 16 + lane];
        uint4 g1 = Hb4[(size_t)s1 * 16 + lane];
        uint4 g2 = Hb4[(size_t)s2 * 16 + lane];
        uint4 g3 = Hb4[(size_t)s3 * 16 + lane];
        float w0 = dn * dis[s0], w1 = dn * dis[s1];
        float w2 = dn * dis[s2], w3 = dn * dis[s3];
        a0[0] = fmaf(w0, bfl(g0.x), a0[0]); a0[1] = fmaf(w0, bfh(g0.x), a0[1]);
        a0[2] = fmaf(w0, bfl(g0.y), a0[2]); a0[3] = fmaf(w0, bfh(g0.y), a0[3]);
        a0[4] = fmaf(w0, bfl(g0.z), a0[4]); a0[5] = fmaf(w0, bfh(g0.z), a0[5]);
        a0[6] = fmaf(w0, bfl(g0.w), a0[6]); a0[7] = fmaf(w0, bfh(g0.w), a0[7]);
        a1[0] = fmaf(w1, bfl(g1.x), a1[0]); a1[1] = fmaf(w1, bfh(g1.x), a1[1]);
        a1[2] = fmaf(w1, bfl(g1.y), a1[2]); a1[3] = fmaf(w1, bfh(g1.y), a1[3]);
        a1[4] = fmaf(w1, bfl(g1.z), a1[4]); a1[5] = fmaf(w1, bfh(g1.z), a1[5]);
        a1[6] = fmaf(w1, bfl(g1.w), a1[6]); a1[7] = fmaf(w1, bfh(g1.w), a1[7]);
        a2[0] = fmaf(w2, bfl(g2.x), a2[0]); a2[1] = fmaf(w2, bfh(g2.x), a2[1]);
        a2[2] = fmaf(w2, bfl(g2.y), a2[2]); a2[3] = fmaf(w2, bfh(g2.y), a2[3]);
        a2[4] = fmaf(w2, bfl(g2.z), a2[4]); a2[5] = fmaf(w2, bfh(g2.z), a2[5]);
        a2[6] = fmaf(w2, bfl(g2.w), a2[6]); a2[7] = fmaf(w2, bfh(g2.w), a2[7]);
        a3[0] = fmaf(w3, bfl(g3.x), a3[0]); a3[1] = fmaf(w3, bfh(g3.x), a3[1]);
        a3[2] = fmaf(w3, bfl(g3.y), a3[2]); a3[3] = fmaf(w3, bfh(g3.y), a3[3]);
        a3[4] = fmaf(w3, bfl(g3.z), a3[4]); a3[5] = fmaf(w3, bfh(g3.z), a3[5]);
        a3[6] = fmaf(w3, bfl(g3.w), a3[6]); a3[7] = fmaf(w3, bfh(g3.w), a3[7]);
    }
    for (; e < e1; ++e) {
        int s = csr[e];
        uint4 g = Hb4[(size_t)s * 16 + lane];
        float w = dn * dis[s];
        a0[0] = fmaf(w, bfl(g.x), a0[0]); a0[1] = fmaf(w, bfh(g.x), a0[1]);
        a0[2] = fmaf(w, bfl(g.y), a0[2]); a0[3] = fmaf(w, bfh(g.y), a0[3]);
        a0[4] = fmaf(w, bfl(g.z), a0[4]); a0[5] = fmaf(w, bfh(g.z), a0[5]);
        a0[6] = fmaf(w, bfl(g.w), a0[6]); a0[7] = fmaf(w, bfh(g.w), a0[7]);
    }

    float4 b0 = ((const float4*)bias)[lane * 2];
    float4 b1v = ((const float4*)bias)[lane * 2 + 1];
    float r[8];
    r[0] = fmaxf(a0[0] + a1[0] + a2[0] + a3[0] + b0.x, 0.f);
    r[1] = fmaxf(a0[1] + a1[1] + a2[1] + a3[1] + b0.y, 0.f);
    r[2] = fmaxf(a0[2] + a1[2] + a2[2] + a3[2] + b0.z, 0.f);
    r[3] = fmaxf(a0[3] + a1[3] + a2[3] + a3[3] + b0.w, 0.f);
    r[4] = fmaxf(a0[4] + a1[4] + a2[4] + a3[4] + b1v.x, 0.f);
    r[5] = fmaxf(a0[5] + a1[5] + a2[5] + a3[5] + b1v.y, 0.f);
    r[6] = fmaxf(a0[6] + a1[6] + a2[6] + a3[6] + b1v.z, 0.f);
    r[7] = fmaxf(a0[7] + a1[7] + a2[7] + a3[7] + b1v.w, 0.f);
    uint4 ov;
    ov.x = (unsigned)f2bf(r[0]) | ((unsigned)f2bf(r[1]) << 16);
    ov.y = (unsigned)f2bf(r[2]) | ((unsigned)f2bf(r[3]) << 16);
    ov.z = (unsigned)f2bf(r[4]) | ((unsigned)f2bf(r[5]) << 16);
    ov.w = (unsigned)f2bf(r[6]) | ((unsigned)f2bf(r[7]) << 16);
    out[(size_t)node * 16 + lane] = ov;
}

// ---------------- Mean pool (bf16 in, parallel + ILP-4) ----------------
__global__ __launch_bounds__(128) void k_pool(const unsigned short* __restrict__ h,
                                              const int* __restrict__ batch,
                                              float* __restrict__ pool,
                                              float* __restrict__ pcnt) {
    int chunk = (N_NODES + POOL_BLOCKS - 1) / POOL_BLOCKS;
    int n0 = blockIdx.x * chunk;
    int n1 = min(n0 + chunk, N_NODES);
    if (n0 >= n1) return;
    int c = threadIdx.x;
    int curg = batch[n0];
    float acc = 0.f;
    int count = 0;
    int n = n0;
    for (; n + 4 <= n1; ) {
        int g0 = batch[n], g3 = batch[n + 3];
        if (g0 == curg && g3 == curg) {
            float v0 = b2f(h[(size_t)(n + 0) * DIM + c]);
            float v1 = b2f(h[(size_t)(n + 1) * DIM + c]);
            float v2 = b2f(h[(size_t)(n + 2) * DIM + c]);
            float v3 = b2f(h[(size_t)(n + 3) * DIM + c]);
            acc += (v0 + v1) + (v2 + v3);
            count += 4;
            n += 4;
        } else {
            int g = g0;
            if (g != curg) {
                atomicAdd(&pool[curg * DIM + c], acc);
                if (c == 0) atomicAdd(&pcnt[curg], (float)count);
                acc = 0.f; count = 0; curg = g;
            }
            acc += b2f(h[(size_t)n * DIM + c]);
            count++;
            n += 1;
        }
    }
    for (; n < n1; ++n) {
        int g = batch[n];
        if (g != curg) {
            atomicAdd(&pool[curg * DIM + c], acc);
            if (c == 0) atomicAdd(&pcnt[curg], (float)count);
            acc = 0.f; count = 0; curg = g;
        }
        acc += b2f(h[(size_t)n * DIM + c]);
        count++;
    }
    atomicAdd(&pool[curg * DIM + c], acc);
    if (c == 0) atomicAdd(&pcnt[curg], (float)count);
}

// ---------------- Final FC ----------------
__global__ void k_fc(const float* __restrict__ pool, const float* __restrict__ pcnt,
                     const float* __restrict__ Wfc, const float* __restrict__ bfc,
                     float* __restrict__ out) {
    int id = blockIdx.x * blockDim.x + threadIdx.x;
    if (id >= N_GRAPHS * OUTD) return;
    int g = id >> 4, o = id & 15;
    float inv = 1.0f / fmaxf(pcnt[g], 1.0f);
    float acc = bfc[o];
    const float* p = pool + g * DIM;
    for (int c = 0; c < DIM; ++c)
        acc = fmaf(p[c] * inv, Wfc[c * OUTD + o], acc);
    out[id] = acc;
}

// ---------------- launch ----------------

extern "C" void kernel_launch(void* const* d_in, const int* in_sizes, int n_in,
                              void* d_out, int out_size, void* d_ws, size_t ws_size,
                              hipStream_t stream) {
    const float* x    = (const float*)d_in[0];
    const int*   ei   = (const int*)d_in[1];
    const int*   batch= (const int*)d_in[2];
    const float* W1   = (const float*)d_in[3];
    const float* b1   = (const float*)d_in[4];
    const float* W2   = (const float*)d_in[5];
    const float* b2   = (const float*)d_in[6];
    const float* Wfc  = (const float*)d_in[7];
    const float* bfc  = (const float*)d_in[8];
    float* out = (float*)d_out;

    char* ws = (char*)d_ws;
    size_t off = 0;
    auto alloc = [&](size_t bytes) -> char* {
        char* p = ws + off;
        off = (off + bytes + 255) & ~(size_t)255;
        return p;
    };
    int*      bcnt     = (int*)     alloc((size_t)NBUCK * 4);
    int*      row_off  = (int*)     alloc((size_t)(N_NODES + 1) * 4);
    float*    dis      = (float*)   alloc((size_t)N_NODES * 4);
    unsigned short* csr= (unsigned short*)alloc((size_t)N_EDGES * 2);
    unsigned* barr     = (unsigned*)alloc((size_t)NBUCK * BSLOT * 4);
    float*    pool     = (float*)   alloc((size_t)N_GRAPHS * DIM * 4);
    float*    pcnt     = (float*)   alloc((size_t)N_GRAPHS * 4);
    unsigned short* Hb = (unsigned short*)alloc((size_t)N_NODES * DIM * 2);
    unsigned short* Hb2= (unsigned short*)alloc((size_t)N_NODES * DIM * 2);

    const int* src = ei;
    const int* dst = ei + N_EDGES;

    k_init<<<1, 256, 0, stream>>>(bcnt, pool, pcnt);
    // fused: layer-1 GEMM (f32 -> bf16) runs concurrently with edge binning
    k_fused1<<<GEMMB + BIN_GRID, 256, 0, stream>>>(x, W1, Hb, N_NODES,
                                                   src, dst, bcnt, barr);
    k_binB<<<NBUCK, 256, 0, stream>>>(barr, bcnt, row_off, dis, csr);

    int agg_grid = (N_NODES + 15) / 16;    // 3125
    k_agg<<<agg_grid, 256, 0, stream>>>((const uint4*)Hb, row_off, csr, dis, b1, (uint4*)Hb2);
    k_gemm2<<<GEMMB, 256, 0, stream>>>(Hb2, W2, Hb, N_NODES);
    k_agg<<<agg_grid, 256, 0, stream>>>((const uint4*)Hb, row_off, csr, dis, b2, (uint4*)Hb2);
    k_pool<<<POOL_BLOCKS, DIM, 0, stream>>>(Hb2, batch, pool, pcnt);
    k_fc<<<(N_GRAPHS * OUTD + 255) / 256, 256, 0, stream>>>(pool, pcnt, Wfc, bfc, out);
}

// Round 12
// 203.857 us; speedup vs baseline: 2.1431x; 1.0199x over previous
//
#include <hip/hip_runtime.h>
#include <math.h>

#define N_NODES 50000
#define N_EDGES 800000
#define N_GRAPHS 64
#define DIM 128
#define OUTD 16

// bucketed CSR build: 256 nodes per bucket, STATIC bucket regions
#define BSHIFT 8
#define BNODES 256
#define NBUCK ((N_NODES + BNODES - 1) / BNODES)   // 196
#define TILE 2048                                  // edges per binning block
#define RCAP 8192                                  // LDS stage capacity (entries)
#define BSLOT 4864                                 // static region (mean 4096 + 12 sigma)
#define GEMMB 256                                  // persistent gemm blocks
#define BIN_GRID ((N_EDGES + TILE - 1) / TILE)     // 391

typedef __attribute__((ext_vector_type(8))) short short8;
typedef __attribute__((ext_vector_type(4))) float f32x4;

// ---- bf16 helpers (round-to-nearest-even; values are finite) ----
static __device__ __forceinline__ unsigned short f2bf(float f) {
    unsigned u = __float_as_uint(f);
    u += 0x7fffu + ((u >> 16) & 1u);
    return (unsigned short)(u >> 16);
}
static __device__ __forceinline__ float bfl(unsigned u) {
    return __uint_as_float(u << 16);
}
static __device__ __forceinline__ float bfh(unsigned u) {
    return __uint_as_float(u & 0xffff0000u);
}

// ---------------- init: zero bucket counts + pool ----------------
__global__ __launch_bounds__(256) void k_init(int* __restrict__ bcnt,
                                              float* __restrict__ pool) {
    int tid = threadIdx.x;
    if (tid < NBUCK) bcnt[tid] = 0;
    for (int i = tid; i < N_GRAPHS * DIM; i += 256) pool[i] = 0.f;
}

// ---------------- shared GEMM body (W in LDS, MFMA, LDS C-stage) ----------
template <int BF16IN>
static __device__ __forceinline__ void gemm_body(const void* __restrict__ Av,
                                                 const float* __restrict__ Wg,
                                                 unsigned short* __restrict__ C,
                                                 int nrows,
                                                 unsigned* smemW, unsigned* smemC,
                                                 int tile0, int tstride) {
    unsigned* Wl = smemW;
    {
        int t = threadIdx.x;
        int p = t & 63;
        int kp = p * 2;
        int n0 = (t >> 6) * 32;
        int kstep = kp >> 5;
        int quad = (kp >> 3) & 3;
        int jw = (kp & 7) >> 1;
        const float* r0 = Wg + (size_t)kp * DIM;
        const float* r1 = r0 + DIM;
        int rot = (p >> 2) & 7;
#pragma unroll
        for (int i4 = 0; i4 < 8; ++i4) {
            int nb = ((i4 + rot) & 7) * 4;
            int n = n0 + nb;
            float4 lo = *(const float4*)(r0 + n);
            float4 hi = *(const float4*)(r1 + n);
            const float* lp = &lo.x;
            const float* hp = &hi.x;
#pragma unroll
            for (int ii = 0; ii < 4; ++ii) {
                int nn = n + ii;
                int ct = nn >> 4;
                int l  = quad * 16 + (nn & 15);
                unsigned vlo = f2bf(lp[ii]);
                unsigned vhi = f2bf(hp[ii]);
                Wl[(((kstep * 8 + ct) * 64) + l) * 4 + jw] = vlo | (vhi << 16);
            }
        }
    }
    __syncthreads();

    int wid  = threadIdx.x >> 6;
    int lane = threadIdx.x & 63;
    int m    = lane & 15;
    int quad = lane >> 4;
    const short8* Wf = (const short8*)Wl;
    unsigned short* cs = (unsigned short*)smemC + wid * 4352;  // 32 rows x 136 ushorts
    const unsigned char* cb = (const unsigned char*)smemC + wid * 8704;

    int ntiles = (nrows + 127) / 128;
    for (int tile = tile0; tile < ntiles; tile += tstride) {
        int row0 = tile * 128 + wid * 32;
        if (row0 >= nrows) continue;

        int rA = row0 + m;      if (rA >= nrows) rA = nrows - 1;
        int rB = row0 + 16 + m; if (rB >= nrows) rB = nrows - 1;

        short8 af0[4], af1[4];
        if (BF16IN) {
            const unsigned short* arowA = (const unsigned short*)Av + (size_t)rA * DIM + quad * 8;
            const unsigned short* arowB = (const unsigned short*)Av + (size_t)rB * DIM + quad * 8;
#pragma unroll
            for (int ks = 0; ks < 4; ++ks) {
                af0[ks] = *(const short8*)(arowA + ks * 32);
                af1[ks] = *(const short8*)(arowB + ks * 32);
            }
        } else {
            const float* arowA = (const float*)Av + (size_t)rA * DIM + quad * 8;
            const float* arowB = (const float*)Av + (size_t)rB * DIM + quad * 8;
#pragma unroll
            for (int ks = 0; ks < 4; ++ks) {
                float4 lo = *(const float4*)(arowA + ks * 32);
                float4 hi = *(const float4*)(arowA + ks * 32 + 4);
                short8 f;
                f[0] = (short)f2bf(lo.x); f[1] = (short)f2bf(lo.y);
                f[2] = (short)f2bf(lo.z); f[3] = (short)f2bf(lo.w);
                f[4] = (short)f2bf(hi.x); f[5] = (short)f2bf(hi.y);
                f[6] = (short)f2bf(hi.z); f[7] = (short)f2bf(hi.w);
                af0[ks] = f;
                lo = *(const float4*)(arowB + ks * 32);
                hi = *(const float4*)(arowB + ks * 32 + 4);
                f[0] = (short)f2bf(lo.x); f[1] = (short)f2bf(lo.y);
                f[2] = (short)f2bf(lo.z); f[3] = (short)f2bf(lo.w);
                f[4] = (short)f2bf(hi.x); f[5] = (short)f2bf(hi.y);
                f[6] = (short)f2bf(hi.z); f[7] = (short)f2bf(hi.w);
                af1[ks] = f;
            }
        }

        f32x4 acc0[8], acc1[8];
#pragma unroll
        for (int ct = 0; ct < 8; ++ct) {
            acc0[ct] = (f32x4){0.f, 0.f, 0.f, 0.f};
            acc1[ct] = (f32x4){0.f, 0.f, 0.f, 0.f};
        }

#pragma unroll
        for (int ks = 0; ks < 4; ++ks) {
#pragma unroll
            for (int ct = 0; ct < 8; ++ct) {
                short8 bfrag = Wf[(ks * 8 + ct) * 64 + lane];
                acc0[ct] = __builtin_amdgcn_mfma_f32_16x16x32_bf16(af0[ks], bfrag, acc0[ct], 0, 0, 0);
                acc1[ct] = __builtin_amdgcn_mfma_f32_16x16x32_bf16(af1[ks], bfrag, acc1[ct], 0, 0, 0);
            }
        }

        // C staging: wave-private region, no barrier needed
#pragma unroll
        for (int ct = 0; ct < 8; ++ct) {
#pragma unroll
            for (int reg = 0; reg < 4; ++reg) {
                cs[(quad * 4 + reg) * 136 + ct * 16 + m]      = f2bf(acc0[ct][reg]);
                cs[(16 + quad * 4 + reg) * 136 + ct * 16 + m] = f2bf(acc1[ct][reg]);
            }
        }
#pragma unroll
        for (int i = 0; i < 8; ++i) {
            int rg = i * 4 + quad;
            int r = row0 + rg;
            if (r < nrows) {
                uint4 vv = *(const uint4*)(cb + rg * 272 + m * 16);
                *((uint4*)(C + (size_t)r * DIM) + m) = vv;
            }
        }
    }
}

// ---------------- fused layer-1 GEMM + binA (independent work) ------------
__global__ __launch_bounds__(256) void k_fused1(const float* __restrict__ A,
                                                const float* __restrict__ Wg,
                                                unsigned short* __restrict__ C,
                                                int nrows,
                                                const int* __restrict__ src,
                                                const int* __restrict__ dstp,
                                                int* __restrict__ bcnt,
                                                unsigned* __restrict__ bucket_arr) {
    __shared__ unsigned smemW[32768 / 4];
    __shared__ unsigned smemC[34816 / 4];
    if (blockIdx.x >= GEMMB) {
        int* cnt  = (int*)smemW;
        int* base = cnt + NBUCK;
        int tile0 = (blockIdx.x - GEMMB) * TILE;
        for (int i = threadIdx.x; i < NBUCK; i += 256) cnt[i] = 0;
        __syncthreads();
#pragma unroll
        for (int j = 0; j < TILE / 512; ++j) {
            int e = tile0 + j * 512 + threadIdx.x * 2;
            if (e < N_EDGES) {
                int2 d = *(const int2*)(dstp + e);
                atomicAdd(&cnt[d.x >> BSHIFT], 1);
                atomicAdd(&cnt[d.y >> BSHIFT], 1);
            }
        }
        __syncthreads();
        for (int i = threadIdx.x; i < NBUCK; i += 256) {
            int c = cnt[i];
            base[i] = i * BSLOT + (c ? atomicAdd(&bcnt[i], c) : 0);
            cnt[i] = 0;   // reuse as local cursor
        }
        __syncthreads();
#pragma unroll
        for (int j = 0; j < TILE / 512; ++j) {
            int e = tile0 + j * 512 + threadIdx.x * 2;
            if (e < N_EDGES) {
                int2 s = *(const int2*)(src + e);
                int2 d = *(const int2*)(dstp + e);
                int b0 = d.x >> BSHIFT, b1 = d.y >> BSHIFT;
                int p0 = base[b0] + atomicAdd(&cnt[b0], 1);
                bucket_arr[p0] = (unsigned)s.x | ((unsigned)(d.x & 255) << 16);
                int p1 = base[b1] + atomicAdd(&cnt[b1], 1);
                bucket_arr[p1] = (unsigned)s.y | ((unsigned)(d.y & 255) << 16);
            }
        }
        return;
    }
    gemm_body<0>(A, Wg, C, nrows, smemW, smemC, blockIdx.x, GEMMB);
}

// ---------------- layer-2 GEMM (bf16 input) ----------------
__global__ __launch_bounds__(256) void k_gemm2(const unsigned short* __restrict__ A,
                                               const float* __restrict__ Wg,
                                               unsigned short* __restrict__ C,
                                               int nrows) {
    __shared__ unsigned smemW[32768 / 4];
    __shared__ unsigned smemC[34816 / 4];
    gemm_body<1>(A, Wg, C, nrows, smemW, smemC, blockIdx.x, gridDim.x);
}

// ---------------- Pass B: bases scan + fine scatter + degree/rowoff/dis ----
__global__ __launch_bounds__(256) void k_binB(const unsigned* __restrict__ barr,
                                              const int* __restrict__ bcnt,
                                              int* __restrict__ row_off,
                                              float* __restrict__ dis,
                                              unsigned short* __restrict__ csr) {
    __shared__ unsigned raw[RCAP];
    __shared__ unsigned short stage[RCAP];
    __shared__ int hist[BNODES];
    __shared__ int scn[BNODES];
    __shared__ int borig[256], bscan[256];
    int tid = threadIdx.x;
    int b = blockIdx.x;
    int n0 = b << BSHIFT;

    int cv = (tid < NBUCK) ? bcnt[tid] : 0;
    borig[tid] = cv;
    bscan[tid] = cv;
    __syncthreads();
    for (int off = 1; off < 256; off <<= 1) {
        int t = (tid >= off) ? bscan[tid - off] : 0;
        __syncthreads();
        bscan[tid] += t;
        __syncthreads();
    }
    int rbase = bscan[b] - borig[b];
    int len = borig[b];
    const unsigned* bin = barr + (size_t)b * BSLOT;

    hist[tid] = 0;
    __syncthreads();
    for (int i = tid; i < len; i += 256) {
        unsigned ed = bin[i];
        if (i < RCAP) raw[i] = ed;
        atomicAdd(&hist[ed >> 16], 1);
    }
    __syncthreads();
    int v = hist[tid];
    scn[tid] = v;
    __syncthreads();
    for (int off = 1; off < 256; off <<= 1) {
        int t = (tid >= off) ? scn[tid - off] : 0;
        __syncthreads();
        scn[tid] += t;
        __syncthreads();
    }
    int excl = scn[tid] - v;
    int n = n0 + tid;
    if (n < N_NODES) {
        row_off[n] = rbase + excl;
        dis[n] = rsqrtf((float)(v + 1));   // +1 = self-loop
    }
    if (b == NBUCK - 1 && tid == 0) row_off[N_NODES] = N_EDGES;
    hist[tid] = excl;   // reuse as cursor
    __syncthreads();
    for (int i = tid; i < len; i += 256) {
        unsigned ed = (i < RCAP) ? raw[i] : bin[i];
        int p = atomicAdd(&hist[ed >> 16], 1);
        unsigned short sv = (unsigned short)(ed & 0xffffu);
        if (p < RCAP) stage[p] = sv;
        else csr[rbase + p] = sv;
    }
    __syncthreads();
    int lim = min(len, RCAP);
    for (int i = tid; i < lim; i += 256)
        csr[rbase + i] = stage[i];
}

// ---------------- Aggregation (pull, bf16 gather) ----------------
// 16 lanes/node, 16 nodes/block. FUSE_POOL=0: write bf16 rows to out.
// FUSE_POOL=1: skip the global store; stage rows in LDS and accumulate
// per-graph sums into pool (batch sorted -> ~1 atomic row per block).
template <int FUSE_POOL>
__global__ __launch_bounds__(256) void k_agg(const uint4* __restrict__ Hb4,
                                             const int* __restrict__ row_off,
                                             const unsigned short* __restrict__ csr,
                                             const float* __restrict__ dis,
                                             const float* __restrict__ bias,
                                             uint4* __restrict__ out,
                                             const int* __restrict__ batch,
                                             float* __restrict__ pool) {
    __shared__ float sacc[16][DIM];   // used only when FUSE_POOL
    __shared__ int sg[16];
    int lane = threadIdx.x & 15;
    int nl   = threadIdx.x >> 4;      // node-local 0..15
    int node = blockIdx.x * 16 + nl;
    if (node >= N_NODES) return;      // grid exact: 3125*16 = 50000

    float dn = dis[node];
    float wself = dn * dn;
    uint4 hp = Hb4[(size_t)node * 16 + lane];
    float a0[8], a1[8], a2[8], a3[8];
    a0[0] = wself * bfl(hp.x); a0[1] = wself * bfh(hp.x);
    a0[2] = wself * bfl(hp.y); a0[3] = wself * bfh(hp.y);
    a0[4] = wself * bfl(hp.z); a0[5] = wself * bfh(hp.z);
    a0[6] = wself * bfl(hp.w); a0[7] = wself * bfh(hp.w);
#pragma unroll
    for (int j = 0; j < 8; ++j) { a1[j] = 0.f; a2[j] = 0.f; a3[j] = 0.f; }

    int e = row_off[node], e1 = row_off[node + 1];
    for (; e + 4 <= e1; e += 4) {
        int s0 = csr[e];     int s1 = csr[e + 1];
        int s2 = csr[e + 2]; int s3 = csr[e + 3];
        uint4 g0 = Hb4[(size_t)s0 * 16 + lane];
        uint4 g1 = Hb4[(size_t)s1 * 16 + lane];
        uint4 g2 = Hb4[(size_t)s2 * 16 + lane];
        uint4 g3 = Hb4[(size_t)s3 * 16 + lane];
        float w0 = dn * dis[s0], w1 = dn * dis[s1];
        float w2 = dn * dis[s2], w3 = dn * dis[s3];
        a0[0] = fmaf(w0, bfl(g0.x), a0[0]); a0[1] = fmaf(w0, bfh(g0.x), a0[1]);
        a0[2] = fmaf(w0, bfl(g0.y), a0[2]); a0[3] = fmaf(w0, bfh(g0.y), a0[3]);
        a0[4] = fmaf(w0, bfl(g0.z), a0[4]); a0[5] = fmaf(w0, bfh(g0.z), a0[5]);
        a0[6] = fmaf(w0, bfl(g0.w), a0[6]); a0[7] = fmaf(w0, bfh(g0.w), a0[7]);
        a1[0] = fmaf(w1, bfl(g1.x), a1[0]); a1[1] = fmaf(w1, bfh(g1.x), a1[1]);
        a1[2] = fmaf(w1, bfl(g1.y), a1[2]); a1[3] = fmaf(w1, bfh(g1.y), a1[3]);
        a1[4] = fmaf(w1, bfl(g1.z), a1[4]); a1[5] = fmaf(w1, bfh(g1.z), a1[5]);
        a1[6] = fmaf(w1, bfl(g1.w), a1[6]); a1[7] = fmaf(w1, bfh(g1.w), a1[7]);
        a2[0] = fmaf(w2, bfl(g2.x), a2[0]); a2[1] = fmaf(w2, bfh(g2.x), a2[1]);
        a2[2] = fmaf(w2, bfl(g2.y), a2[2]); a2[3] = fmaf(w2, bfh(g2.y), a2[3]);
        a2[4] = fmaf(w2, bfl(g2.z), a2[4]); a2[5] = fmaf(w2, bfh(g2.z), a2[5]);
        a2[6] = fmaf(w2, bfl(g2.w), a2[6]); a2[7] = fmaf(w2, bfh(g2.w), a2[7]);
        a3[0] = fmaf(w3, bfl(g3.x), a3[0]); a3[1] = fmaf(w3, bfh(g3.x), a3[1]);
        a3[2] = fmaf(w3, bfl(g3.y), a3[2]); a3[3] = fmaf(w3, bfh(g3.y), a3[3]);
        a3[4] = fmaf(w3, bfl(g3.z), a3[4]); a3[5] = fmaf(w3, bfh(g3.z), a3[5]);
        a3[6] = fmaf(w3, bfl(g3.w), a3[6]); a3[7] = fmaf(w3, bfh(g3.w), a3[7]);
    }
    for (; e < e1; ++e) {
        int s = csr[e];
        uint4 g = Hb4[(size_t)s * 16 + lane];
        float w = dn * dis[s];
        a0[0] = fmaf(w, bfl(g.x), a0[0]); a0[1] = fmaf(w, bfh(g.x), a0[1]);
        a0[2] = fmaf(w, bfl(g.y), a0[2]); a0[3] = fmaf(w, bfh(g.y), a0[3]);
        a0[4] = fmaf(w, bfl(g.z), a0[4]); a0[5] = fmaf(w, bfh(g.z), a0[5]);
        a0[6] = fmaf(w, bfl(g.w), a0[6]); a0[7] = fmaf(w, bfh(g.w), a0[7]);
    }

    float4 b0 = ((const float4*)bias)[lane * 2];
    float4 b1v = ((const float4*)bias)[lane * 2 + 1];
    float r[8];
    r[0] = fmaxf(a0[0] + a1[0] + a2[0] + a3[0] + b0.x, 0.f);
    r[1] = fmaxf(a0[1] + a1[1] + a2[1] + a3[1] + b0.y, 0.f);
    r[2] = fmaxf(a0[2] + a1[2] + a2[2] + a3[2] + b0.z, 0.f);
    r[3] = fmaxf(a0[3] + a1[3] + a2[3] + a3[3] + b0.w, 0.f);
    r[4] = fmaxf(a0[4] + a1[4] + a2[4] + a3[4] + b1v.x, 0.f);
    r[5] = fmaxf(a0[5] + a1[5] + a2[5] + a3[5] + b1v.y, 0.f);
    r[6] = fmaxf(a0[6] + a1[6] + a2[6] + a3[6] + b1v.z, 0.f);
    r[7] = fmaxf(a0[7] + a1[7] + a2[7] + a3[7] + b1v.w, 0.f);

    if (!FUSE_POOL) {
        uint4 ov;
        ov.x = (unsigned)f2bf(r[0]) | ((unsigned)f2bf(r[1]) << 16);
        ov.y = (unsigned)f2bf(r[2]) | ((unsigned)f2bf(r[3]) << 16);
        ov.z = (unsigned)f2bf(r[4]) | ((unsigned)f2bf(r[5]) << 16);
        ov.w = (unsigned)f2bf(r[6]) | ((unsigned)f2bf(r[7]) << 16);
        out[(size_t)node * 16 + lane] = ov;
    } else {
        // stage this node's 8 channels; reduce 16 nodes by graph run
#pragma unroll
        for (int j = 0; j < 8; ++j) sacc[nl][lane * 8 + j] = r[j];
        if (lane == 0) sg[nl] = batch[node];
        __syncthreads();
        int c = threadIdx.x;            // 256 threads; channels on first 128
        if (c < DIM) {
            float acc = 0.f;
            int curg = sg[0];
#pragma unroll
            for (int n = 0; n < 16; ++n) {
                int g = sg[n];
                if (g != curg) {
                    atomicAdd(&pool[curg * DIM + c], acc);
                    acc = 0.f; curg = g;
                }
                acc += sacc[n][c];
            }
            atomicAdd(&pool[curg * DIM + c], acc);
        }
    }
}

// ---------------- Final FC: counts via binary search on sorted batch ------
__global__ void k_fc(const float* __restrict__ pool, const int* __restrict__ batch,
                     const float* __restrict__ Wfc, const float* __restrict__ bfc,
                     float* __restrict__ out) {
    int id = blockIdx.x * blockDim.x + threadIdx.x;
    if (id >= N_GRAPHS * OUTD) return;
    int g = id >> 4, o = id & 15;
    // lower_bound(g) and lower_bound(g+1)
    int lo = 0, hi = N_NODES;
    while (lo < hi) { int mid = (lo + hi) >> 1; if (batch[mid] < g) lo = mid + 1; else hi = mid; }
    int l0 = lo;
    lo = 0; hi = N_NODES;
    while (lo < hi) { int mid = (lo + hi) >> 1; if (batch[mid] < g + 1) lo = mid + 1; else hi = mid; }
    int cntg = lo - l0;
    float inv = 1.0f / fmaxf((float)cntg, 1.0f);
    float acc = bfc[o];
    const float* p = pool + g * DIM;
    for (int c = 0; c < DIM; ++c)
        acc = fmaf(p[c] * inv, Wfc[c * OUTD + o], acc);
    out[id] = acc;
}

// ---------------- launch ----------------

extern "C" void kernel_launch(void* const* d_in, const int* in_sizes, int n_in,
                              void* d_out, int out_size, void* d_ws, size_t ws_size,
                              hipStream_t stream) {
    const float* x    = (const float*)d_in[0];
    const int*   ei   = (const int*)d_in[1];
    const int*   batch= (const int*)d_in[2];
    const float* W1   = (const float*)d_in[3];
    const float* b1   = (const float*)d_in[4];
    const float* W2   = (const float*)d_in[5];
    const float* b2   = (const float*)d_in[6];
    const float* Wfc  = (const float*)d_in[7];
    const float* bfc  = (const float*)d_in[8];
    float* out = (float*)d_out;

    char* ws = (char*)d_ws;
    size_t off = 0;
    auto alloc = [&](size_t bytes) -> char* {
        char* p = ws + off;
        off = (off + bytes + 255) & ~(size_t)255;
        return p;
    };
    int*      bcnt     = (int*)     alloc((size_t)NBUCK * 4);
    int*      row_off  = (int*)     alloc((size_t)(N_NODES + 1) * 4);
    float*    dis      = (float*)   alloc((size_t)N_NODES * 4);
    unsigned short* csr= (unsigned short*)alloc((size_t)N_EDGES * 2);
    unsigned* barr     = (unsigned*)alloc((size_t)NBUCK * BSLOT * 4);
    float*    pool     = (float*)   alloc((size_t)N_GRAPHS * DIM * 4);
    unsigned short* Hb = (unsigned short*)alloc((size_t)N_NODES * DIM * 2);
    unsigned short* Hb2= (unsigned short*)alloc((size_t)N_NODES * DIM * 2);

    const int* src = ei;
    const int* dst = ei + N_EDGES;

    k_init<<<1, 256, 0, stream>>>(bcnt, pool);
    // fused: layer-1 GEMM (f32 -> bf16) runs concurrently with edge binning
    k_fused1<<<GEMMB + BIN_GRID, 256, 0, stream>>>(x, W1, Hb, N_NODES,
                                                   src, dst, bcnt, barr);
    k_binB<<<NBUCK, 256, 0, stream>>>(barr, bcnt, row_off, dis, csr);

    int agg_grid = (N_NODES + 15) / 16;    // 3125
    k_agg<0><<<agg_grid, 256, 0, stream>>>((const uint4*)Hb, row_off, csr, dis, b1,
                                           (uint4*)Hb2, batch, pool);
    k_gemm2<<<GEMMB, 256, 0, stream>>>(Hb2, W2, Hb, N_NODES);
    // layer-2 agg with fused mean-pool accumulation (no Hb2 write)
    k_agg<1><<<agg_grid, 256, 0, stream>>>((const uint4*)Hb, row_off, csr, dis, b2,
                                           nullptr, batch, pool);
    k_fc<<<(N_GRAPHS * OUTD + 255) / 256, 256, 0, stream>>>(pool, batch, Wfc, bfc, out);
}

// Round 13
// 197.274 us; speedup vs baseline: 2.2146x; 1.0334x over previous
//
#include <hip/hip_runtime.h>
#include <math.h>

#define N_NODES 50000
#define N_EDGES 800000
#define N_GRAPHS 64
#define DIM 128
#define OUTD 16

// bucketed CSR build: 256 nodes per bucket, STATIC bucket regions
#define BSHIFT 8
#define BNODES 256
#define NBUCK ((N_NODES + BNODES - 1) / BNODES)   // 196
#define TILE 2048                                  // edges per binning block
#define RCAP 8192                                  // LDS stage capacity (entries)
#define BSLOT 4864                                 // static region (mean 4096 + 12 sigma)
#define GEMMB 256                                  // persistent gemm blocks
#define BIN_GRID ((N_EDGES + TILE - 1) / TILE)     // 391

typedef __attribute__((ext_vector_type(8))) short short8;
typedef __attribute__((ext_vector_type(4))) float f32x4;

// ---- bf16 helpers (round-to-nearest-even; values are finite) ----
static __device__ __forceinline__ unsigned short f2bf(float f) {
    unsigned u = __float_as_uint(f);
    u += 0x7fffu + ((u >> 16) & 1u);
    return (unsigned short)(u >> 16);
}
static __device__ __forceinline__ float bfl(unsigned u) {
    return __uint_as_float(u << 16);
}
static __device__ __forceinline__ float bfh(unsigned u) {
    return __uint_as_float(u & 0xffff0000u);
}

// ---------------- init: zero bucket counts + pool; preconvert W2 ----------
// W2f layout = gemm fragment order: uint[((kstep*8+ct)*64 + quad*16+(n&15))*4 + jw]
// holding bf16(W2[k][n]) | bf16(W2[k+1][n])<<16 for k=2*kp.
__global__ __launch_bounds__(256) void k_init(int* __restrict__ bcnt,
                                              float* __restrict__ pool,
                                              const float* __restrict__ W2,
                                              unsigned* __restrict__ W2f) {
    int tid = threadIdx.x;
    if (tid < NBUCK) bcnt[tid] = 0;
    for (int i = tid; i < N_GRAPHS * DIM; i += 256) pool[i] = 0.f;
    for (int idx = tid; idx < (DIM / 2) * DIM; idx += 256) {
        int kp = idx >> 7;          // 0..63
        int n  = idx & 127;
        int k  = kp * 2;
        int kstep = kp >> 4;
        int quad  = (kp >> 2) & 3;
        int jw    = kp & 3;
        int ct    = n >> 4;
        unsigned vlo = f2bf(W2[(size_t)k * DIM + n]);
        unsigned vhi = f2bf(W2[(size_t)(k + 1) * DIM + n]);
        W2f[(((kstep * 8 + ct) * 64) + quad * 16 + (n & 15)) * 4 + jw] = vlo | (vhi << 16);
    }
}

// ---------------- shared GEMM body (W in LDS, MFMA, LDS C-stage) ----------
template <int BF16IN>
static __device__ __forceinline__ void gemm_body(const void* __restrict__ Av,
                                                 const float* __restrict__ Wg,
                                                 unsigned short* __restrict__ C,
                                                 int nrows,
                                                 unsigned* smemW, unsigned* smemC,
                                                 int tile0, int tstride) {
    unsigned* Wl = smemW;
    {
        int t = threadIdx.x;
        int p = t & 63;
        int kp = p * 2;
        int n0 = (t >> 6) * 32;
        int kstep = kp >> 5;
        int quad = (kp >> 3) & 3;
        int jw = (kp & 7) >> 1;
        const float* r0 = Wg + (size_t)kp * DIM;
        const float* r1 = r0 + DIM;
        int rot = (p >> 2) & 7;
#pragma unroll
        for (int i4 = 0; i4 < 8; ++i4) {
            int nb = ((i4 + rot) & 7) * 4;
            int n = n0 + nb;
            float4 lo = *(const float4*)(r0 + n);
            float4 hi = *(const float4*)(r1 + n);
            const float* lp = &lo.x;
            const float* hp = &hi.x;
#pragma unroll
            for (int ii = 0; ii < 4; ++ii) {
                int nn = n + ii;
                int ct = nn >> 4;
                int l  = quad * 16 + (nn & 15);
                unsigned vlo = f2bf(lp[ii]);
                unsigned vhi = f2bf(hp[ii]);
                Wl[(((kstep * 8 + ct) * 64) + l) * 4 + jw] = vlo | (vhi << 16);
            }
        }
    }
    __syncthreads();

    int wid  = threadIdx.x >> 6;
    int lane = threadIdx.x & 63;
    int m    = lane & 15;
    int quad = lane >> 4;
    const short8* Wf = (const short8*)Wl;
    unsigned short* cs = (unsigned short*)smemC + wid * 4352;  // 32 rows x 136 ushorts
    const unsigned char* cb = (const unsigned char*)smemC + wid * 8704;

    int ntiles = (nrows + 127) / 128;
    for (int tile = tile0; tile < ntiles; tile += tstride) {
        int row0 = tile * 128 + wid * 32;
        if (row0 >= nrows) continue;

        int rA = row0 + m;      if (rA >= nrows) rA = nrows - 1;
        int rB = row0 + 16 + m; if (rB >= nrows) rB = nrows - 1;

        short8 af0[4], af1[4];
        if (BF16IN) {
            const unsigned short* arowA = (const unsigned short*)Av + (size_t)rA * DIM + quad * 8;
            const unsigned short* arowB = (const unsigned short*)Av + (size_t)rB * DIM + quad * 8;
#pragma unroll
            for (int ks = 0; ks < 4; ++ks) {
                af0[ks] = *(const short8*)(arowA + ks * 32);
                af1[ks] = *(const short8*)(arowB + ks * 32);
            }
        } else {
            const float* arowA = (const float*)Av + (size_t)rA * DIM + quad * 8;
            const float* arowB = (const float*)Av + (size_t)rB * DIM + quad * 8;
#pragma unroll
            for (int ks = 0; ks < 4; ++ks) {
                float4 lo = *(const float4*)(arowA + ks * 32);
                float4 hi = *(const float4*)(arowA + ks * 32 + 4);
                short8 f;
                f[0] = (short)f2bf(lo.x); f[1] = (short)f2bf(lo.y);
                f[2] = (short)f2bf(lo.z); f[3] = (short)f2bf(lo.w);
                f[4] = (short)f2bf(hi.x); f[5] = (short)f2bf(hi.y);
                f[6] = (short)f2bf(hi.z); f[7] = (short)f2bf(hi.w);
                af0[ks] = f;
                lo = *(const float4*)(arowB + ks * 32);
                hi = *(const float4*)(arowB + ks * 32 + 4);
                f[0] = (short)f2bf(lo.x); f[1] = (short)f2bf(lo.y);
                f[2] = (short)f2bf(lo.z); f[3] = (short)f2bf(lo.w);
                f[4] = (short)f2bf(hi.x); f[5] = (short)f2bf(hi.y);
                f[6] = (short)f2bf(hi.z); f[7] = (short)f2bf(hi.w);
                af1[ks] = f;
            }
        }

        f32x4 acc0[8], acc1[8];
#pragma unroll
        for (int ct = 0; ct < 8; ++ct) {
            acc0[ct] = (f32x4){0.f, 0.f, 0.f, 0.f};
            acc1[ct] = (f32x4){0.f, 0.f, 0.f, 0.f};
        }

#pragma unroll
        for (int ks = 0; ks < 4; ++ks) {
#pragma unroll
            for (int ct = 0; ct < 8; ++ct) {
                short8 bfrag = Wf[(ks * 8 + ct) * 64 + lane];
                acc0[ct] = __builtin_amdgcn_mfma_f32_16x16x32_bf16(af0[ks], bfrag, acc0[ct], 0, 0, 0);
                acc1[ct] = __builtin_amdgcn_mfma_f32_16x16x32_bf16(af1[ks], bfrag, acc1[ct], 0, 0, 0);
            }
        }

#pragma unroll
        for (int ct = 0; ct < 8; ++ct) {
#pragma unroll
            for (int reg = 0; reg < 4; ++reg) {
                cs[(quad * 4 + reg) * 136 + ct * 16 + m]      = f2bf(acc0[ct][reg]);
                cs[(16 + quad * 4 + reg) * 136 + ct * 16 + m] = f2bf(acc1[ct][reg]);
            }
        }
#pragma unroll
        for (int i = 0; i < 8; ++i) {
            int rg = i * 4 + quad;
            int r = row0 + rg;
            if (r < nrows) {
                uint4 vv = *(const uint4*)(cb + rg * 272 + m * 16);
                *((uint4*)(C + (size_t)r * DIM) + m) = vv;
            }
        }
    }
}

// ---------------- fused layer-1 GEMM + binA (independent work) ------------
__global__ __launch_bounds__(256) void k_fused1(const float* __restrict__ A,
                                                const float* __restrict__ Wg,
                                                unsigned short* __restrict__ C,
                                                int nrows,
                                                const int* __restrict__ src,
                                                const int* __restrict__ dstp,
                                                int* __restrict__ bcnt,
                                                unsigned* __restrict__ bucket_arr) {
    __shared__ unsigned smemW[32768 / 4];
    __shared__ unsigned smemC[34816 / 4];
    if (blockIdx.x >= GEMMB) {
        int* cnt  = (int*)smemW;
        int* base = cnt + NBUCK;
        int tile0 = (blockIdx.x - GEMMB) * TILE;
        for (int i = threadIdx.x; i < NBUCK; i += 256) cnt[i] = 0;
        __syncthreads();
#pragma unroll
        for (int j = 0; j < TILE / 512; ++j) {
            int e = tile0 + j * 512 + threadIdx.x * 2;
            if (e < N_EDGES) {
                int2 d = *(const int2*)(dstp + e);
                atomicAdd(&cnt[d.x >> BSHIFT], 1);
                atomicAdd(&cnt[d.y >> BSHIFT], 1);
            }
        }
        __syncthreads();
        for (int i = threadIdx.x; i < NBUCK; i += 256) {
            int c = cnt[i];
            base[i] = i * BSLOT + (c ? atomicAdd(&bcnt[i], c) : 0);
            cnt[i] = 0;   // reuse as local cursor
        }
        __syncthreads();
#pragma unroll
        for (int j = 0; j < TILE / 512; ++j) {
            int e = tile0 + j * 512 + threadIdx.x * 2;
            if (e < N_EDGES) {
                int2 s = *(const int2*)(src + e);
                int2 d = *(const int2*)(dstp + e);
                int b0 = d.x >> BSHIFT, b1 = d.y >> BSHIFT;
                int p0 = base[b0] + atomicAdd(&cnt[b0], 1);
                bucket_arr[p0] = (unsigned)s.x | ((unsigned)(d.x & 255) << 16);
                int p1 = base[b1] + atomicAdd(&cnt[b1], 1);
                bucket_arr[p1] = (unsigned)s.y | ((unsigned)(d.y & 255) << 16);
            }
        }
        return;
    }
    gemm_body<0>(A, Wg, C, nrows, smemW, smemC, blockIdx.x, GEMMB);
}

// ---------------- Pass B: bases scan + fine scatter + degree/rowoff/dis ----
__global__ __launch_bounds__(256) void k_binB(const unsigned* __restrict__ barr,
                                              const int* __restrict__ bcnt,
                                              int* __restrict__ row_off,
                                              float* __restrict__ dis,
                                              unsigned short* __restrict__ csr) {
    __shared__ unsigned raw[RCAP];
    __shared__ unsigned short stage[RCAP];
    __shared__ int hist[BNODES];
    __shared__ int scn[BNODES];
    __shared__ int borig[256], bscan[256];
    int tid = threadIdx.x;
    int b = blockIdx.x;
    int n0 = b << BSHIFT;

    int cv = (tid < NBUCK) ? bcnt[tid] : 0;
    borig[tid] = cv;
    bscan[tid] = cv;
    __syncthreads();
    for (int off = 1; off < 256; off <<= 1) {
        int t = (tid >= off) ? bscan[tid - off] : 0;
        __syncthreads();
        bscan[tid] += t;
        __syncthreads();
    }
    int rbase = bscan[b] - borig[b];
    int len = borig[b];
    const unsigned* bin = barr + (size_t)b * BSLOT;

    hist[tid] = 0;
    __syncthreads();
    for (int i = tid; i < len; i += 256) {
        unsigned ed = bin[i];
        if (i < RCAP) raw[i] = ed;
        atomicAdd(&hist[ed >> 16], 1);
    }
    __syncthreads();
    int v = hist[tid];
    scn[tid] = v;
    __syncthreads();
    for (int off = 1; off < 256; off <<= 1) {
        int t = (tid >= off) ? scn[tid - off] : 0;
        __syncthreads();
        scn[tid] += t;
        __syncthreads();
    }
    int excl = scn[tid] - v;
    int n = n0 + tid;
    if (n < N_NODES) {
        row_off[n] = rbase + excl;
        dis[n] = rsqrtf((float)(v + 1));   // +1 = self-loop
    }
    if (b == NBUCK - 1 && tid == 0) row_off[N_NODES] = N_EDGES;
    hist[tid] = excl;   // reuse as cursor
    __syncthreads();
    for (int i = tid; i < len; i += 256) {
        unsigned ed = (i < RCAP) ? raw[i] : bin[i];
        int p = atomicAdd(&hist[ed >> 16], 1);
        unsigned short sv = (unsigned short)(ed & 0xffffu);
        if (p < RCAP) stage[p] = sv;
        else csr[rbase + p] = sv;
    }
    __syncthreads();
    int lim = min(len, RCAP);
    for (int i = tid; i < lim; i += 256)
        csr[rbase + i] = stage[i];
}

// ---------------- Aggregation (pull, bf16 gather) ----------------
// 16 lanes/node, 16 nodes/block. MODE==2 (layer 1): fuse the layer-2 GEMM —
// A1 staged bf16 in LDS, 4 waves x 8 MFMAs vs preconverted W2f, write G2.
// MODE==1 (layer 2): fuse mean-pool accumulation (no H write).
template <int MODE>
__global__ __launch_bounds__(256) void k_agg(const uint4* __restrict__ Hb4,
                                             const int* __restrict__ row_off,
                                             const unsigned short* __restrict__ csr,
                                             const float* __restrict__ dis,
                                             const float* __restrict__ bias,
                                             uint4* __restrict__ out,
                                             const int* __restrict__ batch,
                                             float* __restrict__ pool,
                                             const short8* __restrict__ W2f) {
    __shared__ unsigned char smem[8768];
    int lane = threadIdx.x & 15;
    int nl   = threadIdx.x >> 4;      // node-local 0..15
    int node = blockIdx.x * 16 + nl;  // grid exact: 3125*16 = 50000

    float dn = dis[node];
    float wself = dn * dn;
    uint4 hp = Hb4[(size_t)node * 16 + lane];
    float a0[8], a1[8], a2[8], a3[8];
    a0[0] = wself * bfl(hp.x); a0[1] = wself * bfh(hp.x);
    a0[2] = wself * bfl(hp.y); a0[3] = wself * bfh(hp.y);
    a0[4] = wself * bfl(hp.z); a0[5] = wself * bfh(hp.z);
    a0[6] = wself * bfl(hp.w); a0[7] = wself * bfh(hp.w);
#pragma unroll
    for (int j = 0; j < 8; ++j) { a1[j] = 0.f; a2[j] = 0.f; a3[j] = 0.f; }

    int e = row_off[node], e1 = row_off[node + 1];
    for (; e + 4 <= e1; e += 4) {
        int s0 = csr[e];     int s1 = csr[e + 1];
        int s2 = csr[e + 2]; int s3 = csr[e + 3];
        uint4 g0 = Hb4[(size_t)s0 * 16 + lane];
        uint4 g1 = Hb4[(size_t)s1 * 16 + lane];
        uint4 g2 = Hb4[(size_t)s2 * 16 + lane];
        uint4 g3 = Hb4[(size_t)s3 * 16 + lane];
        float w0 = dn * dis[s0], w1 = dn * dis[s1];
        float w2 = dn * dis[s2], w3 = dn * dis[s3];
        a0[0] = fmaf(w0, bfl(g0.x), a0[0]); a0[1] = fmaf(w0, bfh(g0.x), a0[1]);
        a0[2] = fmaf(w0, bfl(g0.y), a0[2]); a0[3] = fmaf(w0, bfh(g0.y), a0[3]);
        a0[4] = fmaf(w0, bfl(g0.z), a0[4]); a0[5] = fmaf(w0, bfh(g0.z), a0[5]);
        a0[6] = fmaf(w0, bfl(g0.w), a0[6]); a0[7] = fmaf(w0, bfh(g0.w), a0[7]);
        a1[0] = fmaf(w1, bfl(g1.x), a1[0]); a1[1] = fmaf(w1, bfh(g1.x), a1[1]);
        a1[2] = fmaf(w1, bfl(g1.y), a1[2]); a1[3] = fmaf(w1, bfh(g1.y), a1[3]);
        a1[4] = fmaf(w1, bfl(g1.z), a1[4]); a1[5] = fmaf(w1, bfh(g1.z), a1[5]);
        a1[6] = fmaf(w1, bfl(g1.w), a1[6]); a1[7] = fmaf(w1, bfh(g1.w), a1[7]);
        a2[0] = fmaf(w2, bfl(g2.x), a2[0]); a2[1] = fmaf(w2, bfh(g2.x), a2[1]);
        a2[2] = fmaf(w2, bfl(g2.y), a2[2]); a2[3] = fmaf(w2, bfh(g2.y), a2[3]);
        a2[4] = fmaf(w2, bfl(g2.z), a2[4]); a2[5] = fmaf(w2, bfh(g2.z), a2[5]);
        a2[6] = fmaf(w2, bfl(g2.w), a2[6]); a2[7] = fmaf(w2, bfh(g2.w), a2[7]);
        a3[0] = fmaf(w3, bfl(g3.x), a3[0]); a3[1] = fmaf(w3, bfh(g3.x), a3[1]);
        a3[2] = fmaf(w3, bfl(g3.y), a3[2]); a3[3] = fmaf(w3, bfh(g3.y), a3[3]);
        a3[4] = fmaf(w3, bfl(g3.z), a3[4]); a3[5] = fmaf(w3, bfh(g3.z), a3[5]);
        a3[6] = fmaf(w3, bfl(g3.w), a3[6]); a3[7] = fmaf(w3, bfh(g3.w), a3[7]);
    }
    for (; e < e1; ++e) {
        int s = csr[e];
        uint4 g = Hb4[(size_t)s * 16 + lane];
        float w = dn * dis[s];
        a0[0] = fmaf(w, bfl(g.x), a0[0]); a0[1] = fmaf(w, bfh(g.x), a0[1]);
        a0[2] = fmaf(w, bfl(g.y), a0[2]); a0[3] = fmaf(w, bfh(g.y), a0[3]);
        a0[4] = fmaf(w, bfl(g.z), a0[4]); a0[5] = fmaf(w, bfh(g.z), a0[5]);
        a0[6] = fmaf(w, bfl(g.w), a0[6]); a0[7] = fmaf(w, bfh(g.w), a0[7]);
    }

    float4 b0 = ((const float4*)bias)[lane * 2];
    float4 b1v = ((const float4*)bias)[lane * 2 + 1];
    float r[8];
    r[0] = fmaxf(a0[0] + a1[0] + a2[0] + a3[0] + b0.x, 0.f);
    r[1] = fmaxf(a0[1] + a1[1] + a2[1] + a3[1] + b0.y, 0.f);
    r[2] = fmaxf(a0[2] + a1[2] + a2[2] + a3[2] + b0.z, 0.f);
    r[3] = fmaxf(a0[3] + a1[3] + a2[3] + a3[3] + b0.w, 0.f);
    r[4] = fmaxf(a0[4] + a1[4] + a2[4] + a3[4] + b1v.x, 0.f);
    r[5] = fmaxf(a0[5] + a1[5] + a2[5] + a3[5] + b1v.y, 0.f);
    r[6] = fmaxf(a0[6] + a1[6] + a2[6] + a3[6] + b1v.z, 0.f);
    r[7] = fmaxf(a0[7] + a1[7] + a2[7] + a3[7] + b1v.w, 0.f);

    if (MODE == 2) {
        // --- fused layer-2 GEMM: G2[16x128] = A1[16x128] @ W2 ---
        unsigned short* sA = (unsigned short*)smem;          // 16 x 136
        unsigned short* sC = (unsigned short*)smem + 2176;   // 16 x 136
        uint4 av;
        av.x = (unsigned)f2bf(r[0]) | ((unsigned)f2bf(r[1]) << 16);
        av.y = (unsigned)f2bf(r[2]) | ((unsigned)f2bf(r[3]) << 16);
        av.z = (unsigned)f2bf(r[4]) | ((unsigned)f2bf(r[5]) << 16);
        av.w = (unsigned)f2bf(r[6]) | ((unsigned)f2bf(r[7]) << 16);
        *(uint4*)(sA + nl * 136 + lane * 8) = av;
        __syncthreads();

        int wid = threadIdx.x >> 6;
        int l64 = threadIdx.x & 63;
        int m   = l64 & 15;
        int q   = l64 >> 4;
        short8 af[4];
#pragma unroll
        for (int ks = 0; ks < 4; ++ks)
            af[ks] = *(const short8*)(sA + m * 136 + ks * 32 + q * 8);
        f32x4 acc[2];
        acc[0] = (f32x4){0.f, 0.f, 0.f, 0.f};
        acc[1] = (f32x4){0.f, 0.f, 0.f, 0.f};
#pragma unroll
        for (int ks = 0; ks < 4; ++ks) {
#pragma unroll
            for (int j = 0; j < 2; ++j) {
                int ct = wid * 2 + j;
                short8 bfrag = W2f[(ks * 8 + ct) * 64 + l64];
                acc[j] = __builtin_amdgcn_mfma_f32_16x16x32_bf16(af[ks], bfrag, acc[j], 0, 0, 0);
            }
        }
#pragma unroll
        for (int j = 0; j < 2; ++j) {
#pragma unroll
            for (int reg = 0; reg < 4; ++reg)
                sC[(q * 4 + reg) * 136 + (wid * 2 + j) * 16 + m] = f2bf(acc[j][reg]);
        }
        __syncthreads();
        {
            int t = threadIdx.x;
            int row = t >> 4, ch = t & 15;
            uint4 vv = *(const uint4*)((const unsigned char*)sC + row * 272 + ch * 16);
            out[(size_t)(blockIdx.x * 16 + row) * 16 + ch] = vv;
        }
    } else {
        // --- MODE 1: fused mean-pool accumulation ---
        float* sacc = (float*)smem;            // 16 x DIM f32
        int* sg = (int*)(smem + 16 * DIM * 4); // 16 ints
#pragma unroll
        for (int j = 0; j < 8; ++j) sacc[nl * DIM + lane * 8 + j] = r[j];
        if (lane == 0) sg[nl] = batch[node];
        __syncthreads();
        int c = threadIdx.x;
        if (c < DIM) {
            float acc = 0.f;
            int curg = sg[0];
#pragma unroll
            for (int n = 0; n < 16; ++n) {
                int g = sg[n];
                if (g != curg) {
                    atomicAdd(&pool[curg * DIM + c], acc);
                    acc = 0.f; curg = g;
                }
                acc += sacc[n * DIM + c];
            }
            atomicAdd(&pool[curg * DIM + c], acc);
        }
    }
}

// ---------------- Final FC: counts via binary search on sorted batch ------
__global__ void k_fc(const float* __restrict__ pool, const int* __restrict__ batch,
                     const float* __restrict__ Wfc, const float* __restrict__ bfc,
                     float* __restrict__ out) {
    int id = blockIdx.x * blockDim.x + threadIdx.x;
    if (id >= N_GRAPHS * OUTD) return;
    int g = id >> 4, o = id & 15;
    int lo = 0, hi = N_NODES;
    while (lo < hi) { int mid = (lo + hi) >> 1; if (batch[mid] < g) lo = mid + 1; else hi = mid; }
    int l0 = lo;
    lo = 0; hi = N_NODES;
    while (lo < hi) { int mid = (lo + hi) >> 1; if (batch[mid] < g + 1) lo = mid + 1; else hi = mid; }
    int cntg = lo - l0;
    float inv = 1.0f / fmaxf((float)cntg, 1.0f);
    float acc = bfc[o];
    const float* p = pool + g * DIM;
    for (int c = 0; c < DIM; ++c)
        acc = fmaf(p[c] * inv, Wfc[c * OUTD + o], acc);
    out[id] = acc;
}

// ---------------- launch ----------------

extern "C" void kernel_launch(void* const* d_in, const int* in_sizes, int n_in,
                              void* d_out, int out_size, void* d_ws, size_t ws_size,
                              hipStream_t stream) {
    const float* x    = (const float*)d_in[0];
    const int*   ei   = (const int*)d_in[1];
    const int*   batch= (const int*)d_in[2];
    const float* W1   = (const float*)d_in[3];
    const float* b1   = (const float*)d_in[4];
    const float* W2   = (const float*)d_in[5];
    const float* b2   = (const float*)d_in[6];
    const float* Wfc  = (const float*)d_in[7];
    const float* bfc  = (const float*)d_in[8];
    float* out = (float*)d_out;

    char* ws = (char*)d_ws;
    size_t off = 0;
    auto alloc = [&](size_t bytes) -> char* {
        char* p = ws + off;
        off = (off + bytes + 255) & ~(size_t)255;
        return p;
    };
    int*      bcnt     = (int*)     alloc((size_t)NBUCK * 4);
    int*      row_off  = (int*)     alloc((size_t)(N_NODES + 1) * 4);
    float*    dis      = (float*)   alloc((size_t)N_NODES * 4);
    unsigned short* csr= (unsigned short*)alloc((size_t)N_EDGES * 2);
    unsigned* barr     = (unsigned*)alloc((size_t)NBUCK * BSLOT * 4);
    float*    pool     = (float*)   alloc((size_t)N_GRAPHS * DIM * 4);
    unsigned* W2f      = (unsigned*)alloc((size_t)(DIM / 2) * DIM * 4);
    unsigned short* Hb = (unsigned short*)alloc((size_t)N_NODES * DIM * 2);
    unsigned short* Hb2= (unsigned short*)alloc((size_t)N_NODES * DIM * 2);

    const int* src = ei;
    const int* dst = ei + N_EDGES;

    k_init<<<1, 256, 0, stream>>>(bcnt, pool, W2, W2f);
    // fused: layer-1 GEMM (f32 -> bf16) runs concurrently with edge binning
    k_fused1<<<GEMMB + BIN_GRID, 256, 0, stream>>>(x, W1, Hb, N_NODES,
                                                   src, dst, bcnt, barr);
    k_binB<<<NBUCK, 256, 0, stream>>>(barr, bcnt, row_off, dis, csr);

    int agg_grid = (N_NODES + 15) / 16;    // 3125
    // layer-1 agg + fused layer-2 GEMM: reads G1(Hb), writes G2(Hb2)
    k_agg<2><<<agg_grid, 256, 0, stream>>>((const uint4*)Hb, row_off, csr, dis, b1,
                                           (uint4*)Hb2, batch, pool, (const short8*)W2f);
    // layer-2 agg + fused mean-pool: reads G2(Hb2)
    k_agg<1><<<agg_grid, 256, 0, stream>>>((const uint4*)Hb2, row_off, csr, dis, b2,
                                           nullptr, batch, pool, nullptr);
    k_fc<<<(N_GRAPHS * OUTD + 255) / 256, 256, 0, stream>>>(pool, batch, Wfc, bfc, out);
}